// Round 3
// baseline (927.137 us; speedup 1.0000x reference)
//
#include <hip/hip_runtime.h>
#include <hip/hip_bf16.h>

#define NN 50000
#define NE 600000
#define NG 64
#define HD 128
#define NL 3
#define NEG 0.2f

typedef __hip_bfloat16 bf16;
typedef unsigned short u16;

// converted-f32 weight region offsets (element units)
#define OFF_GE    0
#define OFF_QE    4096
#define OFF_W     6656
#define OFF_AL    55808
#define OFF_AR    56192
#define OFF_BIAS  56576
#define OFF_LNG   56960
#define OFF_LNB   57088
#define OFF_GW    57216
#define OFF_GB    57344
#define OFF_PW1   57345
#define OFF_PB1   73729
#define OFF_PW2   73857
#define OFF_PB2   82049
#define CVT_TOTAL 82113

__device__ __forceinline__ float b2f(bf16 x) { return __bfloat162float(x); }
__device__ __forceinline__ bf16 f2b(float x) { return __float2bfloat16(x); }
__device__ __forceinline__ float lrelu(float x) { return x > 0.f ? x : NEG * x; }

__device__ __forceinline__ float wave_max64(float v) {
    #pragma unroll
    for (int m = 1; m < 64; m <<= 1) v = fmaxf(v, __shfl_xor(v, m, 64));
    return v;
}
__device__ __forceinline__ float wave_sum64(float v) {
    #pragma unroll
    for (int m = 1; m < 64; m <<= 1) v += __shfl_xor(v, m, 64);
    return v;
}
__device__ __forceinline__ float group_sum32(float v) {
    #pragma unroll
    for (int m = 1; m < 32; m <<= 1) v += __shfl_xor(v, m, 64);
    return v;
}

// ---- diagnostics ----
__global__ void k_diag(float* out, int n, float code) {
    int i = blockIdx.x * blockDim.x + threadIdx.x;
    if (i < n) out[i] = code;
}

// ---- input dtype detection: read W as raw u16; true-bf16 small-scale data
// never has bf16-exponent >= 0x90; f32 misread as bf16 has ~44% such slots.
__global__ void k_detect(const u16* __restrict__ w, int* __restrict__ flag) {
    __shared__ int cnt;
    if (threadIdx.x == 0) cnt = 0;
    __syncthreads();
    int bad = 0;
    for (int i = threadIdx.x; i < 2048; i += 256) {
        int e = (w[i] >> 7) & 0xFF;
        if (e == 0xFF || e >= 0x90) bad++;
    }
    atomicAdd(&cnt, bad);
    __syncthreads();
    if (threadIdx.x == 0) *flag = (cnt > 16) ? 1 : 0;
}

struct CvtSrc { const void* p[14]; };

__global__ void k_convert(CvtSrc srcs, const int* __restrict__ flag,
                          float* __restrict__ dst) {
    const bool isf32 = (*flag != 0);
    const int starts[15] = {OFF_GE, OFF_QE, OFF_W, OFF_AL, OFF_AR, OFF_BIAS,
                            OFF_LNG, OFF_LNB, OFF_GW, OFF_GB, OFF_PW1, OFF_PB1,
                            OFF_PW2, OFF_PB2, CVT_TOTAL};
    for (int i = blockIdx.x * blockDim.x + threadIdx.x; i < CVT_TOTAL;
         i += gridDim.x * blockDim.x) {
        int a = 0;
        while (i >= starts[a + 1]) a++;
        int off = i - starts[a];
        dst[i] = isf32 ? ((const float*)srcs.p[a])[off]
                       : b2f(((const bf16*)srcs.p[a])[off]);
    }
}

// h[n][c] = gate_emb[gt[n]][c] + qubit_emb[qi[n]][c]  (bf16 store)
__global__ void k_embed(const int* __restrict__ gt, const int* __restrict__ qi,
                        const float* __restrict__ wc, bf16* __restrict__ h) {
    int idx = blockIdx.x * blockDim.x + threadIdx.x;
    if (idx >= NN * HD) return;
    int n = idx >> 7, c = idx & 127;
    h[idx] = f2b(wc[OFF_GE + gt[n] * HD + c] + wc[OFF_QE + qi[n] * HD + c]);
}

__global__ void k_count(const int* __restrict__ dst, int* __restrict__ deg) {
    int e = blockIdx.x * blockDim.x + threadIdx.x;
    if (e < NE) atomicAdd(&deg[dst[e]], 1);
}

__global__ void k_scan(const int* __restrict__ deg, int* __restrict__ row_ptr,
                       int* __restrict__ cursor) {
    __shared__ int s[1024];
    int tid = threadIdx.x;
    int running = 0;
    for (int base = 0; base < NN; base += 1024) {
        int i = base + tid;
        int x = (i < NN) ? deg[i] : 0;
        s[tid] = x;
        __syncthreads();
        for (int off = 1; off < 1024; off <<= 1) {
            int t = (tid >= off) ? s[tid - off] : 0;
            __syncthreads();
            if (tid >= off) s[tid] += t;
            __syncthreads();
        }
        int incl = s[tid];
        int tot = s[1023];
        if (i < NN) {
            int excl = running + incl - x;
            row_ptr[i] = excl;
            cursor[i] = excl;
        }
        running += tot;
        __syncthreads();
    }
    if (tid == 0) row_ptr[NN] = running;
}

__global__ void k_fill(const int* __restrict__ src, const int* __restrict__ dst,
                       int* __restrict__ cursor, int* __restrict__ csr_src) {
    int e = blockIdx.x * blockDim.x + threadIdx.x;
    if (e < NE) {
        int p = atomicAdd(&cursor[dst[e]], 1);
        csr_src[p] = src[e];
    }
}

// feat = h @ W[l] (f32 acc, bf16 store); el/er per-head attn dots. 1 node/wave.
__global__ __launch_bounds__(256) void k_gemm(
        const bf16* __restrict__ h, const float* __restrict__ wc,
        float* __restrict__ feat_unused, bf16* __restrict__ feat,
        float* __restrict__ el, float* __restrict__ er, int l) {
    __shared__ float Ws[HD * HD];
    const float* Wl = wc + OFF_W + l * HD * HD;
    for (int i = threadIdx.x; i < HD * HD; i += 256) Ws[i] = Wl[i];
    __syncthreads();
    int lane = threadIdx.x & 63, wid = threadIdx.x >> 6;
    float alA = wc[OFF_AL + l * HD + lane],      alB = wc[OFF_AL + l * HD + 64 + lane];
    float arA = wc[OFF_AR + l * HD + lane],      arB = wc[OFF_AR + l * HD + 64 + lane];
    for (int n = blockIdx.x * 4 + wid; n < NN; n += gridDim.x * 4) {
        float hr0 = b2f(h[n * HD + lane]), hr1 = b2f(h[n * HD + 64 + lane]);
        float acc0 = 0.f, acc1 = 0.f;
        #pragma unroll 16
        for (int k = 0; k < 64; k++) {
            float hk = __shfl(hr0, k, 64);
            acc0 += hk * Ws[k * HD + lane];
            acc1 += hk * Ws[k * HD + 64 + lane];
        }
        #pragma unroll 16
        for (int k = 0; k < 64; k++) {
            float hk = __shfl(hr1, k, 64);
            acc0 += hk * Ws[(64 + k) * HD + lane];
            acc1 += hk * Ws[(64 + k) * HD + 64 + lane];
        }
        feat[n * HD + lane] = f2b(acc0);
        feat[n * HD + 64 + lane] = f2b(acc1);
        float tlA = group_sum32(acc0 * alA);
        float tlB = group_sum32(acc1 * alB);
        float trA = group_sum32(acc0 * arA);
        float trB = group_sum32(acc1 * arB);
        if ((lane & 31) == 0) {
            int g = lane >> 5;
            el[n * 4 + g]     = tlA;
            el[n * 4 + 2 + g] = tlB;
            er[n * 4 + g]     = trA;
            er[n * 4 + 2 + g] = trB;
        }
    }
}

// per-dst online softmax + aggregation; one wave per node
__global__ __launch_bounds__(256) void k_agg(
        const bf16* __restrict__ feat, const float* __restrict__ el,
        const float* __restrict__ er, const int* __restrict__ row_ptr,
        const int* __restrict__ csr_src, const float* __restrict__ wc,
        bf16* __restrict__ h, int l) {
    int lane = threadIdx.x & 63, wid = threadIdx.x >> 6;
    for (int n = blockIdx.x * 4 + wid; n < NN; n += gridDim.x * 4) {
        int rp = row_ptr[n];
        int deg = row_ptr[n + 1] - rp;
        float4 erv = *reinterpret_cast<const float4*>(er + n * 4);
        float m0 = -1e30f, m1 = -1e30f, m2 = -1e30f, m3 = -1e30f;
        float z0 = 0.f, z1 = 0.f, z2 = 0.f, z3 = 0.f;
        float acc0 = 0.f, acc1 = 0.f;
        for (int base = 0; base < deg; base += 64) {
            int e = base + lane;
            bool act = e < deg;
            int s = act ? csr_src[rp + e] : 0;
            float s0 = -1e30f, s1 = -1e30f, s2 = -1e30f, s3 = -1e30f;
            if (act) {
                float4 elv = *reinterpret_cast<const float4*>(el + s * 4);
                s0 = lrelu(elv.x + erv.x);
                s1 = lrelu(elv.y + erv.y);
                s2 = lrelu(elv.z + erv.z);
                s3 = lrelu(elv.w + erv.w);
            }
            float nm0 = fmaxf(m0, wave_max64(s0));
            float nm1 = fmaxf(m1, wave_max64(s1));
            float nm2 = fmaxf(m2, wave_max64(s2));
            float nm3 = fmaxf(m3, wave_max64(s3));
            float sc0 = __expf(m0 - nm0), sc1 = __expf(m1 - nm1);
            float sc2 = __expf(m2 - nm2), sc3 = __expf(m3 - nm3);
            float p0 = act ? __expf(s0 - nm0) : 0.f;
            float p1 = act ? __expf(s1 - nm1) : 0.f;
            float p2 = act ? __expf(s2 - nm2) : 0.f;
            float p3 = act ? __expf(s3 - nm3) : 0.f;
            z0 = z0 * sc0 + wave_sum64(p0);
            z1 = z1 * sc1 + wave_sum64(p1);
            z2 = z2 * sc2 + wave_sum64(p2);
            z3 = z3 * sc3 + wave_sum64(p3);
            float sA = (lane < 32) ? sc0 : sc1;
            float sB = (lane < 32) ? sc2 : sc3;
            acc0 *= sA;
            acc1 *= sB;
            m0 = nm0; m1 = nm1; m2 = nm2; m3 = nm3;
            int cnt = min(64, deg - base);
            for (int j = 0; j < cnt; j++) {
                int sj = __shfl(s, j, 64);
                float a0 = __shfl(p0, j, 64), a1 = __shfl(p1, j, 64);
                float a2 = __shfl(p2, j, 64), a3 = __shfl(p3, j, 64);
                float aA = (lane < 32) ? a0 : a1;
                float aB = (lane < 32) ? a2 : a3;
                const bf16* fr = feat + sj * HD;
                acc0 += aA * b2f(fr[lane]);
                acc1 += aB * b2f(fr[64 + lane]);
            }
        }
        float zA = (lane < 32) ? z0 : z1;
        float zB = (lane < 32) ? z2 : z3;
        float r0 = deg ? acc0 / zA : 0.f;
        float r1 = deg ? acc1 / zB : 0.f;
        int idx = n * HD + lane;
        float v0 = r0 + b2f(h[idx])      + wc[OFF_BIAS + l * HD + lane];
        float v1 = r1 + b2f(h[idx + 64]) + wc[OFF_BIAS + l * HD + 64 + lane];
        h[idx]      = f2b(fmaxf(v0, 0.f));
        h[idx + 64] = f2b(fmaxf(v1, 0.f));
    }
}

// LayerNorm + gate scalar; one wave per node
__global__ __launch_bounds__(256) void k_ln_gate(
        bf16* __restrict__ h, const float* __restrict__ wc,
        float* __restrict__ gate) {
    int lane = threadIdx.x & 63, wid = threadIdx.x >> 6;
    int n = blockIdx.x * 4 + wid;
    if (n >= NN) return;
    float x0 = b2f(h[n * HD + lane]), x1 = b2f(h[n * HD + 64 + lane]);
    float mu = wave_sum64(x0 + x1) * (1.0f / 128.0f);
    float d0 = x0 - mu, d1 = x1 - mu;
    float var = wave_sum64(d0 * d0 + d1 * d1) * (1.0f / 128.0f);
    float rs = rsqrtf(var + 1e-5f);
    float y0 = d0 * rs * wc[OFF_LNG + lane]      + wc[OFF_LNB + lane];
    float y1 = d1 * rs * wc[OFF_LNG + 64 + lane] + wc[OFF_LNB + 64 + lane];
    h[n * HD + lane] = f2b(y0);
    h[n * HD + 64 + lane] = f2b(y1);
    float g = wave_sum64(y0 * wc[OFF_GW + lane] + y1 * wc[OFF_GW + 64 + lane]);
    if (lane == 0) gate[n] = g + wc[OFF_GB];
}

__global__ void k_gbound(const int* __restrict__ gid, int* __restrict__ gb) {
    int g = threadIdx.x;
    if (g > NG) return;
    int lo = 0, hi = NN;
    while (lo < hi) {
        int mid = (lo + hi) >> 1;
        if (gid[mid] < g) lo = mid + 1;
        else hi = mid;
    }
    gb[g] = lo;
}

__global__ __launch_bounds__(256) void k_pool(
        const bf16* __restrict__ h, const float* __restrict__ gate,
        const int* __restrict__ gb, float* __restrict__ zg) {
    __shared__ float red[256];
    int g = blockIdx.x, tid = threadIdx.x;
    int s0 = gb[g], e0 = gb[g + 1];
    float m = -1e30f;
    for (int i = s0 + tid; i < e0; i += 256) m = fmaxf(m, gate[i]);
    red[tid] = m;
    __syncthreads();
    for (int off = 128; off; off >>= 1) {
        if (tid < off) red[tid] = fmaxf(red[tid], red[tid + off]);
        __syncthreads();
    }
    m = red[0];
    __syncthreads();
    float zs = 0.f;
    for (int i = s0 + tid; i < e0; i += 256) zs += __expf(gate[i] - m);
    red[tid] = zs;
    __syncthreads();
    for (int off = 128; off; off >>= 1) {
        if (tid < off) red[tid] += red[tid + off];
        __syncthreads();
    }
    float z = red[0];
    __syncthreads();
    float inv = (e0 > s0) ? 1.0f / z : 0.f;
    int ch = tid & 127, half = tid >> 7;
    float acc = 0.f;
    for (int i = s0 + half; i < e0; i += 2) {
        float w = __expf(gate[i] - m);
        acc += w * b2f(h[i * HD + ch]);
    }
    red[tid] = acc;
    __syncthreads();
    if (tid < 128) zg[g * HD + tid] = (red[tid] + red[tid + 128]) * inv;
}

__global__ __launch_bounds__(128) void k_mlp(
        const float* __restrict__ zg, const float* __restrict__ wc,
        float* __restrict__ out) {
    __shared__ float zr[HD], z1[HD];
    int g = blockIdx.x, tid = threadIdx.x;
    zr[tid] = zg[g * HD + tid];
    __syncthreads();
    float acc = wc[OFF_PB1 + tid];
    for (int k = 0; k < HD; k++) acc += zr[k] * wc[OFF_PW1 + k * HD + tid];
    z1[tid] = fmaxf(acc, 0.f);
    __syncthreads();
    if (tid < 64) {
        float a2 = wc[OFF_PB2 + tid];
        for (int k = 0; k < HD; k++) a2 += z1[k] * wc[OFF_PW2 + k * 64 + tid];
        out[g * 64 + tid] = a2;
    }
}

extern "C" void kernel_launch(void* const* d_in, const int* in_sizes, int n_in,
                              void* d_out, int out_size, void* d_ws, size_t ws_size,
                              hipStream_t stream) {
    const int* gate_types = (const int*)d_in[0];
    const int* qubit_idx  = (const int*)d_in[1];
    const int* src        = (const int*)d_in[2];
    const int* dst        = (const int*)d_in[3];
    const int* graph_ids  = (const int*)d_in[4];
    float* out = (float*)d_out;

    // sanity on input layout — if this trips, absmax decodes to 7777000+i
    const int expect[19] = {NN, NN, NE, NE, NN, 4096, 2560, 49152, 384, 384,
                            384, 128, 128, 128, 1, 16384, 128, 8192, 64};
    for (int i = 0; i < 19 && i < n_in; i++) {
        if (in_sizes[i] != expect[i]) {
            k_diag<<<(out_size + 255) / 256, 256, 0, stream>>>(out, out_size,
                                                               7777000.f + i);
            return;
        }
    }

    char* ws = (char*)d_ws;
    size_t off = 0;
    auto alloc = [&](size_t bytes) {
        void* p = ws + off;
        off = (off + bytes + 255) & ~(size_t)255;
        return p;
    };
    int*   flag    = (int*)alloc(sizeof(int));
    float* wc      = (float*)alloc(sizeof(float) * CVT_TOTAL);
    float* el      = (float*)alloc(sizeof(float) * NN * 4);
    float* er      = (float*)alloc(sizeof(float) * NN * 4);
    int*   row_ptr = (int*)alloc(sizeof(int) * (NN + 1));
    int*   deg     = (int*)alloc(sizeof(int) * NN);
    int*   cursor  = (int*)alloc(sizeof(int) * NN);
    int*   csr_src = (int*)alloc(sizeof(int) * NE);
    float* gate    = (float*)alloc(sizeof(float) * NN);
    int*   gb      = (int*)alloc(sizeof(int) * (NG + 1));
    float* zg      = (float*)alloc(sizeof(float) * NG * HD);
    bf16*  h       = (bf16*)alloc(sizeof(bf16) * NN * HD);
    bf16*  feat    = (bf16*)alloc(sizeof(bf16) * NN * HD);

    if (off > ws_size) {
        // absmax will read ~ws_size in KiB — tells us the real budget
        k_diag<<<(out_size + 255) / 256, 256, 0, stream>>>(
            out, out_size, (float)(ws_size >> 10));
        return;
    }

    // detect float-input dtype and build canonical f32 weight region
    k_detect<<<1, 256, 0, stream>>>((const u16*)d_in[7], flag);
    CvtSrc cs;
    for (int i = 0; i < 14; i++) cs.p[i] = d_in[5 + i];
    k_convert<<<128, 256, 0, stream>>>(cs, flag, wc);

    k_embed<<<(NN * HD + 255) / 256, 256, 0, stream>>>(gate_types, qubit_idx,
                                                       wc, h);
    hipMemsetAsync(deg, 0, sizeof(int) * NN, stream);
    k_count<<<(NE + 255) / 256, 256, 0, stream>>>(dst, deg);
    k_scan<<<1, 1024, 0, stream>>>(deg, row_ptr, cursor);
    k_fill<<<(NE + 255) / 256, 256, 0, stream>>>(src, dst, cursor, csr_src);

    for (int l = 0; l < NL; l++) {
        k_gemm<<<2048, 256, 0, stream>>>(h, wc, nullptr, feat, el, er, l);
        k_agg<<<2048, 256, 0, stream>>>(feat, el, er, row_ptr, csr_src, wc, h, l);
    }
    k_ln_gate<<<(NN + 3) / 4, 256, 0, stream>>>(h, wc, gate);
    k_gbound<<<1, 128, 0, stream>>>(graph_ids, gb);
    k_pool<<<NG, 256, 0, stream>>>(h, gate, gb, zg);
    k_mlp<<<NG, 128, 0, stream>>>(zg, wc, out);
}

// Round 4
// 591.086 us; speedup vs baseline: 1.5685x; 1.5685x over previous
//
#include <hip/hip_runtime.h>
#include <hip/hip_bf16.h>

#define NN 50000
#define NE 600000
#define NG 64
#define HD 128
#define NL 3
#define NEG 0.2f
#define MTILES 3125   // NN/16

typedef __hip_bfloat16 bf16;
typedef unsigned short u16;
typedef __attribute__((ext_vector_type(8))) short short8v;   // 8 bf16 (4 VGPR)
typedef __attribute__((ext_vector_type(4))) float float4v;   // MFMA acc

// converted-f32 weight region offsets (element units)
#define OFF_GE    0
#define OFF_QE    4096
#define OFF_W     6656
#define OFF_AL    55808
#define OFF_AR    56192
#define OFF_BIAS  56576
#define OFF_LNG   56960
#define OFF_LNB   57088
#define OFF_GW    57216
#define OFF_GB    57344
#define OFF_PW1   57345
#define OFF_PB1   73729
#define OFF_PW2   73857
#define OFF_PB2   82049
#define CVT_TOTAL 82113

__device__ __forceinline__ float b2f(bf16 x) { return __bfloat162float(x); }
__device__ __forceinline__ bf16 f2b(float x) { return __float2bfloat16(x); }
__device__ __forceinline__ short f2bs(float x) {
    bf16 t = __float2bfloat16(x);
    return *reinterpret_cast<short*>(&t);
}
__device__ __forceinline__ float lrelu(float x) { return x > 0.f ? x : NEG * x; }

__device__ __forceinline__ float wave_max64(float v) {
    #pragma unroll
    for (int m = 1; m < 64; m <<= 1) v = fmaxf(v, __shfl_xor(v, m, 64));
    return v;
}
__device__ __forceinline__ float wave_sum64(float v) {
    #pragma unroll
    for (int m = 1; m < 64; m <<= 1) v += __shfl_xor(v, m, 64);
    return v;
}

// ---- diagnostics ----
__global__ void k_diag(float* out, int n, float code) {
    int i = blockIdx.x * blockDim.x + threadIdx.x;
    if (i < n) out[i] = code;
}

// ---- input dtype detection (bf16 vs f32 misread) ----
__global__ void k_detect(const u16* __restrict__ w, int* __restrict__ flag) {
    __shared__ int cnt;
    if (threadIdx.x == 0) cnt = 0;
    __syncthreads();
    int bad = 0;
    for (int i = threadIdx.x; i < 2048; i += 256) {
        int e = (w[i] >> 7) & 0xFF;
        if (e == 0xFF || e >= 0x90) bad++;
    }
    atomicAdd(&cnt, bad);
    __syncthreads();
    if (threadIdx.x == 0) *flag = (cnt > 16) ? 1 : 0;
}

struct CvtSrc { const void* p[14]; };

__global__ void k_convert(CvtSrc srcs, const int* __restrict__ flag,
                          float* __restrict__ dst) {
    const bool isf32 = (*flag != 0);
    const int starts[15] = {OFF_GE, OFF_QE, OFF_W, OFF_AL, OFF_AR, OFF_BIAS,
                            OFF_LNG, OFF_LNB, OFF_GW, OFF_GB, OFF_PW1, OFF_PB1,
                            OFF_PW2, OFF_PB2, CVT_TOTAL};
    for (int i = blockIdx.x * blockDim.x + threadIdx.x; i < CVT_TOTAL;
         i += gridDim.x * blockDim.x) {
        int a = 0;
        while (i >= starts[a + 1]) a++;
        int off = i - starts[a];
        dst[i] = isf32 ? ((const float*)srcs.p[a])[off]
                       : b2f(((const bf16*)srcs.p[a])[off]);
    }
}

__global__ void k_embed(const int* __restrict__ gt, const int* __restrict__ qi,
                        const float* __restrict__ wc, bf16* __restrict__ h) {
    int idx = blockIdx.x * blockDim.x + threadIdx.x;
    if (idx >= NN * HD) return;
    int n = idx >> 7, c = idx & 127;
    h[idx] = f2b(wc[OFF_GE + gt[n] * HD + c] + wc[OFF_QE + qi[n] * HD + c]);
}

__global__ void k_count(const int* __restrict__ dst, int* __restrict__ deg) {
    int e = blockIdx.x * blockDim.x + threadIdx.x;
    if (e < NE) atomicAdd(&deg[dst[e]], 1);
}

__global__ void k_scan(const int* __restrict__ deg, int* __restrict__ row_ptr,
                       int* __restrict__ cursor) {
    __shared__ int s[1024];
    int tid = threadIdx.x;
    int running = 0;
    for (int base = 0; base < NN; base += 1024) {
        int i = base + tid;
        int x = (i < NN) ? deg[i] : 0;
        s[tid] = x;
        __syncthreads();
        for (int off = 1; off < 1024; off <<= 1) {
            int t = (tid >= off) ? s[tid - off] : 0;
            __syncthreads();
            if (tid >= off) s[tid] += t;
            __syncthreads();
        }
        int incl = s[tid];
        int tot = s[1023];
        if (i < NN) {
            int excl = running + incl - x;
            row_ptr[i] = excl;
            cursor[i] = excl;
        }
        running += tot;
        __syncthreads();
    }
    if (tid == 0) row_ptr[NN] = running;
}

__global__ void k_fill(const int* __restrict__ src, const int* __restrict__ dst,
                       int* __restrict__ cursor, int* __restrict__ csr_src) {
    int e = blockIdx.x * blockDim.x + threadIdx.x;
    if (e < NE) {
        int p = atomicAdd(&cursor[dst[e]], 1);
        csr_src[p] = src[e];
    }
}

// MFMA GEMM: feat = h @ W[l], fused el/er. Block = 4 waves; wave `wid` owns
// cols [wid*32, wid*32+32) (= head wid); grid-stride over 16-row M-tiles.
// k-convention: lane l, elem j -> k = (l>>4)*8 + j, IDENTICAL for A and B
// (symmetric lane maps => any k-permutation error cancels in sum over k).
// C/D layout (HW-verified): col = lane&15, row = (lane>>4)*4 + reg.
__global__ __launch_bounds__(256) void k_gemm_mfma(
        const bf16* __restrict__ h, const float* __restrict__ wc,
        bf16* __restrict__ feat, float* __restrict__ el,
        float* __restrict__ er, int l) {
    const int lane = threadIdx.x & 63, wid = threadIdx.x >> 6;
    const int r = lane & 15, q = lane >> 4;
    const int wbase = wid * 32;
    const float* Wl = wc + OFF_W + l * HD * HD;

    // B fragments: [tile t][k-step ks]; b[j] = W[k][col], k=ks*32+q*8+j
    short8v bfr[2][4];
    #pragma unroll
    for (int t = 0; t < 2; t++)
        #pragma unroll
        for (int ks = 0; ks < 4; ks++) {
            short8v b;
            #pragma unroll
            for (int j = 0; j < 8; j++)
                b[j] = f2bs(Wl[(ks * 32 + q * 8 + j) * HD + wbase + t * 16 + r]);
            bfr[t][ks] = b;
        }

    const float al0 = wc[OFF_AL + l * HD + wbase + r];
    const float al1 = wc[OFF_AL + l * HD + wbase + 16 + r];
    const float ar0 = wc[OFF_AR + l * HD + wbase + r];
    const float ar1 = wc[OFF_AR + l * HD + wbase + 16 + r];

    for (int tile = blockIdx.x; tile < MTILES; tile += gridDim.x) {
        const int base = tile * 16;
        float4v acc0 = {0.f, 0.f, 0.f, 0.f};
        float4v acc1 = {0.f, 0.f, 0.f, 0.f};
        #pragma unroll
        for (int ks = 0; ks < 4; ks++) {
            short8v a = *reinterpret_cast<const short8v*>(
                h + (base + r) * HD + ks * 32 + q * 8);
            acc0 = __builtin_amdgcn_mfma_f32_16x16x32_bf16(a, bfr[0][ks], acc0, 0, 0, 0);
            acc1 = __builtin_amdgcn_mfma_f32_16x16x32_bf16(a, bfr[1][ks], acc1, 0, 0, 0);
        }
        #pragma unroll
        for (int reg = 0; reg < 4; reg++) {
            const int row = base + q * 4 + reg;
            feat[row * HD + wbase + r]      = f2b(acc0[reg]);
            feat[row * HD + wbase + 16 + r] = f2b(acc1[reg]);
            float elp = acc0[reg] * al0 + acc1[reg] * al1;
            float erp = acc0[reg] * ar0 + acc1[reg] * ar1;
            #pragma unroll
            for (int m = 1; m < 16; m <<= 1) {
                elp += __shfl_xor(elp, m, 64);
                erp += __shfl_xor(erp, m, 64);
            }
            if (r == 0) {
                el[row * 4 + wid] = elp;
                er[row * 4 + wid] = erp;
            }
        }
    }
}

// per-dst online softmax + aggregation; one wave per node
__global__ __launch_bounds__(256) void k_agg(
        const bf16* __restrict__ feat, const float* __restrict__ el,
        const float* __restrict__ er, const int* __restrict__ row_ptr,
        const int* __restrict__ csr_src, const float* __restrict__ wc,
        bf16* __restrict__ h, int l) {
    int lane = threadIdx.x & 63, wid = threadIdx.x >> 6;
    for (int n = blockIdx.x * 4 + wid; n < NN; n += gridDim.x * 4) {
        int rp = row_ptr[n];
        int deg = row_ptr[n + 1] - rp;
        float4 erv = *reinterpret_cast<const float4*>(er + n * 4);
        float m0 = -1e30f, m1 = -1e30f, m2 = -1e30f, m3 = -1e30f;
        float z0 = 0.f, z1 = 0.f, z2 = 0.f, z3 = 0.f;
        float acc0 = 0.f, acc1 = 0.f;
        for (int base = 0; base < deg; base += 64) {
            int e = base + lane;
            bool act = e < deg;
            int s = act ? csr_src[rp + e] : 0;
            float s0 = -1e30f, s1 = -1e30f, s2 = -1e30f, s3 = -1e30f;
            if (act) {
                float4 elv = *reinterpret_cast<const float4*>(el + s * 4);
                s0 = lrelu(elv.x + erv.x);
                s1 = lrelu(elv.y + erv.y);
                s2 = lrelu(elv.z + erv.z);
                s3 = lrelu(elv.w + erv.w);
            }
            float nm0 = fmaxf(m0, wave_max64(s0));
            float nm1 = fmaxf(m1, wave_max64(s1));
            float nm2 = fmaxf(m2, wave_max64(s2));
            float nm3 = fmaxf(m3, wave_max64(s3));
            float sc0 = __expf(m0 - nm0), sc1 = __expf(m1 - nm1);
            float sc2 = __expf(m2 - nm2), sc3 = __expf(m3 - nm3);
            float p0 = act ? __expf(s0 - nm0) : 0.f;
            float p1 = act ? __expf(s1 - nm1) : 0.f;
            float p2 = act ? __expf(s2 - nm2) : 0.f;
            float p3 = act ? __expf(s3 - nm3) : 0.f;
            z0 = z0 * sc0 + wave_sum64(p0);
            z1 = z1 * sc1 + wave_sum64(p1);
            z2 = z2 * sc2 + wave_sum64(p2);
            z3 = z3 * sc3 + wave_sum64(p3);
            float sA = (lane < 32) ? sc0 : sc1;
            float sB = (lane < 32) ? sc2 : sc3;
            acc0 *= sA;
            acc1 *= sB;
            m0 = nm0; m1 = nm1; m2 = nm2; m3 = nm3;
            int cnt = min(64, deg - base);
            for (int j = 0; j < cnt; j++) {
                int sj = __shfl(s, j, 64);
                float a0 = __shfl(p0, j, 64), a1 = __shfl(p1, j, 64);
                float a2 = __shfl(p2, j, 64), a3 = __shfl(p3, j, 64);
                float aA = (lane < 32) ? a0 : a1;
                float aB = (lane < 32) ? a2 : a3;
                const bf16* fr = feat + sj * HD;
                acc0 += aA * b2f(fr[lane]);
                acc1 += aB * b2f(fr[64 + lane]);
            }
        }
        float zA = (lane < 32) ? z0 : z1;
        float zB = (lane < 32) ? z2 : z3;
        float r0 = deg ? acc0 / zA : 0.f;
        float r1 = deg ? acc1 / zB : 0.f;
        int idx = n * HD + lane;
        float v0 = r0 + b2f(h[idx])      + wc[OFF_BIAS + l * HD + lane];
        float v1 = r1 + b2f(h[idx + 64]) + wc[OFF_BIAS + l * HD + 64 + lane];
        h[idx]      = f2b(fmaxf(v0, 0.f));
        h[idx + 64] = f2b(fmaxf(v1, 0.f));
    }
}

__global__ __launch_bounds__(256) void k_ln_gate(
        bf16* __restrict__ h, const float* __restrict__ wc,
        float* __restrict__ gate) {
    int lane = threadIdx.x & 63, wid = threadIdx.x >> 6;
    int n = blockIdx.x * 4 + wid;
    if (n >= NN) return;
    float x0 = b2f(h[n * HD + lane]), x1 = b2f(h[n * HD + 64 + lane]);
    float mu = wave_sum64(x0 + x1) * (1.0f / 128.0f);
    float d0 = x0 - mu, d1 = x1 - mu;
    float var = wave_sum64(d0 * d0 + d1 * d1) * (1.0f / 128.0f);
    float rs = rsqrtf(var + 1e-5f);
    float y0 = d0 * rs * wc[OFF_LNG + lane]      + wc[OFF_LNB + lane];
    float y1 = d1 * rs * wc[OFF_LNG + 64 + lane] + wc[OFF_LNB + 64 + lane];
    h[n * HD + lane] = f2b(y0);
    h[n * HD + 64 + lane] = f2b(y1);
    float g = wave_sum64(y0 * wc[OFF_GW + lane] + y1 * wc[OFF_GW + 64 + lane]);
    if (lane == 0) gate[n] = g + wc[OFF_GB];
}

__global__ void k_gbound(const int* __restrict__ gid, int* __restrict__ gb) {
    int g = threadIdx.x;
    if (g > NG) return;
    int lo = 0, hi = NN;
    while (lo < hi) {
        int mid = (lo + hi) >> 1;
        if (gid[mid] < g) lo = mid + 1;
        else hi = mid;
    }
    gb[g] = lo;
}

__global__ __launch_bounds__(256) void k_pool(
        const bf16* __restrict__ h, const float* __restrict__ gate,
        const int* __restrict__ gb, float* __restrict__ zg) {
    __shared__ float red[256];
    int g = blockIdx.x, tid = threadIdx.x;
    int s0 = gb[g], e0 = gb[g + 1];
    float m = -1e30f;
    for (int i = s0 + tid; i < e0; i += 256) m = fmaxf(m, gate[i]);
    red[tid] = m;
    __syncthreads();
    for (int off = 128; off; off >>= 1) {
        if (tid < off) red[tid] = fmaxf(red[tid], red[tid + off]);
        __syncthreads();
    }
    m = red[0];
    __syncthreads();
    float zs = 0.f;
    for (int i = s0 + tid; i < e0; i += 256) zs += __expf(gate[i] - m);
    red[tid] = zs;
    __syncthreads();
    for (int off = 128; off; off >>= 1) {
        if (tid < off) red[tid] += red[tid + off];
        __syncthreads();
    }
    float z = red[0];
    __syncthreads();
    float inv = (e0 > s0) ? 1.0f / z : 0.f;
    int ch = tid & 127, half = tid >> 7;
    float acc = 0.f;
    for (int i = s0 + half; i < e0; i += 2) {
        float w = __expf(gate[i] - m);
        acc += w * b2f(h[i * HD + ch]);
    }
    red[tid] = acc;
    __syncthreads();
    if (tid < 128) zg[g * HD + tid] = (red[tid] + red[tid + 128]) * inv;
}

__global__ __launch_bounds__(128) void k_mlp(
        const float* __restrict__ zg, const float* __restrict__ wc,
        float* __restrict__ out) {
    __shared__ float zr[HD], z1[HD];
    int g = blockIdx.x, tid = threadIdx.x;
    zr[tid] = zg[g * HD + tid];
    __syncthreads();
    float acc = wc[OFF_PB1 + tid];
    for (int k = 0; k < HD; k++) acc += zr[k] * wc[OFF_PW1 + k * HD + tid];
    z1[tid] = fmaxf(acc, 0.f);
    __syncthreads();
    if (tid < 64) {
        float a2 = wc[OFF_PB2 + tid];
        for (int k = 0; k < HD; k++) a2 += z1[k] * wc[OFF_PW2 + k * 64 + tid];
        out[g * 64 + tid] = a2;
    }
}

extern "C" void kernel_launch(void* const* d_in, const int* in_sizes, int n_in,
                              void* d_out, int out_size, void* d_ws, size_t ws_size,
                              hipStream_t stream) {
    const int* gate_types = (const int*)d_in[0];
    const int* qubit_idx  = (const int*)d_in[1];
    const int* src        = (const int*)d_in[2];
    const int* dst        = (const int*)d_in[3];
    const int* graph_ids  = (const int*)d_in[4];
    float* out = (float*)d_out;

    const int expect[19] = {NN, NN, NE, NE, NN, 4096, 2560, 49152, 384, 384,
                            384, 128, 128, 128, 1, 16384, 128, 8192, 64};
    for (int i = 0; i < 19 && i < n_in; i++) {
        if (in_sizes[i] != expect[i]) {
            k_diag<<<(out_size + 255) / 256, 256, 0, stream>>>(out, out_size,
                                                               7777000.f + i);
            return;
        }
    }

    char* ws = (char*)d_ws;
    size_t off = 0;
    auto alloc = [&](size_t bytes) {
        void* p = ws + off;
        off = (off + bytes + 255) & ~(size_t)255;
        return p;
    };
    int*   flag    = (int*)alloc(sizeof(int));
    float* wc      = (float*)alloc(sizeof(float) * CVT_TOTAL);
    float* el      = (float*)alloc(sizeof(float) * NN * 4);
    float* er      = (float*)alloc(sizeof(float) * NN * 4);
    int*   row_ptr = (int*)alloc(sizeof(int) * (NN + 1));
    int*   deg     = (int*)alloc(sizeof(int) * NN);
    int*   cursor  = (int*)alloc(sizeof(int) * NN);
    int*   csr_src = (int*)alloc(sizeof(int) * NE);
    float* gate    = (float*)alloc(sizeof(float) * NN);
    int*   gb      = (int*)alloc(sizeof(int) * (NG + 1));
    float* zg      = (float*)alloc(sizeof(float) * NG * HD);
    bf16*  h       = (bf16*)alloc(sizeof(bf16) * NN * HD);
    bf16*  feat    = (bf16*)alloc(sizeof(bf16) * NN * HD);

    if (off > ws_size) {
        k_diag<<<(out_size + 255) / 256, 256, 0, stream>>>(
            out, out_size, (float)(ws_size >> 10));
        return;
    }

    k_detect<<<1, 256, 0, stream>>>((const u16*)d_in[7], flag);
    CvtSrc cs;
    for (int i = 0; i < 14; i++) cs.p[i] = d_in[5 + i];
    k_convert<<<128, 256, 0, stream>>>(cs, flag, wc);

    k_embed<<<(NN * HD + 255) / 256, 256, 0, stream>>>(gate_types, qubit_idx,
                                                       wc, h);
    hipMemsetAsync(deg, 0, sizeof(int) * NN, stream);
    k_count<<<(NE + 255) / 256, 256, 0, stream>>>(dst, deg);
    k_scan<<<1, 1024, 0, stream>>>(deg, row_ptr, cursor);
    k_fill<<<(NE + 255) / 256, 256, 0, stream>>>(src, dst, cursor, csr_src);

    for (int l = 0; l < NL; l++) {
        k_gemm_mfma<<<512, 256, 0, stream>>>(h, wc, feat, el, er, l);
        k_agg<<<2048, 256, 0, stream>>>(feat, el, er, row_ptr, csr_src, wc, h, l);
    }
    k_ln_gate<<<(NN + 3) / 4, 256, 0, stream>>>(h, wc, gate);
    k_gbound<<<1, 128, 0, stream>>>(graph_ids, gb);
    k_pool<<<NG, 256, 0, stream>>>(h, gate, gb, zg);
    k_mlp<<<NG, 128, 0, stream>>>(zg, wc, out);
}

// Round 5
// 502.452 us; speedup vs baseline: 1.8452x; 1.1764x over previous
//
#include <hip/hip_runtime.h>
#include <hip/hip_bf16.h>

#define NN 50000
#define NE 600000
#define NG 64
#define HD 128
#define NL 3
#define NEG 0.2f
#define MTILES 3125   // NN/16
#define PCHUNK 16     // pooling blocks per graph

typedef __hip_bfloat16 bf16;
typedef unsigned short u16;
typedef __attribute__((ext_vector_type(8))) short short8v;   // 8 bf16 (4 VGPR)
typedef __attribute__((ext_vector_type(4))) float float4v;   // MFMA acc

// converted-f32 weight region offsets (element units)
#define OFF_GE    0
#define OFF_QE    4096
#define OFF_W     6656
#define OFF_AL    55808
#define OFF_AR    56192
#define OFF_BIAS  56576
#define OFF_LNG   56960
#define OFF_LNB   57088
#define OFF_GW    57216
#define OFF_GB    57344
#define OFF_PW1   57345
#define OFF_PB1   73729
#define OFF_PW2   73857
#define OFF_PB2   82049
#define CVT_TOTAL 82113

__device__ __forceinline__ float b2f(bf16 x) { return __bfloat162float(x); }
__device__ __forceinline__ bf16 f2b(float x) { return __float2bfloat16(x); }
__device__ __forceinline__ short f2bs(float x) {
    bf16 t = __float2bfloat16(x);
    return *reinterpret_cast<short*>(&t);
}
__device__ __forceinline__ float lrelu(float x) { return x > 0.f ? x : NEG * x; }

__device__ __forceinline__ float wave_max64(float v) {
    #pragma unroll
    for (int m = 1; m < 64; m <<= 1) v = fmaxf(v, __shfl_xor(v, m, 64));
    return v;
}
__device__ __forceinline__ float wave_sum64(float v) {
    #pragma unroll
    for (int m = 1; m < 64; m <<= 1) v += __shfl_xor(v, m, 64);
    return v;
}

// ---- diagnostics ----
__global__ void k_diag(float* out, int n, float code) {
    int i = blockIdx.x * blockDim.x + threadIdx.x;
    if (i < n) out[i] = code;
}

// ---- input dtype detection (bf16 vs f32 misread) ----
__global__ void k_detect(const u16* __restrict__ w, int* __restrict__ flag) {
    __shared__ int cnt;
    if (threadIdx.x == 0) cnt = 0;
    __syncthreads();
    int bad = 0;
    for (int i = threadIdx.x; i < 2048; i += 256) {
        int e = (w[i] >> 7) & 0xFF;
        if (e == 0xFF || e >= 0x90) bad++;
    }
    atomicAdd(&cnt, bad);
    __syncthreads();
    if (threadIdx.x == 0) *flag = (cnt > 16) ? 1 : 0;
}

struct CvtSrc { const void* p[14]; };

__global__ void k_convert(CvtSrc srcs, const int* __restrict__ flag,
                          float* __restrict__ dst) {
    const bool isf32 = (*flag != 0);
    const int starts[15] = {OFF_GE, OFF_QE, OFF_W, OFF_AL, OFF_AR, OFF_BIAS,
                            OFF_LNG, OFF_LNB, OFF_GW, OFF_GB, OFF_PW1, OFF_PB1,
                            OFF_PW2, OFF_PB2, CVT_TOTAL};
    for (int i = blockIdx.x * blockDim.x + threadIdx.x; i < CVT_TOTAL;
         i += gridDim.x * blockDim.x) {
        int a = 0;
        while (i >= starts[a + 1]) a++;
        int off = i - starts[a];
        dst[i] = isf32 ? ((const float*)srcs.p[a])[off]
                       : b2f(((const bf16*)srcs.p[a])[off]);
    }
}

__global__ void k_embed(const int* __restrict__ gt, const int* __restrict__ qi,
                        const float* __restrict__ wc, bf16* __restrict__ h) {
    int idx = blockIdx.x * blockDim.x + threadIdx.x;
    if (idx >= NN * HD) return;
    int n = idx >> 7, c = idx & 127;
    h[idx] = f2b(wc[OFF_GE + gt[n] * HD + c] + wc[OFF_QE + qi[n] * HD + c]);
}

__global__ void k_count(const int* __restrict__ dst, int* __restrict__ deg) {
    int e = blockIdx.x * blockDim.x + threadIdx.x;
    if (e < NE) atomicAdd(&deg[dst[e]], 1);
}

__global__ void k_scan(const int* __restrict__ deg, int* __restrict__ row_ptr,
                       int* __restrict__ cursor) {
    __shared__ int s[1024];
    int tid = threadIdx.x;
    int running = 0;
    for (int base = 0; base < NN; base += 1024) {
        int i = base + tid;
        int x = (i < NN) ? deg[i] : 0;
        s[tid] = x;
        __syncthreads();
        for (int off = 1; off < 1024; off <<= 1) {
            int t = (tid >= off) ? s[tid - off] : 0;
            __syncthreads();
            if (tid >= off) s[tid] += t;
            __syncthreads();
        }
        int incl = s[tid];
        int tot = s[1023];
        if (i < NN) {
            int excl = running + incl - x;
            row_ptr[i] = excl;
            cursor[i] = excl;
        }
        running += tot;
        __syncthreads();
    }
    if (tid == 0) row_ptr[NN] = running;
}

__global__ void k_fill(const int* __restrict__ src, const int* __restrict__ dst,
                       int* __restrict__ cursor, int* __restrict__ csr_src) {
    int e = blockIdx.x * blockDim.x + threadIdx.x;
    if (e < NE) {
        int p = atomicAdd(&cursor[dst[e]], 1);
        csr_src[p] = src[e];
    }
}

// MFMA GEMM: feat = h @ W[l], fused el/er. Block = 4 waves; wave `wid` owns
// cols [wid*32, wid*32+32) (= head wid); grid-stride over 16-row M-tiles.
__global__ __launch_bounds__(256) void k_gemm_mfma(
        const bf16* __restrict__ h, const float* __restrict__ wc,
        bf16* __restrict__ feat, float* __restrict__ el,
        float* __restrict__ er, int l) {
    const int lane = threadIdx.x & 63, wid = threadIdx.x >> 6;
    const int r = lane & 15, q = lane >> 4;
    const int wbase = wid * 32;
    const float* Wl = wc + OFF_W + l * HD * HD;

    short8v bfr[2][4];
    #pragma unroll
    for (int t = 0; t < 2; t++)
        #pragma unroll
        for (int ks = 0; ks < 4; ks++) {
            short8v b;
            #pragma unroll
            for (int j = 0; j < 8; j++)
                b[j] = f2bs(Wl[(ks * 32 + q * 8 + j) * HD + wbase + t * 16 + r]);
            bfr[t][ks] = b;
        }

    const float al0 = wc[OFF_AL + l * HD + wbase + r];
    const float al1 = wc[OFF_AL + l * HD + wbase + 16 + r];
    const float ar0 = wc[OFF_AR + l * HD + wbase + r];
    const float ar1 = wc[OFF_AR + l * HD + wbase + 16 + r];

    for (int tile = blockIdx.x; tile < MTILES; tile += gridDim.x) {
        const int base = tile * 16;
        float4v acc0 = {0.f, 0.f, 0.f, 0.f};
        float4v acc1 = {0.f, 0.f, 0.f, 0.f};
        #pragma unroll
        for (int ks = 0; ks < 4; ks++) {
            short8v a = *reinterpret_cast<const short8v*>(
                h + (base + r) * HD + ks * 32 + q * 8);
            acc0 = __builtin_amdgcn_mfma_f32_16x16x32_bf16(a, bfr[0][ks], acc0, 0, 0, 0);
            acc1 = __builtin_amdgcn_mfma_f32_16x16x32_bf16(a, bfr[1][ks], acc1, 0, 0, 0);
        }
        #pragma unroll
        for (int reg = 0; reg < 4; reg++) {
            const int row = base + q * 4 + reg;
            feat[row * HD + wbase + r]      = f2b(acc0[reg]);
            feat[row * HD + wbase + 16 + r] = f2b(acc1[reg]);
            float elp = acc0[reg] * al0 + acc1[reg] * al1;
            float erp = acc0[reg] * ar0 + acc1[reg] * ar1;
            #pragma unroll
            for (int m = 1; m < 16; m <<= 1) {
                elp += __shfl_xor(elp, m, 64);
                erp += __shfl_xor(erp, m, 64);
            }
            if (r == 0) {
                el[row * 4 + wid] = elp;
                er[row * 4 + wid] = erp;
            }
        }
    }
}

// per-dst online softmax + aggregation; one wave per node
__global__ __launch_bounds__(256) void k_agg(
        const bf16* __restrict__ feat, const float* __restrict__ el,
        const float* __restrict__ er, const int* __restrict__ row_ptr,
        const int* __restrict__ csr_src, const float* __restrict__ wc,
        bf16* __restrict__ h, int l) {
    int lane = threadIdx.x & 63, wid = threadIdx.x >> 6;
    for (int n = blockIdx.x * 4 + wid; n < NN; n += gridDim.x * 4) {
        int rp = row_ptr[n];
        int deg = row_ptr[n + 1] - rp;
        float4 erv = *reinterpret_cast<const float4*>(er + n * 4);
        float m0 = -1e30f, m1 = -1e30f, m2 = -1e30f, m3 = -1e30f;
        float z0 = 0.f, z1 = 0.f, z2 = 0.f, z3 = 0.f;
        float acc0 = 0.f, acc1 = 0.f;
        for (int base = 0; base < deg; base += 64) {
            int e = base + lane;
            bool act = e < deg;
            int s = act ? csr_src[rp + e] : 0;
            float s0 = -1e30f, s1 = -1e30f, s2 = -1e30f, s3 = -1e30f;
            if (act) {
                float4 elv = *reinterpret_cast<const float4*>(el + s * 4);
                s0 = lrelu(elv.x + erv.x);
                s1 = lrelu(elv.y + erv.y);
                s2 = lrelu(elv.z + erv.z);
                s3 = lrelu(elv.w + erv.w);
            }
            float nm0 = fmaxf(m0, wave_max64(s0));
            float nm1 = fmaxf(m1, wave_max64(s1));
            float nm2 = fmaxf(m2, wave_max64(s2));
            float nm3 = fmaxf(m3, wave_max64(s3));
            float sc0 = __expf(m0 - nm0), sc1 = __expf(m1 - nm1);
            float sc2 = __expf(m2 - nm2), sc3 = __expf(m3 - nm3);
            float p0 = act ? __expf(s0 - nm0) : 0.f;
            float p1 = act ? __expf(s1 - nm1) : 0.f;
            float p2 = act ? __expf(s2 - nm2) : 0.f;
            float p3 = act ? __expf(s3 - nm3) : 0.f;
            z0 = z0 * sc0 + wave_sum64(p0);
            z1 = z1 * sc1 + wave_sum64(p1);
            z2 = z2 * sc2 + wave_sum64(p2);
            z3 = z3 * sc3 + wave_sum64(p3);
            float sA = (lane < 32) ? sc0 : sc1;
            float sB = (lane < 32) ? sc2 : sc3;
            acc0 *= sA;
            acc1 *= sB;
            m0 = nm0; m1 = nm1; m2 = nm2; m3 = nm3;
            int cnt = min(64, deg - base);
            for (int j = 0; j < cnt; j++) {
                int sj = __shfl(s, j, 64);
                float a0 = __shfl(p0, j, 64), a1 = __shfl(p1, j, 64);
                float a2 = __shfl(p2, j, 64), a3 = __shfl(p3, j, 64);
                float aA = (lane < 32) ? a0 : a1;
                float aB = (lane < 32) ? a2 : a3;
                const bf16* fr = feat + sj * HD;
                acc0 += aA * b2f(fr[lane]);
                acc1 += aB * b2f(fr[64 + lane]);
            }
        }
        float zA = (lane < 32) ? z0 : z1;
        float zB = (lane < 32) ? z2 : z3;
        float r0 = deg ? acc0 / zA : 0.f;
        float r1 = deg ? acc1 / zB : 0.f;
        int idx = n * HD + lane;
        float v0 = r0 + b2f(h[idx])      + wc[OFF_BIAS + l * HD + lane];
        float v1 = r1 + b2f(h[idx + 64]) + wc[OFF_BIAS + l * HD + 64 + lane];
        h[idx]      = f2b(fmaxf(v0, 0.f));
        h[idx + 64] = f2b(fmaxf(v1, 0.f));
    }
}

__global__ __launch_bounds__(256) void k_ln_gate(
        bf16* __restrict__ h, const float* __restrict__ wc,
        float* __restrict__ gate) {
    int lane = threadIdx.x & 63, wid = threadIdx.x >> 6;
    int n = blockIdx.x * 4 + wid;
    if (n >= NN) return;
    float x0 = b2f(h[n * HD + lane]), x1 = b2f(h[n * HD + 64 + lane]);
    float mu = wave_sum64(x0 + x1) * (1.0f / 128.0f);
    float d0 = x0 - mu, d1 = x1 - mu;
    float var = wave_sum64(d0 * d0 + d1 * d1) * (1.0f / 128.0f);
    float rs = rsqrtf(var + 1e-5f);
    float y0 = d0 * rs * wc[OFF_LNG + lane]      + wc[OFF_LNB + lane];
    float y1 = d1 * rs * wc[OFF_LNG + 64 + lane] + wc[OFF_LNB + 64 + lane];
    h[n * HD + lane] = f2b(y0);
    h[n * HD + 64 + lane] = f2b(y1);
    float g = wave_sum64(y0 * wc[OFF_GW + lane] + y1 * wc[OFF_GW + 64 + lane]);
    if (lane == 0) gate[n] = g + wc[OFF_GB];
}

__global__ void k_gbound(const int* __restrict__ gid, int* __restrict__ gb) {
    int g = threadIdx.x;
    if (g > NG) return;
    int lo = 0, hi = NN;
    while (lo < hi) {
        int mid = (lo + hi) >> 1;
        if (gid[mid] < g) lo = mid + 1;
        else hi = mid;
    }
    gb[g] = lo;
}

// per-graph gate max + 1/z (one block per graph; touches only gate[])
__global__ __launch_bounds__(256) void k_gmaxz(
        const float* __restrict__ gate, const int* __restrict__ gb,
        float* __restrict__ gmax, float* __restrict__ gzinv) {
    __shared__ float red[256];
    int g = blockIdx.x, tid = threadIdx.x;
    int s0 = gb[g], e0 = gb[g + 1];
    float m = -1e30f;
    for (int i = s0 + tid; i < e0; i += 256) m = fmaxf(m, gate[i]);
    red[tid] = m;
    __syncthreads();
    for (int off = 128; off; off >>= 1) {
        if (tid < off) red[tid] = fmaxf(red[tid], red[tid + off]);
        __syncthreads();
    }
    m = red[0];
    __syncthreads();
    float z = 0.f;
    for (int i = s0 + tid; i < e0; i += 256) z += __expf(gate[i] - m);
    red[tid] = z;
    __syncthreads();
    for (int off = 128; off; off >>= 1) {
        if (tid < off) red[tid] += red[tid + off];
        __syncthreads();
    }
    if (tid == 0) {
        gmax[g] = m;
        gzinv[g] = (e0 > s0 && red[0] > 0.f) ? 1.0f / red[0] : 0.f;
    }
}

// weighted node-sum, PCHUNK blocks per graph, atomicAdd into zeroed zg
__global__ __launch_bounds__(256) void k_poolsum(
        const bf16* __restrict__ h, const float* __restrict__ gate,
        const int* __restrict__ gb, const float* __restrict__ gmax,
        float* __restrict__ zg) {
    __shared__ float red[256];
    int b = blockIdx.x;
    int g = b / PCHUNK, c = b % PCHUNK;
    int s0 = gb[g], e0 = gb[g + 1];
    int len = e0 - s0;
    int beg = s0 + (int)(((long long)len * c) / PCHUNK);
    int end = s0 + (int)(((long long)len * (c + 1)) / PCHUNK);
    int ch = threadIdx.x & 127, half = threadIdx.x >> 7;
    float m = gmax[g];
    float acc = 0.f;
    for (int i = beg + half; i < end; i += 2)
        acc += __expf(gate[i] - m) * b2f(h[i * HD + ch]);
    red[threadIdx.x] = acc;
    __syncthreads();
    if (threadIdx.x < 128) {
        float v = red[threadIdx.x] + red[threadIdx.x + 128];
        if (v != 0.f) atomicAdd(&zg[g * HD + ch], v);
    }
}

__global__ __launch_bounds__(128) void k_mlp(
        const float* __restrict__ zg, const float* __restrict__ gzinv,
        const float* __restrict__ wc, float* __restrict__ out) {
    __shared__ float zr[HD], z1[HD];
    int g = blockIdx.x, tid = threadIdx.x;
    zr[tid] = zg[g * HD + tid] * gzinv[g];
    __syncthreads();
    float acc = wc[OFF_PB1 + tid];
    for (int k = 0; k < HD; k++) acc += zr[k] * wc[OFF_PW1 + k * HD + tid];
    z1[tid] = fmaxf(acc, 0.f);
    __syncthreads();
    if (tid < 64) {
        float a2 = wc[OFF_PB2 + tid];
        for (int k = 0; k < HD; k++) a2 += z1[k] * wc[OFF_PW2 + k * 64 + tid];
        out[g * 64 + tid] = a2;
    }
}

extern "C" void kernel_launch(void* const* d_in, const int* in_sizes, int n_in,
                              void* d_out, int out_size, void* d_ws, size_t ws_size,
                              hipStream_t stream) {
    const int* gate_types = (const int*)d_in[0];
    const int* qubit_idx  = (const int*)d_in[1];
    const int* src        = (const int*)d_in[2];
    const int* dst        = (const int*)d_in[3];
    const int* graph_ids  = (const int*)d_in[4];
    float* out = (float*)d_out;

    const int expect[19] = {NN, NN, NE, NE, NN, 4096, 2560, 49152, 384, 384,
                            384, 128, 128, 128, 1, 16384, 128, 8192, 64};
    for (int i = 0; i < 19 && i < n_in; i++) {
        if (in_sizes[i] != expect[i]) {
            k_diag<<<(out_size + 255) / 256, 256, 0, stream>>>(out, out_size,
                                                               7777000.f + i);
            return;
        }
    }

    char* ws = (char*)d_ws;
    size_t off = 0;
    auto alloc = [&](size_t bytes) {
        void* p = ws + off;
        off = (off + bytes + 255) & ~(size_t)255;
        return p;
    };
    int*   flag    = (int*)alloc(sizeof(int));
    float* wc      = (float*)alloc(sizeof(float) * CVT_TOTAL);
    float* el      = (float*)alloc(sizeof(float) * NN * 4);
    float* er      = (float*)alloc(sizeof(float) * NN * 4);
    int*   row_ptr = (int*)alloc(sizeof(int) * (NN + 1));
    int*   deg     = (int*)alloc(sizeof(int) * NN);
    int*   cursor  = (int*)alloc(sizeof(int) * NN);
    int*   csr_src = (int*)alloc(sizeof(int) * NE);
    float* gate    = (float*)alloc(sizeof(float) * NN);
    int*   gb      = (int*)alloc(sizeof(int) * (NG + 1));
    float* zg      = (float*)alloc(sizeof(float) * NG * HD);
    float* gmax    = (float*)alloc(sizeof(float) * NG);
    float* gzinv   = (float*)alloc(sizeof(float) * NG);
    bf16*  h       = (bf16*)alloc(sizeof(bf16) * NN * HD);
    bf16*  feat    = (bf16*)alloc(sizeof(bf16) * NN * HD);

    if (off > ws_size) {
        k_diag<<<(out_size + 255) / 256, 256, 0, stream>>>(
            out, out_size, (float)(ws_size >> 10));
        return;
    }

    k_detect<<<1, 256, 0, stream>>>((const u16*)d_in[7], flag);
    CvtSrc cs;
    for (int i = 0; i < 14; i++) cs.p[i] = d_in[5 + i];
    k_convert<<<128, 256, 0, stream>>>(cs, flag, wc);

    k_embed<<<(NN * HD + 255) / 256, 256, 0, stream>>>(gate_types, qubit_idx,
                                                       wc, h);
    hipMemsetAsync(deg, 0, sizeof(int) * NN, stream);
    k_count<<<(NE + 255) / 256, 256, 0, stream>>>(dst, deg);
    k_scan<<<1, 1024, 0, stream>>>(deg, row_ptr, cursor);
    k_fill<<<(NE + 255) / 256, 256, 0, stream>>>(src, dst, cursor, csr_src);

    for (int l = 0; l < NL; l++) {
        k_gemm_mfma<<<512, 256, 0, stream>>>(h, wc, feat, el, er, l);
        k_agg<<<2048, 256, 0, stream>>>(feat, el, er, row_ptr, csr_src, wc, h, l);
    }
    k_ln_gate<<<(NN + 3) / 4, 256, 0, stream>>>(h, wc, gate);
    k_gbound<<<1, 128, 0, stream>>>(graph_ids, gb);
    k_gmaxz<<<NG, 256, 0, stream>>>(gate, gb, gmax, gzinv);
    hipMemsetAsync(zg, 0, sizeof(float) * NG * HD, stream);
    k_poolsum<<<NG * PCHUNK, 256, 0, stream>>>(h, gate, gb, gmax, zg);
    k_mlp<<<NG, 128, 0, stream>>>(zg, gzinv, wc, out);
}

// Round 6
// 418.204 us; speedup vs baseline: 2.2169x; 1.2015x over previous
//
#include <hip/hip_runtime.h>
#include <hip/hip_bf16.h>

#define NN 50000
#define NE 600000
#define NG 64
#define HD 128
#define NL 3
#define NEG 0.2f
#define MTILES 3125   // NN/16
#define PCHUNK 16     // pooling blocks per graph
#define SBLK 256
#define NSB ((NN + SBLK - 1) / SBLK)   // 196 scan blocks

typedef __hip_bfloat16 bf16;
typedef unsigned short u16;
typedef __attribute__((ext_vector_type(8))) short short8v;   // 8 bf16 (4 VGPR)
typedef __attribute__((ext_vector_type(4))) float float4v;   // MFMA acc

// converted-f32 weight region offsets (element units)
#define OFF_GE    0
#define OFF_QE    4096
#define OFF_W     6656
#define OFF_AL    55808
#define OFF_AR    56192
#define OFF_BIAS  56576
#define OFF_LNG   56960
#define OFF_LNB   57088
#define OFF_GW    57216
#define OFF_GB    57344
#define OFF_PW1   57345
#define OFF_PB1   73729
#define OFF_PW2   73857
#define OFF_PB2   82049
#define CVT_TOTAL 82113

__device__ __forceinline__ float b2f(bf16 x) { return __bfloat162float(x); }
__device__ __forceinline__ bf16 f2b(float x) { return __float2bfloat16(x); }
__device__ __forceinline__ short f2bs(float x) {
    bf16 t = __float2bfloat16(x);
    return *reinterpret_cast<short*>(&t);
}
__device__ __forceinline__ float lrelu(float x) { return x > 0.f ? x : NEG * x; }

__device__ __forceinline__ float wave_max64(float v) {
    #pragma unroll
    for (int m = 1; m < 64; m <<= 1) v = fmaxf(v, __shfl_xor(v, m, 64));
    return v;
}
__device__ __forceinline__ float wave_sum64(float v) {
    #pragma unroll
    for (int m = 1; m < 64; m <<= 1) v += __shfl_xor(v, m, 64);
    return v;
}

// ---- diagnostics ----
__global__ void k_diag(float* out, int n, float code) {
    int i = blockIdx.x * blockDim.x + threadIdx.x;
    if (i < n) out[i] = code;
}

// ---- input dtype detection (bf16 vs f32 misread) ----
__global__ void k_detect(const u16* __restrict__ w, int* __restrict__ flag) {
    __shared__ int cnt;
    if (threadIdx.x == 0) cnt = 0;
    __syncthreads();
    int bad = 0;
    for (int i = threadIdx.x; i < 2048; i += 256) {
        int e = (w[i] >> 7) & 0xFF;
        if (e == 0xFF || e >= 0x90) bad++;
    }
    atomicAdd(&cnt, bad);
    __syncthreads();
    if (threadIdx.x == 0) *flag = (cnt > 16) ? 1 : 0;
}

struct CvtSrc { const void* p[14]; };

__global__ void k_convert(CvtSrc srcs, const int* __restrict__ flag,
                          float* __restrict__ dst) {
    const bool isf32 = (*flag != 0);
    const int starts[15] = {OFF_GE, OFF_QE, OFF_W, OFF_AL, OFF_AR, OFF_BIAS,
                            OFF_LNG, OFF_LNB, OFF_GW, OFF_GB, OFF_PW1, OFF_PB1,
                            OFF_PW2, OFF_PB2, CVT_TOTAL};
    for (int i = blockIdx.x * blockDim.x + threadIdx.x; i < CVT_TOTAL;
         i += gridDim.x * blockDim.x) {
        int a = 0;
        while (i >= starts[a + 1]) a++;
        int off = i - starts[a];
        dst[i] = isf32 ? ((const float*)srcs.p[a])[off]
                       : b2f(((const bf16*)srcs.p[a])[off]);
    }
}

__global__ void k_embed(const int* __restrict__ gt, const int* __restrict__ qi,
                        const float* __restrict__ wc, bf16* __restrict__ h) {
    int idx = blockIdx.x * blockDim.x + threadIdx.x;
    if (idx >= NN * HD) return;
    int n = idx >> 7, c = idx & 127;
    h[idx] = f2b(wc[OFF_GE + gt[n] * HD + c] + wc[OFF_QE + qi[n] * HD + c]);
}

__global__ void k_count(const int* __restrict__ dst, int* __restrict__ deg) {
    int e = blockIdx.x * blockDim.x + threadIdx.x;
    if (e < NE) atomicAdd(&deg[dst[e]], 1);
}

// ---- 3-phase multi-block exclusive scan of deg -> row_ptr/cursor ----
__global__ __launch_bounds__(SBLK) void k_bsum(const int* __restrict__ deg,
                                               int* __restrict__ bsum) {
    __shared__ int red[SBLK];
    int i = blockIdx.x * SBLK + threadIdx.x;
    red[threadIdx.x] = (i < NN) ? deg[i] : 0;
    __syncthreads();
    for (int off = SBLK / 2; off; off >>= 1) {
        if (threadIdx.x < off) red[threadIdx.x] += red[threadIdx.x + off];
        __syncthreads();
    }
    if (threadIdx.x == 0) bsum[blockIdx.x] = red[0];
}

__global__ __launch_bounds__(SBLK) void k_bscan(const int* __restrict__ bsum,
                                                int* __restrict__ boff,
                                                int* __restrict__ row_ptr) {
    __shared__ int s[SBLK];
    int t = threadIdx.x;
    int x = (t < NSB) ? bsum[t] : 0;
    s[t] = x;
    __syncthreads();
    #pragma unroll
    for (int off = 1; off < SBLK; off <<= 1) {
        int v = (t >= off) ? s[t - off] : 0;
        __syncthreads();
        if (t >= off) s[t] += v;
        __syncthreads();
    }
    if (t < NSB) boff[t] = s[t] - x;          // exclusive
    if (t == 0) row_ptr[NN] = s[SBLK - 1];    // total (= NE)
}

__global__ __launch_bounds__(SBLK) void k_locscan(const int* __restrict__ deg,
                                                  const int* __restrict__ boff,
                                                  int* __restrict__ row_ptr,
                                                  int* __restrict__ cursor) {
    __shared__ int s[SBLK];
    int t = threadIdx.x;
    int i = blockIdx.x * SBLK + t;
    int x = (i < NN) ? deg[i] : 0;
    s[t] = x;
    __syncthreads();
    #pragma unroll
    for (int off = 1; off < SBLK; off <<= 1) {
        int v = (t >= off) ? s[t - off] : 0;
        __syncthreads();
        if (t >= off) s[t] += v;
        __syncthreads();
    }
    if (i < NN) {
        int excl = boff[blockIdx.x] + s[t] - x;
        row_ptr[i] = excl;
        cursor[i] = excl;
    }
}

__global__ void k_fill(const int* __restrict__ src, const int* __restrict__ dst,
                       int* __restrict__ cursor, int* __restrict__ csr_src) {
    int e = blockIdx.x * blockDim.x + threadIdx.x;
    if (e < NE) {
        int p = atomicAdd(&cursor[dst[e]], 1);
        csr_src[p] = src[e];
    }
}

// MFMA GEMM: feat = h @ W[l], fused el/er. Block = 4 waves; wave `wid` owns
// cols [wid*32, wid*32+32) (= head wid); grid-stride over 16-row M-tiles.
__global__ __launch_bounds__(256) void k_gemm_mfma(
        const bf16* __restrict__ h, const float* __restrict__ wc,
        bf16* __restrict__ feat, float* __restrict__ el,
        float* __restrict__ er, int l) {
    const int lane = threadIdx.x & 63, wid = threadIdx.x >> 6;
    const int r = lane & 15, q = lane >> 4;
    const int wbase = wid * 32;
    const float* Wl = wc + OFF_W + l * HD * HD;

    short8v bfr[2][4];
    #pragma unroll
    for (int t = 0; t < 2; t++)
        #pragma unroll
        for (int ks = 0; ks < 4; ks++) {
            short8v b;
            #pragma unroll
            for (int j = 0; j < 8; j++)
                b[j] = f2bs(Wl[(ks * 32 + q * 8 + j) * HD + wbase + t * 16 + r]);
            bfr[t][ks] = b;
        }

    const float al0 = wc[OFF_AL + l * HD + wbase + r];
    const float al1 = wc[OFF_AL + l * HD + wbase + 16 + r];
    const float ar0 = wc[OFF_AR + l * HD + wbase + r];
    const float ar1 = wc[OFF_AR + l * HD + wbase + 16 + r];

    for (int tile = blockIdx.x; tile < MTILES; tile += gridDim.x) {
        const int base = tile * 16;
        float4v acc0 = {0.f, 0.f, 0.f, 0.f};
        float4v acc1 = {0.f, 0.f, 0.f, 0.f};
        #pragma unroll
        for (int ks = 0; ks < 4; ks++) {
            short8v a = *reinterpret_cast<const short8v*>(
                h + (base + r) * HD + ks * 32 + q * 8);
            acc0 = __builtin_amdgcn_mfma_f32_16x16x32_bf16(a, bfr[0][ks], acc0, 0, 0, 0);
            acc1 = __builtin_amdgcn_mfma_f32_16x16x32_bf16(a, bfr[1][ks], acc1, 0, 0, 0);
        }
        #pragma unroll
        for (int reg = 0; reg < 4; reg++) {
            const int row = base + q * 4 + reg;
            feat[row * HD + wbase + r]      = f2b(acc0[reg]);
            feat[row * HD + wbase + 16 + r] = f2b(acc1[reg]);
            float elp = acc0[reg] * al0 + acc1[reg] * al1;
            float erp = acc0[reg] * ar0 + acc1[reg] * ar1;
            #pragma unroll
            for (int m = 1; m < 16; m <<= 1) {
                elp += __shfl_xor(elp, m, 64);
                erp += __shfl_xor(erp, m, 64);
            }
            if (r == 0) {
                el[row * 4 + wid] = elp;
                er[row * 4 + wid] = erp;
            }
        }
    }
}

// per-dst online softmax + aggregation; one wave per node
__global__ __launch_bounds__(256) void k_agg(
        const bf16* __restrict__ feat, const float* __restrict__ el,
        const float* __restrict__ er, const int* __restrict__ row_ptr,
        const int* __restrict__ csr_src, const float* __restrict__ wc,
        bf16* __restrict__ h, int l) {
    int lane = threadIdx.x & 63, wid = threadIdx.x >> 6;
    for (int n = blockIdx.x * 4 + wid; n < NN; n += gridDim.x * 4) {
        int rp = row_ptr[n];
        int deg = row_ptr[n + 1] - rp;
        float4 erv = *reinterpret_cast<const float4*>(er + n * 4);
        float m0 = -1e30f, m1 = -1e30f, m2 = -1e30f, m3 = -1e30f;
        float z0 = 0.f, z1 = 0.f, z2 = 0.f, z3 = 0.f;
        float acc0 = 0.f, acc1 = 0.f;
        for (int base = 0; base < deg; base += 64) {
            int e = base + lane;
            bool act = e < deg;
            int s = act ? csr_src[rp + e] : 0;
            float s0 = -1e30f, s1 = -1e30f, s2 = -1e30f, s3 = -1e30f;
            if (act) {
                float4 elv = *reinterpret_cast<const float4*>(el + s * 4);
                s0 = lrelu(elv.x + erv.x);
                s1 = lrelu(elv.y + erv.y);
                s2 = lrelu(elv.z + erv.z);
                s3 = lrelu(elv.w + erv.w);
            }
            float nm0 = fmaxf(m0, wave_max64(s0));
            float nm1 = fmaxf(m1, wave_max64(s1));
            float nm2 = fmaxf(m2, wave_max64(s2));
            float nm3 = fmaxf(m3, wave_max64(s3));
            float sc0 = __expf(m0 - nm0), sc1 = __expf(m1 - nm1);
            float sc2 = __expf(m2 - nm2), sc3 = __expf(m3 - nm3);
            float p0 = act ? __expf(s0 - nm0) : 0.f;
            float p1 = act ? __expf(s1 - nm1) : 0.f;
            float p2 = act ? __expf(s2 - nm2) : 0.f;
            float p3 = act ? __expf(s3 - nm3) : 0.f;
            z0 = z0 * sc0 + wave_sum64(p0);
            z1 = z1 * sc1 + wave_sum64(p1);
            z2 = z2 * sc2 + wave_sum64(p2);
            z3 = z3 * sc3 + wave_sum64(p3);
            float sA = (lane < 32) ? sc0 : sc1;
            float sB = (lane < 32) ? sc2 : sc3;
            acc0 *= sA;
            acc1 *= sB;
            m0 = nm0; m1 = nm1; m2 = nm2; m3 = nm3;
            int cnt = min(64, deg - base);
            for (int j = 0; j < cnt; j++) {
                int sj = __shfl(s, j, 64);
                float a0 = __shfl(p0, j, 64), a1 = __shfl(p1, j, 64);
                float a2 = __shfl(p2, j, 64), a3 = __shfl(p3, j, 64);
                float aA = (lane < 32) ? a0 : a1;
                float aB = (lane < 32) ? a2 : a3;
                const bf16* fr = feat + sj * HD;
                acc0 += aA * b2f(fr[lane]);
                acc1 += aB * b2f(fr[64 + lane]);
            }
        }
        float zA = (lane < 32) ? z0 : z1;
        float zB = (lane < 32) ? z2 : z3;
        float r0 = deg ? acc0 / zA : 0.f;
        float r1 = deg ? acc1 / zB : 0.f;
        int idx = n * HD + lane;
        float v0 = r0 + b2f(h[idx])      + wc[OFF_BIAS + l * HD + lane];
        float v1 = r1 + b2f(h[idx + 64]) + wc[OFF_BIAS + l * HD + 64 + lane];
        h[idx]      = f2b(fmaxf(v0, 0.f));
        h[idx + 64] = f2b(fmaxf(v1, 0.f));
    }
}

__global__ __launch_bounds__(256) void k_ln_gate(
        bf16* __restrict__ h, const float* __restrict__ wc,
        float* __restrict__ gate) {
    int lane = threadIdx.x & 63, wid = threadIdx.x >> 6;
    int n = blockIdx.x * 4 + wid;
    if (n >= NN) return;
    float x0 = b2f(h[n * HD + lane]), x1 = b2f(h[n * HD + 64 + lane]);
    float mu = wave_sum64(x0 + x1) * (1.0f / 128.0f);
    float d0 = x0 - mu, d1 = x1 - mu;
    float var = wave_sum64(d0 * d0 + d1 * d1) * (1.0f / 128.0f);
    float rs = rsqrtf(var + 1e-5f);
    float y0 = d0 * rs * wc[OFF_LNG + lane]      + wc[OFF_LNB + lane];
    float y1 = d1 * rs * wc[OFF_LNG + 64 + lane] + wc[OFF_LNB + 64 + lane];
    h[n * HD + lane] = f2b(y0);
    h[n * HD + 64 + lane] = f2b(y1);
    float g = wave_sum64(y0 * wc[OFF_GW + lane] + y1 * wc[OFF_GW + 64 + lane]);
    if (lane == 0) gate[n] = g + wc[OFF_GB];
}

__global__ void k_gbound(const int* __restrict__ gid, int* __restrict__ gb) {
    int g = threadIdx.x;
    if (g > NG) return;
    int lo = 0, hi = NN;
    while (lo < hi) {
        int mid = (lo + hi) >> 1;
        if (gid[mid] < g) lo = mid + 1;
        else hi = mid;
    }
    gb[g] = lo;
}

// per-graph gate max + 1/z (one block per graph; touches only gate[])
__global__ __launch_bounds__(256) void k_gmaxz(
        const float* __restrict__ gate, const int* __restrict__ gb,
        float* __restrict__ gmax, float* __restrict__ gzinv) {
    __shared__ float red[256];
    int g = blockIdx.x, tid = threadIdx.x;
    int s0 = gb[g], e0 = gb[g + 1];
    float m = -1e30f;
    for (int i = s0 + tid; i < e0; i += 256) m = fmaxf(m, gate[i]);
    red[tid] = m;
    __syncthreads();
    for (int off = 128; off; off >>= 1) {
        if (tid < off) red[tid] = fmaxf(red[tid], red[tid + off]);
        __syncthreads();
    }
    m = red[0];
    __syncthreads();
    float z = 0.f;
    for (int i = s0 + tid; i < e0; i += 256) z += __expf(gate[i] - m);
    red[tid] = z;
    __syncthreads();
    for (int off = 128; off; off >>= 1) {
        if (tid < off) red[tid] += red[tid + off];
        __syncthreads();
    }
    if (tid == 0) {
        gmax[g] = m;
        gzinv[g] = (e0 > s0 && red[0] > 0.f) ? 1.0f / red[0] : 0.f;
    }
}

// weighted node-sum, PCHUNK blocks per graph, atomicAdd into zeroed zg
__global__ __launch_bounds__(256) void k_poolsum(
        const bf16* __restrict__ h, const float* __restrict__ gate,
        const int* __restrict__ gb, const float* __restrict__ gmax,
        float* __restrict__ zg) {
    __shared__ float red[256];
    int b = blockIdx.x;
    int g = b / PCHUNK, c = b % PCHUNK;
    int s0 = gb[g], e0 = gb[g + 1];
    int len = e0 - s0;
    int beg = s0 + (int)(((long long)len * c) / PCHUNK);
    int end = s0 + (int)(((long long)len * (c + 1)) / PCHUNK);
    int ch = threadIdx.x & 127, half = threadIdx.x >> 7;
    float m = gmax[g];
    float acc = 0.f;
    for (int i = beg + half; i < end; i += 2)
        acc += __expf(gate[i] - m) * b2f(h[i * HD + ch]);
    red[threadIdx.x] = acc;
    __syncthreads();
    if (threadIdx.x < 128) {
        float v = red[threadIdx.x] + red[threadIdx.x + 128];
        if (v != 0.f) atomicAdd(&zg[g * HD + ch], v);
    }
}

__global__ __launch_bounds__(128) void k_mlp(
        const float* __restrict__ zg, const float* __restrict__ gzinv,
        const float* __restrict__ wc, float* __restrict__ out) {
    __shared__ float zr[HD], z1[HD];
    int g = blockIdx.x, tid = threadIdx.x;
    zr[tid] = zg[g * HD + tid] * gzinv[g];
    __syncthreads();
    float acc = wc[OFF_PB1 + tid];
    for (int k = 0; k < HD; k++) acc += zr[k] * wc[OFF_PW1 + k * HD + tid];
    z1[tid] = fmaxf(acc, 0.f);
    __syncthreads();
    if (tid < 64) {
        float a2 = wc[OFF_PB2 + tid];
        for (int k = 0; k < HD; k++) a2 += z1[k] * wc[OFF_PW2 + k * 64 + tid];
        out[g * 64 + tid] = a2;
    }
}

extern "C" void kernel_launch(void* const* d_in, const int* in_sizes, int n_in,
                              void* d_out, int out_size, void* d_ws, size_t ws_size,
                              hipStream_t stream) {
    const int* gate_types = (const int*)d_in[0];
    const int* qubit_idx  = (const int*)d_in[1];
    const int* src        = (const int*)d_in[2];
    const int* dst        = (const int*)d_in[3];
    const int* graph_ids  = (const int*)d_in[4];
    float* out = (float*)d_out;

    const int expect[19] = {NN, NN, NE, NE, NN, 4096, 2560, 49152, 384, 384,
                            384, 128, 128, 128, 1, 16384, 128, 8192, 64};
    for (int i = 0; i < 19 && i < n_in; i++) {
        if (in_sizes[i] != expect[i]) {
            k_diag<<<(out_size + 255) / 256, 256, 0, stream>>>(out, out_size,
                                                               7777000.f + i);
            return;
        }
    }

    char* ws = (char*)d_ws;
    size_t off = 0;
    auto alloc = [&](size_t bytes) {
        void* p = ws + off;
        off = (off + bytes + 255) & ~(size_t)255;
        return p;
    };
    int*   flag    = (int*)alloc(sizeof(int));
    float* wc      = (float*)alloc(sizeof(float) * CVT_TOTAL);
    float* el      = (float*)alloc(sizeof(float) * NN * 4);
    float* er      = (float*)alloc(sizeof(float) * NN * 4);
    int*   row_ptr = (int*)alloc(sizeof(int) * (NN + 1));
    int*   deg     = (int*)alloc(sizeof(int) * NN);
    int*   cursor  = (int*)alloc(sizeof(int) * NN);
    int*   csr_src = (int*)alloc(sizeof(int) * NE);
    int*   bsum    = (int*)alloc(sizeof(int) * NSB);
    int*   boff    = (int*)alloc(sizeof(int) * NSB);
    float* gate    = (float*)alloc(sizeof(float) * NN);
    int*   gb      = (int*)alloc(sizeof(int) * (NG + 1));
    float* zg      = (float*)alloc(sizeof(float) * NG * HD);
    float* gmax    = (float*)alloc(sizeof(float) * NG);
    float* gzinv   = (float*)alloc(sizeof(float) * NG);
    bf16*  h       = (bf16*)alloc(sizeof(bf16) * NN * HD);
    bf16*  feat    = (bf16*)alloc(sizeof(bf16) * NN * HD);

    if (off > ws_size) {
        k_diag<<<(out_size + 255) / 256, 256, 0, stream>>>(
            out, out_size, (float)(ws_size >> 10));
        return;
    }

    k_detect<<<1, 256, 0, stream>>>((const u16*)d_in[7], flag);
    CvtSrc cs;
    for (int i = 0; i < 14; i++) cs.p[i] = d_in[5 + i];
    k_convert<<<128, 256, 0, stream>>>(cs, flag, wc);

    k_embed<<<(NN * HD + 255) / 256, 256, 0, stream>>>(gate_types, qubit_idx,
                                                       wc, h);
    hipMemsetAsync(deg, 0, sizeof(int) * NN, stream);
    k_count<<<(NE + 255) / 256, 256, 0, stream>>>(dst, deg);
    k_bsum<<<NSB, SBLK, 0, stream>>>(deg, bsum);
    k_bscan<<<1, SBLK, 0, stream>>>(bsum, boff, row_ptr);
    k_locscan<<<NSB, SBLK, 0, stream>>>(deg, boff, row_ptr, cursor);
    k_fill<<<(NE + 255) / 256, 256, 0, stream>>>(src, dst, cursor, csr_src);

    for (int l = 0; l < NL; l++) {
        k_gemm_mfma<<<512, 256, 0, stream>>>(h, wc, feat, el, er, l);
        k_agg<<<2048, 256, 0, stream>>>(feat, el, er, row_ptr, csr_src, wc, h, l);
    }
    k_ln_gate<<<(NN + 3) / 4, 256, 0, stream>>>(h, wc, gate);
    k_gbound<<<1, 128, 0, stream>>>(graph_ids, gb);
    k_gmaxz<<<NG, 256, 0, stream>>>(gate, gb, gmax, gzinv);
    hipMemsetAsync(zg, 0, sizeof(float) * NG * HD, stream);
    k_poolsum<<<NG * PCHUNK, 256, 0, stream>>>(h, gate, gb, gmax, zg);
    k_mlp<<<NG, 128, 0, stream>>>(zg, gzinv, wc, out);
}

// Round 8
// 340.520 us; speedup vs baseline: 2.7227x; 1.2281x over previous
//
#include <hip/hip_runtime.h>
#include <hip/hip_bf16.h>

#define NN 50000
#define NE 600000
#define NG 64
#define HD 128
#define NL 3
#define NEG 0.2f
#define MTILES 3125   // NN/16
#define PCHUNK 16     // pooling blocks per graph
#define SBLK 256
#define NSB ((NN + SBLK - 1) / SBLK)   // 196 scan blocks

typedef __hip_bfloat16 bf16;
typedef unsigned short u16;
typedef unsigned int u32;
typedef __attribute__((ext_vector_type(8))) short short8v;      // 8 bf16
typedef __attribute__((ext_vector_type(4))) float float4v;      // MFMA acc
typedef __attribute__((ext_vector_type(4))) _Float16 half4v;    // 4 f16 = 8B

// converted-f32 weight region offsets (element units)
#define OFF_GE    0
#define OFF_QE    4096
#define OFF_W     6656
#define OFF_AL    55808
#define OFF_AR    56192
#define OFF_BIAS  56576
#define OFF_LNG   56960
#define OFF_LNB   57088
#define OFF_GW    57216
#define OFF_GB    57344
#define OFF_PW1   57345
#define OFF_PB1   73729
#define OFF_PW2   73857
#define OFF_PB2   82049
#define CVT_TOTAL 82113

__device__ __forceinline__ float b2f(bf16 x) { return __bfloat162float(x); }
__device__ __forceinline__ bf16 f2b(float x) { return __float2bfloat16(x); }
__device__ __forceinline__ short f2bs(float x) {
    bf16 t = __float2bfloat16(x);
    return *reinterpret_cast<short*>(&t);
}
__device__ __forceinline__ float lrelu(float x) { return x > 0.f ? x : NEG * x; }
__device__ __forceinline__ float bf16lo(u32 u) { return __uint_as_float(u << 16); }
__device__ __forceinline__ float bf16hi(u32 u) { return __uint_as_float(u & 0xffff0000u); }
__device__ __forceinline__ u32 packbf16(float x, float y) {
    bf16 bx = f2b(x), by = f2b(y);
    u16 ux = *reinterpret_cast<u16*>(&bx);
    u16 uy = *reinterpret_cast<u16*>(&by);
    return (u32)ux | ((u32)uy << 16);
}

__device__ __forceinline__ float wave_sum64(float v) {
    #pragma unroll
    for (int m = 1; m < 64; m <<= 1) v += __shfl_xor(v, m, 64);
    return v;
}

// ---- diagnostics ----
__global__ void k_diag(float* out, int n, float code) {
    int i = blockIdx.x * blockDim.x + threadIdx.x;
    if (i < n) out[i] = code;
}

// ---- input dtype detection (bf16 vs f32 misread) ----
__global__ void k_detect(const u16* __restrict__ w, int* __restrict__ flag) {
    __shared__ int cnt;
    if (threadIdx.x == 0) cnt = 0;
    __syncthreads();
    int bad = 0;
    for (int i = threadIdx.x; i < 2048; i += 256) {
        int e = (w[i] >> 7) & 0xFF;
        if (e == 0xFF || e >= 0x90) bad++;
    }
    atomicAdd(&cnt, bad);
    __syncthreads();
    if (threadIdx.x == 0) *flag = (cnt > 16) ? 1 : 0;
}

struct CvtSrc { const void* p[14]; };

__global__ void k_convert(CvtSrc srcs, const int* __restrict__ flag,
                          float* __restrict__ dst) {
    const bool isf32 = (*flag != 0);
    const int starts[15] = {OFF_GE, OFF_QE, OFF_W, OFF_AL, OFF_AR, OFF_BIAS,
                            OFF_LNG, OFF_LNB, OFF_GW, OFF_GB, OFF_PW1, OFF_PB1,
                            OFF_PW2, OFF_PB2, CVT_TOTAL};
    for (int i = blockIdx.x * blockDim.x + threadIdx.x; i < CVT_TOTAL;
         i += gridDim.x * blockDim.x) {
        int a = 0;
        while (i >= starts[a + 1]) a++;
        int off = i - starts[a];
        dst[i] = isf32 ? ((const float*)srcs.p[a])[off]
                       : b2f(((const bf16*)srcs.p[a])[off]);
    }
}

__global__ void k_embed(const int* __restrict__ gt, const int* __restrict__ qi,
                        const float* __restrict__ wc, bf16* __restrict__ h) {
    int idx = blockIdx.x * blockDim.x + threadIdx.x;
    if (idx >= NN * HD) return;
    int n = idx >> 7, c = idx & 127;
    h[idx] = f2b(wc[OFF_GE + gt[n] * HD + c] + wc[OFF_QE + qi[n] * HD + c]);
}

__global__ void k_count(const int* __restrict__ dst, int* __restrict__ deg) {
    int e = blockIdx.x * blockDim.x + threadIdx.x;
    if (e < NE) atomicAdd(&deg[dst[e]], 1);
}

// ---- 3-phase multi-block exclusive scan of deg -> row_ptr/cursor ----
__global__ __launch_bounds__(SBLK) void k_bsum(const int* __restrict__ deg,
                                               int* __restrict__ bsum) {
    __shared__ int red[SBLK];
    int i = blockIdx.x * SBLK + threadIdx.x;
    red[threadIdx.x] = (i < NN) ? deg[i] : 0;
    __syncthreads();
    for (int off = SBLK / 2; off; off >>= 1) {
        if (threadIdx.x < off) red[threadIdx.x] += red[threadIdx.x + off];
        __syncthreads();
    }
    if (threadIdx.x == 0) bsum[blockIdx.x] = red[0];
}

__global__ __launch_bounds__(SBLK) void k_bscan(const int* __restrict__ bsum,
                                                int* __restrict__ boff,
                                                int* __restrict__ row_ptr) {
    __shared__ int s[SBLK];
    int t = threadIdx.x;
    int x = (t < NSB) ? bsum[t] : 0;
    s[t] = x;
    __syncthreads();
    #pragma unroll
    for (int off = 1; off < SBLK; off <<= 1) {
        int v = (t >= off) ? s[t - off] : 0;
        __syncthreads();
        if (t >= off) s[t] += v;
        __syncthreads();
    }
    if (t < NSB) boff[t] = s[t] - x;          // exclusive
    if (t == 0) row_ptr[NN] = s[SBLK - 1];    // total (= NE)
}

__global__ __launch_bounds__(SBLK) void k_locscan(const int* __restrict__ deg,
                                                  const int* __restrict__ boff,
                                                  int* __restrict__ row_ptr,
                                                  int* __restrict__ cursor) {
    __shared__ int s[SBLK];
    int t = threadIdx.x;
    int i = blockIdx.x * SBLK + t;
    int x = (i < NN) ? deg[i] : 0;
    s[t] = x;
    __syncthreads();
    #pragma unroll
    for (int off = 1; off < SBLK; off <<= 1) {
        int v = (t >= off) ? s[t - off] : 0;
        __syncthreads();
        if (t >= off) s[t] += v;
        __syncthreads();
    }
    if (i < NN) {
        int excl = boff[blockIdx.x] + s[t] - x;
        row_ptr[i] = excl;
        cursor[i] = excl;
    }
}

__global__ void k_fill(const int* __restrict__ src, const int* __restrict__ dst,
                       int* __restrict__ cursor, int* __restrict__ csr_src) {
    int e = blockIdx.x * blockDim.x + threadIdx.x;
    if (e < NE) {
        int p = atomicAdd(&cursor[dst[e]], 1);
        csr_src[p] = src[e];
    }
}

// MFMA GEMM: feat = h @ W[l], fused el/er. Block = 4 waves; wave `wid` owns
// cols [wid*32, wid*32+32) (= head wid); grid-stride over 16-row M-tiles.
__global__ __launch_bounds__(256) void k_gemm_mfma(
        const bf16* __restrict__ h, const float* __restrict__ wc,
        bf16* __restrict__ feat, float* __restrict__ el,
        float* __restrict__ er, int l) {
    const int lane = threadIdx.x & 63, wid = threadIdx.x >> 6;
    const int r = lane & 15, q = lane >> 4;
    const int wbase = wid * 32;
    const float* Wl = wc + OFF_W + l * HD * HD;

    short8v bfr[2][4];
    #pragma unroll
    for (int t = 0; t < 2; t++)
        #pragma unroll
        for (int ks = 0; ks < 4; ks++) {
            short8v b;
            #pragma unroll
            for (int j = 0; j < 8; j++)
                b[j] = f2bs(Wl[(ks * 32 + q * 8 + j) * HD + wbase + t * 16 + r]);
            bfr[t][ks] = b;
        }

    const float al0 = wc[OFF_AL + l * HD + wbase + r];
    const float al1 = wc[OFF_AL + l * HD + wbase + 16 + r];
    const float ar0 = wc[OFF_AR + l * HD + wbase + r];
    const float ar1 = wc[OFF_AR + l * HD + wbase + 16 + r];

    for (int tile = blockIdx.x; tile < MTILES; tile += gridDim.x) {
        const int base = tile * 16;
        float4v acc0 = {0.f, 0.f, 0.f, 0.f};
        float4v acc1 = {0.f, 0.f, 0.f, 0.f};
        #pragma unroll
        for (int ks = 0; ks < 4; ks++) {
            short8v a = *reinterpret_cast<const short8v*>(
                h + (base + r) * HD + ks * 32 + q * 8);
            acc0 = __builtin_amdgcn_mfma_f32_16x16x32_bf16(a, bfr[0][ks], acc0, 0, 0, 0);
            acc1 = __builtin_amdgcn_mfma_f32_16x16x32_bf16(a, bfr[1][ks], acc1, 0, 0, 0);
        }
        #pragma unroll
        for (int reg = 0; reg < 4; reg++) {
            const int row = base + q * 4 + reg;
            feat[row * HD + wbase + r]      = f2b(acc0[reg]);
            feat[row * HD + wbase + 16 + r] = f2b(acc1[reg]);
            float elp = acc0[reg] * al0 + acc1[reg] * al1;
            float erp = acc0[reg] * ar0 + acc1[reg] * ar1;
            #pragma unroll
            for (int m = 1; m < 16; m <<= 1) {
                elp += __shfl_xor(elp, m, 64);
                erp += __shfl_xor(erp, m, 64);
            }
            if (r == 0) {
                el[row * 4 + wid] = elp;
                er[row * 4 + wid] = erp;
            }
        }
    }
}

// per-edge exp-scores (no max-sub: softmax is shift-invariant, scores O(1)).
// alpha[e] = exp(lrelu(el[src]+er[dst])) per head, stored f16x4 in CSR order.
__global__ __launch_bounds__(256) void k_escore(
        const float* __restrict__ el, const float* __restrict__ er,
        const int* __restrict__ row_ptr, const int* __restrict__ csr_src,
        half4v* __restrict__ alpha) {
    int lane = threadIdx.x & 63, wid = threadIdx.x >> 6;
    for (int n = blockIdx.x * 4 + wid; n < NN; n += gridDim.x * 4) {
        int rp = row_ptr[n];
        int deg = row_ptr[n + 1] - rp;
        float4 erv = *reinterpret_cast<const float4*>(er + n * 4);
        for (int e = lane; e < deg; e += 64) {
            int s = csr_src[rp + e];
            float4 elv = *reinterpret_cast<const float4*>(el + s * 4);
            half4v a;
            a[0] = (_Float16)__expf(lrelu(elv.x + erv.x));
            a[1] = (_Float16)__expf(lrelu(elv.y + erv.y));
            a[2] = (_Float16)__expf(lrelu(elv.z + erv.z));
            a[3] = (_Float16)__expf(lrelu(elv.w + erv.w));
            alpha[rp + e] = a;
        }
    }
}

// aggregation: lane owns channels {2*lane, 2*lane+1} (same head ->
// ONE weight per lane per edge, z accumulated per-lane, zero shuffles).
__global__ __launch_bounds__(256) void k_agg2(
        const bf16* __restrict__ feat, const half4v* __restrict__ alpha,
        const int* __restrict__ row_ptr, const int* __restrict__ csr_src,
        const float* __restrict__ wc, bf16* __restrict__ h, int l) {
    int lane = threadIdx.x & 63, wid = threadIdx.x >> 6;
    const int c0 = lane * 2;
    const bool b4 = (lane & 16) != 0, b5 = (lane & 32) != 0;
    for (int n = blockIdx.x * 4 + wid; n < NN; n += gridDim.x * 4) {
        int rp = row_ptr[n];
        int deg = row_ptr[n + 1] - rp;
        float aA0 = 0.f, aB0 = 0.f, aA1 = 0.f, aB1 = 0.f;
        float z0 = 0.f, z1 = 0.f;
        int j = 0;
        for (; j + 2 <= deg; j += 2) {
            int s0 = csr_src[rp + j];
            int s1 = csr_src[rp + j + 1];
            half4v q0 = alpha[rp + j];
            half4v q1 = alpha[rp + j + 1];
            float w0 = (float)(b5 ? (b4 ? q0[3] : q0[2]) : (b4 ? q0[1] : q0[0]));
            float w1 = (float)(b5 ? (b4 ? q1[3] : q1[2]) : (b4 ? q1[1] : q1[0]));
            u32 f0 = *reinterpret_cast<const u32*>(feat + s0 * HD + c0);
            u32 f1 = *reinterpret_cast<const u32*>(feat + s1 * HD + c0);
            aA0 += w0 * bf16lo(f0); aB0 += w0 * bf16hi(f0);
            aA1 += w1 * bf16lo(f1); aB1 += w1 * bf16hi(f1);
            z0 += w0; z1 += w1;
        }
        if (j < deg) {
            int s0 = csr_src[rp + j];
            half4v q0 = alpha[rp + j];
            float w0 = (float)(b5 ? (b4 ? q0[3] : q0[2]) : (b4 ? q0[1] : q0[0]));
            u32 f0 = *reinterpret_cast<const u32*>(feat + s0 * HD + c0);
            aA0 += w0 * bf16lo(f0); aB0 += w0 * bf16hi(f0);
            z0 += w0;
        }
        float z = z0 + z1;
        float rA = deg ? (aA0 + aA1) / z : 0.f;
        float rB = deg ? (aB0 + aB1) / z : 0.f;
        u32 hres = *reinterpret_cast<const u32*>(h + n * HD + c0);
        float v0 = rA + bf16lo(hres) + wc[OFF_BIAS + l * HD + c0];
        float v1 = rB + bf16hi(hres) + wc[OFF_BIAS + l * HD + c0 + 1];
        *reinterpret_cast<u32*>(h + n * HD + c0) =
            packbf16(fmaxf(v0, 0.f), fmaxf(v1, 0.f));
    }
}

__global__ __launch_bounds__(256) void k_ln_gate(
        bf16* __restrict__ h, const float* __restrict__ wc,
        float* __restrict__ gate) {
    int lane = threadIdx.x & 63, wid = threadIdx.x >> 6;
    int n = blockIdx.x * 4 + wid;
    if (n >= NN) return;
    float x0 = b2f(h[n * HD + lane]), x1 = b2f(h[n * HD + 64 + lane]);
    float mu = wave_sum64(x0 + x1) * (1.0f / 128.0f);
    float d0 = x0 - mu, d1 = x1 - mu;
    float var = wave_sum64(d0 * d0 + d1 * d1) * (1.0f / 128.0f);
    float rs = rsqrtf(var + 1e-5f);
    float y0 = d0 * rs * wc[OFF_LNG + lane]      + wc[OFF_LNB + lane];
    float y1 = d1 * rs * wc[OFF_LNG + 64 + lane] + wc[OFF_LNB + 64 + lane];
    h[n * HD + lane] = f2b(y0);
    h[n * HD + 64 + lane] = f2b(y1);
    float g = wave_sum64(y0 * wc[OFF_GW + lane] + y1 * wc[OFF_GW + 64 + lane]);
    if (lane == 0) gate[n] = g + wc[OFF_GB];
}

__global__ void k_gbound(const int* __restrict__ gid, int* __restrict__ gb) {
    int g = threadIdx.x;
    if (g > NG) return;
    int lo = 0, hi = NN;
    while (lo < hi) {
        int mid = (lo + hi) >> 1;
        if (gid[mid] < g) lo = mid + 1;
        else hi = mid;
    }
    gb[g] = lo;
}

// per-graph gate max + 1/z (one block per graph; touches only gate[])
__global__ __launch_bounds__(256) void k_gmaxz(
        const float* __restrict__ gate, const int* __restrict__ gb,
        float* __restrict__ gmax, float* __restrict__ gzinv) {
    __shared__ float red[256];
    int g = blockIdx.x, tid = threadIdx.x;
    int s0 = gb[g], e0 = gb[g + 1];
    float m = -1e30f;
    for (int i = s0 + tid; i < e0; i += 256) m = fmaxf(m, gate[i]);
    red[tid] = m;
    __syncthreads();
    for (int off = 128; off; off >>= 1) {
        if (tid < off) red[tid] = fmaxf(red[tid], red[tid + off]);
        __syncthreads();
    }
    m = red[0];
    __syncthreads();
    float z = 0.f;
    for (int i = s0 + tid; i < e0; i += 256) z += __expf(gate[i] - m);
    red[tid] = z;
    __syncthreads();
    for (int off = 128; off; off >>= 1) {
        if (tid < off) red[tid] += red[tid + off];
        __syncthreads();
    }
    if (tid == 0) {
        gmax[g] = m;
        gzinv[g] = (e0 > s0 && red[0] > 0.f) ? 1.0f / red[0] : 0.f;
    }
}

// weighted node-sum, PCHUNK blocks per graph, atomicAdd into zeroed zg
__global__ __launch_bounds__(256) void k_poolsum(
        const bf16* __restrict__ h, const float* __restrict__ gate,
        const int* __restrict__ gb, const float* __restrict__ gmax,
        float* __restrict__ zg) {
    __shared__ float red[256];
    int b = blockIdx.x;
    int g = b / PCHUNK, c = b % PCHUNK;
    int s0 = gb[g], e0 = gb[g + 1];
    int len = e0 - s0;
    int beg = s0 + (int)(((long long)len * c) / PCHUNK);
    int end = s0 + (int)(((long long)len * (c + 1)) / PCHUNK);
    int ch = threadIdx.x & 127, half = threadIdx.x >> 7;
    float m = gmax[g];
    float acc = 0.f;
    for (int i = beg + half; i < end; i += 2)
        acc += __expf(gate[i] - m) * b2f(h[i * HD + ch]);
    red[threadIdx.x] = acc;
    __syncthreads();
    if (threadIdx.x < 128) {
        float v = red[threadIdx.x] + red[threadIdx.x + 128];
        if (v != 0.f) atomicAdd(&zg[g * HD + ch], v);
    }
}

__global__ __launch_bounds__(128) void k_mlp(
        const float* __restrict__ zg, const float* __restrict__ gzinv,
        const float* __restrict__ wc, float* __restrict__ out) {
    __shared__ float zr[HD], z1[HD];
    int g = blockIdx.x, tid = threadIdx.x;
    zr[tid] = zg[g * HD + tid] * gzinv[g];
    __syncthreads();
    float acc = wc[OFF_PB1 + tid];
    for (int k = 0; k < HD; k++) acc += zr[k] * wc[OFF_PW1 + k * HD + tid];
    z1[tid] = fmaxf(acc, 0.f);
    __syncthreads();
    if (tid < 64) {
        float a2 = wc[OFF_PB2 + tid];
        for (int k = 0; k < HD; k++) a2 += z1[k] * wc[OFF_PW2 + k * 64 + tid];
        out[g * 64 + tid] = a2;
    }
}

extern "C" void kernel_launch(void* const* d_in, const int* in_sizes, int n_in,
                              void* d_out, int out_size, void* d_ws, size_t ws_size,
                              hipStream_t stream) {
    const int* gate_types = (const int*)d_in[0];
    const int* qubit_idx  = (const int*)d_in[1];
    const int* src        = (const int*)d_in[2];
    const int* dst        = (const int*)d_in[3];
    const int* graph_ids  = (const int*)d_in[4];
    float* out = (float*)d_out;

    const int expect[19] = {NN, NN, NE, NE, NN, 4096, 2560, 49152, 384, 384,
                            384, 128, 128, 128, 1, 16384, 128, 8192, 64};
    for (int i = 0; i < 19 && i < n_in; i++) {
        if (in_sizes[i] != expect[i]) {
            k_diag<<<(out_size + 255) / 256, 256, 0, stream>>>(out, out_size,
                                                               7777000.f + i);
            return;
        }
    }

    char* ws = (char*)d_ws;
    size_t off = 0;
    auto alloc = [&](size_t bytes) {
        void* p = ws + off;
        off = (off + bytes + 255) & ~(size_t)255;
        return p;
    };
    int*    flag    = (int*)alloc(sizeof(int));
    float*  wc      = (float*)alloc(sizeof(float) * CVT_TOTAL);
    float*  el      = (float*)alloc(sizeof(float) * NN * 4);
    float*  er      = (float*)alloc(sizeof(float) * NN * 4);
    int*    row_ptr = (int*)alloc(sizeof(int) * (NN + 1));
    int*    deg     = (int*)alloc(sizeof(int) * NN);
    int*    cursor  = (int*)alloc(sizeof(int) * NN);
    int*    csr_src = (int*)alloc(sizeof(int) * NE);
    int*    bsum    = (int*)alloc(sizeof(int) * NSB);
    int*    boff    = (int*)alloc(sizeof(int) * NSB);
    half4v* alpha   = (half4v*)alloc(sizeof(half4v) * NE);
    float*  gate    = (float*)alloc(sizeof(float) * NN);
    int*    gb      = (int*)alloc(sizeof(int) * (NG + 1));
    float*  zg      = (float*)alloc(sizeof(float) * NG * HD);
    float*  gmax    = (float*)alloc(sizeof(float) * NG);
    float*  gzinv   = (float*)alloc(sizeof(float) * NG);
    bf16*   h       = (bf16*)alloc(sizeof(bf16) * NN * HD);
    bf16*   feat    = (bf16*)alloc(sizeof(bf16) * NN * HD);

    if (off > ws_size) {
        k_diag<<<(out_size + 255) / 256, 256, 0, stream>>>(
            out, out_size, (float)(ws_size >> 10));
        return;
    }

    k_detect<<<1, 256, 0, stream>>>((const u16*)d_in[7], flag);
    CvtSrc cs;
    for (int i = 0; i < 14; i++) cs.p[i] = d_in[5 + i];
    k_convert<<<128, 256, 0, stream>>>(cs, flag, wc);

    k_embed<<<(NN * HD + 255) / 256, 256, 0, stream>>>(gate_types, qubit_idx,
                                                       wc, h);
    (void)hipMemsetAsync(deg, 0, sizeof(int) * NN, stream);
    k_count<<<(NE + 255) / 256, 256, 0, stream>>>(dst, deg);
    k_bsum<<<NSB, SBLK, 0, stream>>>(deg, bsum);
    k_bscan<<<1, SBLK, 0, stream>>>(bsum, boff, row_ptr);
    k_locscan<<<NSB, SBLK, 0, stream>>>(deg, boff, row_ptr, cursor);
    k_fill<<<(NE + 255) / 256, 256, 0, stream>>>(src, dst, cursor, csr_src);

    for (int l = 0; l < NL; l++) {
        k_gemm_mfma<<<512, 256, 0, stream>>>(h, wc, feat, el, er, l);
        k_escore<<<2048, 256, 0, stream>>>(el, er, row_ptr, csr_src, alpha);
        k_agg2<<<2048, 256, 0, stream>>>(feat, alpha, row_ptr, csr_src, wc, h, l);
    }
    k_ln_gate<<<(NN + 3) / 4, 256, 0, stream>>>(h, wc, gate);
    k_gbound<<<1, 128, 0, stream>>>(graph_ids, gb);
    k_gmaxz<<<NG, 256, 0, stream>>>(gate, gb, gmax, gzinv);
    (void)hipMemsetAsync(zg, 0, sizeof(float) * NG * HD, stream);
    k_poolsum<<<NG * PCHUNK, 256, 0, stream>>>(h, gate, gb, gmax, zg);
    k_mlp<<<NG, 128, 0, stream>>>(zg, gzinv, wc, out);
}

// Round 9
// 328.760 us; speedup vs baseline: 2.8201x; 1.0358x over previous
//
#include <hip/hip_runtime.h>
#include <hip/hip_bf16.h>

#define NN 50000
#define NE 600000
#define NG 64
#define HD 128
#define NL 3
#define NEG 0.2f
#define PCHUNK 16     // pooling blocks per graph
#define SBLK 256
#define NSB ((NN + SBLK - 1) / SBLK)   // 196 scan blocks
#define GBLK ((NN + 63) / 64)          // 782 gemm/elr blocks

typedef __hip_bfloat16 bf16;
typedef unsigned short u16;
typedef unsigned int u32;
typedef __attribute__((ext_vector_type(8))) short short8v;      // 8 bf16
typedef __attribute__((ext_vector_type(4))) float float4v;      // MFMA acc

// converted-f32 weight region offsets (element units)
#define OFF_GE    0
#define OFF_QE    4096
#define OFF_W     6656
#define OFF_AL    55808
#define OFF_AR    56192
#define OFF_BIAS  56576
#define OFF_LNG   56960
#define OFF_LNB   57088
#define OFF_GW    57216
#define OFF_GB    57344
#define OFF_PW1   57345
#define OFF_PB1   73729
#define OFF_PW2   73857
#define OFF_PB2   82049
#define CVT_TOTAL 82113

__device__ __forceinline__ float b2f(bf16 x) { return __bfloat162float(x); }
__device__ __forceinline__ bf16 f2b(float x) { return __float2bfloat16(x); }
__device__ __forceinline__ short f2bs(float x) {
    bf16 t = __float2bfloat16(x);
    return *reinterpret_cast<short*>(&t);
}
__device__ __forceinline__ float lrelu(float x) { return x > 0.f ? x : NEG * x; }
__device__ __forceinline__ float bf16lo(u32 u) { return __uint_as_float(u << 16); }
__device__ __forceinline__ float bf16hi(u32 u) { return __uint_as_float(u & 0xffff0000u); }
__device__ __forceinline__ u32 packbf16(float x, float y) {
    bf16 bx = f2b(x), by = f2b(y);
    u16 ux = *reinterpret_cast<u16*>(&bx);
    u16 uy = *reinterpret_cast<u16*>(&by);
    return (u32)ux | ((u32)uy << 16);
}

__device__ __forceinline__ float wave_sum64(float v) {
    #pragma unroll
    for (int m = 1; m < 64; m <<= 1) v += __shfl_xor(v, m, 64);
    return v;
}

// ---- diagnostics ----
__global__ void k_diag(float* out, int n, float code) {
    int i = blockIdx.x * blockDim.x + threadIdx.x;
    if (i < n) out[i] = code;
}

// ---- input dtype detection (bf16 vs f32 misread) ----
__global__ void k_detect(const u16* __restrict__ w, int* __restrict__ flag) {
    __shared__ int cnt;
    if (threadIdx.x == 0) cnt = 0;
    __syncthreads();
    int bad = 0;
    for (int i = threadIdx.x; i < 2048; i += 256) {
        int e = (w[i] >> 7) & 0xFF;
        if (e == 0xFF || e >= 0x90) bad++;
    }
    atomicAdd(&cnt, bad);
    __syncthreads();
    if (threadIdx.x == 0) *flag = (cnt > 16) ? 1 : 0;
}

struct CvtSrc { const void* p[14]; };

__global__ void k_convert(CvtSrc srcs, const int* __restrict__ flag,
                          float* __restrict__ dst) {
    const bool isf32 = (*flag != 0);
    const int starts[15] = {OFF_GE, OFF_QE, OFF_W, OFF_AL, OFF_AR, OFF_BIAS,
                            OFF_LNG, OFF_LNB, OFF_GW, OFF_GB, OFF_PW1, OFF_PB1,
                            OFF_PW2, OFF_PB2, CVT_TOTAL};
    for (int i = blockIdx.x * blockDim.x + threadIdx.x; i < CVT_TOTAL;
         i += gridDim.x * blockDim.x) {
        int a = 0;
        while (i >= starts[a + 1]) a++;
        int off = i - starts[a];
        dst[i] = isf32 ? ((const float*)srcs.p[a])[off]
                       : b2f(((const bf16*)srcs.p[a])[off]);
    }
}

// 2 channels per thread, packed u32 store
__global__ void k_embed(const int* __restrict__ gt, const int* __restrict__ qi,
                        const float* __restrict__ wc, bf16* __restrict__ h) {
    int idx = blockIdx.x * blockDim.x + threadIdx.x;
    if (idx >= NN * 64) return;
    int n = idx >> 6, c = (idx & 63) * 2;
    int g = gt[n], q = qi[n];
    float a0 = wc[OFF_GE + g * HD + c]     + wc[OFF_QE + q * HD + c];
    float a1 = wc[OFF_GE + g * HD + c + 1] + wc[OFF_QE + q * HD + c + 1];
    *reinterpret_cast<u32*>(h + n * HD + c) = packbf16(a0, a1);
}

__global__ void k_count(const int* __restrict__ dst, int* __restrict__ deg) {
    int e = blockIdx.x * blockDim.x + threadIdx.x;
    if (e < NE) atomicAdd(&deg[dst[e]], 1);
}

// ---- 3-phase multi-block exclusive scan of deg -> row_ptr/cursor ----
__global__ __launch_bounds__(SBLK) void k_bsum(const int* __restrict__ deg,
                                               int* __restrict__ bsum) {
    __shared__ int red[SBLK];
    int i = blockIdx.x * SBLK + threadIdx.x;
    red[threadIdx.x] = (i < NN) ? deg[i] : 0;
    __syncthreads();
    for (int off = SBLK / 2; off; off >>= 1) {
        if (threadIdx.x < off) red[threadIdx.x] += red[threadIdx.x + off];
        __syncthreads();
    }
    if (threadIdx.x == 0) bsum[blockIdx.x] = red[0];
}

__global__ __launch_bounds__(SBLK) void k_bscan(const int* __restrict__ bsum,
                                                int* __restrict__ boff,
                                                int* __restrict__ row_ptr) {
    __shared__ int s[SBLK];
    int t = threadIdx.x;
    int x = (t < NSB) ? bsum[t] : 0;
    s[t] = x;
    __syncthreads();
    #pragma unroll
    for (int off = 1; off < SBLK; off <<= 1) {
        int v = (t >= off) ? s[t - off] : 0;
        __syncthreads();
        if (t >= off) s[t] += v;
        __syncthreads();
    }
    if (t < NSB) boff[t] = s[t] - x;          // exclusive
    if (t == 0) row_ptr[NN] = s[SBLK - 1];    // total (= NE)
}

__global__ __launch_bounds__(SBLK) void k_locscan(const int* __restrict__ deg,
                                                  const int* __restrict__ boff,
                                                  int* __restrict__ row_ptr,
                                                  int* __restrict__ cursor) {
    __shared__ int s[SBLK];
    int t = threadIdx.x;
    int i = blockIdx.x * SBLK + t;
    int x = (i < NN) ? deg[i] : 0;
    s[t] = x;
    __syncthreads();
    #pragma unroll
    for (int off = 1; off < SBLK; off <<= 1) {
        int v = (t >= off) ? s[t - off] : 0;
        __syncthreads();
        if (t >= off) s[t] += v;
        __syncthreads();
    }
    if (i < NN) {
        int excl = boff[blockIdx.x] + s[t] - x;
        row_ptr[i] = excl;
        cursor[i] = excl;
    }
}

__global__ void k_fill(const int* __restrict__ src, const int* __restrict__ dst,
                       int* __restrict__ cursor, int* __restrict__ csr_src) {
    int e = blockIdx.x * blockDim.x + threadIdx.x;
    if (e < NE) {
        int p = atomicAdd(&cursor[dst[e]], 1);
        csr_src[p] = src[e];
    }
}

// Pure MFMA GEMM: feat = h @ W[l]. Block = 4 waves; wave wid owns head wid's
// 32 cols. Each block does a 64-row supertile (4 M-tiles). No epilogue reduce.
__global__ __launch_bounds__(256) void k_gemm_mfma(
        const bf16* __restrict__ h, const float* __restrict__ wc,
        bf16* __restrict__ feat, int l) {
    const int lane = threadIdx.x & 63, wid = threadIdx.x >> 6;
    const int r = lane & 15, q = lane >> 4;
    const int wbase = wid * 32;
    const float* Wl = wc + OFF_W + l * HD * HD;

    short8v bfr[2][4];
    #pragma unroll
    for (int t = 0; t < 2; t++)
        #pragma unroll
        for (int ks = 0; ks < 4; ks++) {
            short8v b;
            #pragma unroll
            for (int j = 0; j < 8; j++)
                b[j] = f2bs(Wl[(ks * 32 + q * 8 + j) * HD + wbase + t * 16 + r]);
            bfr[t][ks] = b;
        }

    const int base0 = blockIdx.x * 64;
    #pragma unroll
    for (int mt = 0; mt < 4; mt++) {
        const int base = base0 + mt * 16;
        if (base >= NN) break;
        float4v acc0 = {0.f, 0.f, 0.f, 0.f};
        float4v acc1 = {0.f, 0.f, 0.f, 0.f};
        #pragma unroll
        for (int ks = 0; ks < 4; ks++) {
            short8v a = *reinterpret_cast<const short8v*>(
                h + (base + r) * HD + ks * 32 + q * 8);
            acc0 = __builtin_amdgcn_mfma_f32_16x16x32_bf16(a, bfr[0][ks], acc0, 0, 0, 0);
            acc1 = __builtin_amdgcn_mfma_f32_16x16x32_bf16(a, bfr[1][ks], acc1, 0, 0, 0);
        }
        #pragma unroll
        for (int reg = 0; reg < 4; reg++) {
            const int row = base + q * 4 + reg;
            feat[row * HD + wbase + r]      = f2b(acc0[reg]);
            feat[row * HD + wbase + 16 + r] = f2b(acc1[reg]);
        }
    }
}

// el/er head-dots from feat: thread = (node, head); coalesced 64B feat slice.
__global__ __launch_bounds__(256) void k_elr(
        const bf16* __restrict__ feat, const float* __restrict__ wc,
        float* __restrict__ el, float* __restrict__ er, int l) {
    int t = blockIdx.x * blockDim.x + threadIdx.x;
    if (t >= NN * 4) return;
    int n = t >> 2, head = t & 3;
    const float* alh = wc + OFF_AL + l * HD + head * 32;
    const float* arh = wc + OFF_AR + l * HD + head * 32;
    const u32* f = reinterpret_cast<const u32*>(feat + n * HD + head * 32);
    float e1 = 0.f, e2 = 0.f;
    #pragma unroll
    for (int i = 0; i < 16; i++) {
        u32 v = f[i];
        float lo = bf16lo(v), hi = bf16hi(v);
        e1 += lo * alh[2 * i] + hi * alh[2 * i + 1];
        e2 += lo * arh[2 * i] + hi * arh[2 * i + 1];
    }
    el[t] = e1;
    er[t] = e2;
}

// fused aggregation: alpha computed in-register (exp w/o max-sub: shift-inv,
// O(1) scores). Lane owns channels {2l, 2l+1} of head (lane>>4); per-lane z.
__global__ __launch_bounds__(256) void k_agg2(
        const bf16* __restrict__ feat, const float* __restrict__ el4,
        const float* __restrict__ er4, const int* __restrict__ row_ptr,
        const int* __restrict__ csr_src, const float* __restrict__ wc,
        bf16* __restrict__ h, int l) {
    int lane = threadIdx.x & 63, wid = threadIdx.x >> 6;
    const int c0 = lane * 2;
    const int hsel = lane >> 4;
    for (int n = blockIdx.x * 4 + wid; n < NN; n += gridDim.x * 4) {
        int rp = row_ptr[n];
        int deg = row_ptr[n + 1] - rp;
        float ern = er4[n * 4 + hsel];
        float aA0 = 0.f, aB0 = 0.f, aA1 = 0.f, aB1 = 0.f;
        float aA2 = 0.f, aB2 = 0.f, aA3 = 0.f, aB3 = 0.f;
        float z0 = 0.f, z1 = 0.f, z2 = 0.f, z3 = 0.f;
        int j = 0;
        for (; j + 4 <= deg; j += 4) {
            int s0 = csr_src[rp + j];
            int s1 = csr_src[rp + j + 1];
            int s2 = csr_src[rp + j + 2];
            int s3 = csr_src[rp + j + 3];
            float w0 = __expf(lrelu(el4[s0 * 4 + hsel] + ern));
            float w1 = __expf(lrelu(el4[s1 * 4 + hsel] + ern));
            float w2 = __expf(lrelu(el4[s2 * 4 + hsel] + ern));
            float w3 = __expf(lrelu(el4[s3 * 4 + hsel] + ern));
            u32 f0 = *reinterpret_cast<const u32*>(feat + s0 * HD + c0);
            u32 f1 = *reinterpret_cast<const u32*>(feat + s1 * HD + c0);
            u32 f2 = *reinterpret_cast<const u32*>(feat + s2 * HD + c0);
            u32 f3 = *reinterpret_cast<const u32*>(feat + s3 * HD + c0);
            aA0 += w0 * bf16lo(f0); aB0 += w0 * bf16hi(f0); z0 += w0;
            aA1 += w1 * bf16lo(f1); aB1 += w1 * bf16hi(f1); z1 += w1;
            aA2 += w2 * bf16lo(f2); aB2 += w2 * bf16hi(f2); z2 += w2;
            aA3 += w3 * bf16lo(f3); aB3 += w3 * bf16hi(f3); z3 += w3;
        }
        for (; j < deg; j++) {
            int s0 = csr_src[rp + j];
            float w0 = __expf(lrelu(el4[s0 * 4 + hsel] + ern));
            u32 f0 = *reinterpret_cast<const u32*>(feat + s0 * HD + c0);
            aA0 += w0 * bf16lo(f0); aB0 += w0 * bf16hi(f0); z0 += w0;
        }
        float z = (z0 + z1) + (z2 + z3);
        float rA = deg ? ((aA0 + aA1) + (aA2 + aA3)) / z : 0.f;
        float rB = deg ? ((aB0 + aB1) + (aB2 + aB3)) / z : 0.f;
        u32 hres = *reinterpret_cast<const u32*>(h + n * HD + c0);
        float v0 = rA + bf16lo(hres) + wc[OFF_BIAS + l * HD + c0];
        float v1 = rB + bf16hi(hres) + wc[OFF_BIAS + l * HD + c0 + 1];
        *reinterpret_cast<u32*>(h + n * HD + c0) =
            packbf16(fmaxf(v0, 0.f), fmaxf(v1, 0.f));
    }
}

__global__ __launch_bounds__(256) void k_ln_gate(
        bf16* __restrict__ h, const float* __restrict__ wc,
        float* __restrict__ gate) {
    int lane = threadIdx.x & 63, wid = threadIdx.x >> 6;
    int n = blockIdx.x * 4 + wid;
    if (n >= NN) return;
    float x0 = b2f(h[n * HD + lane]), x1 = b2f(h[n * HD + 64 + lane]);
    float mu = wave_sum64(x0 + x1) * (1.0f / 128.0f);
    float d0 = x0 - mu, d1 = x1 - mu;
    float var = wave_sum64(d0 * d0 + d1 * d1) * (1.0f / 128.0f);
    float rs = rsqrtf(var + 1e-5f);
    float y0 = d0 * rs * wc[OFF_LNG + lane]      + wc[OFF_LNB + lane];
    float y1 = d1 * rs * wc[OFF_LNG + 64 + lane] + wc[OFF_LNB + 64 + lane];
    h[n * HD + lane] = f2b(y0);
    h[n * HD + 64 + lane] = f2b(y1);
    float g = wave_sum64(y0 * wc[OFF_GW + lane] + y1 * wc[OFF_GW + 64 + lane]);
    if (lane == 0) gate[n] = g + wc[OFF_GB];
}

__global__ void k_gbound(const int* __restrict__ gid, int* __restrict__ gb) {
    int g = threadIdx.x;
    if (g > NG) return;
    int lo = 0, hi = NN;
    while (lo < hi) {
        int mid = (lo + hi) >> 1;
        if (gid[mid] < g) lo = mid + 1;
        else hi = mid;
    }
    gb[g] = lo;
}

// per-graph gate max + 1/z (one block per graph; touches only gate[])
__global__ __launch_bounds__(256) void k_gmaxz(
        const float* __restrict__ gate, const int* __restrict__ gb,
        float* __restrict__ gmax, float* __restrict__ gzinv) {
    __shared__ float red[256];
    int g = blockIdx.x, tid = threadIdx.x;
    int s0 = gb[g], e0 = gb[g + 1];
    float m = -1e30f;
    for (int i = s0 + tid; i < e0; i += 256) m = fmaxf(m, gate[i]);
    red[tid] = m;
    __syncthreads();
    for (int off = 128; off; off >>= 1) {
        if (tid < off) red[tid] = fmaxf(red[tid], red[tid + off]);
        __syncthreads();
    }
    m = red[0];
    __syncthreads();
    float z = 0.f;
    for (int i = s0 + tid; i < e0; i += 256) z += __expf(gate[i] - m);
    red[tid] = z;
    __syncthreads();
    for (int off = 128; off; off >>= 1) {
        if (tid < off) red[tid] += red[tid + off];
        __syncthreads();
    }
    if (tid == 0) {
        gmax[g] = m;
        gzinv[g] = (e0 > s0 && red[0] > 0.f) ? 1.0f / red[0] : 0.f;
    }
}

// weighted node-sum, PCHUNK blocks per graph, atomicAdd into zeroed zg
__global__ __launch_bounds__(256) void k_poolsum(
        const bf16* __restrict__ h, const float* __restrict__ gate,
        const int* __restrict__ gb, const float* __restrict__ gmax,
        float* __restrict__ zg) {
    __shared__ float red[256];
    int b = blockIdx.x;
    int g = b / PCHUNK, c = b % PCHUNK;
    int s0 = gb[g], e0 = gb[g + 1];
    int len = e0 - s0;
    int beg = s0 + (int)(((long long)len * c) / PCHUNK);
    int end = s0 + (int)(((long long)len * (c + 1)) / PCHUNK);
    int ch = threadIdx.x & 127, half = threadIdx.x >> 7;
    float m = gmax[g];
    float acc = 0.f;
    for (int i = beg + half; i < end; i += 2)
        acc += __expf(gate[i] - m) * b2f(h[i * HD + ch]);
    red[threadIdx.x] = acc;
    __syncthreads();
    if (threadIdx.x < 128) {
        float v = red[threadIdx.x] + red[threadIdx.x + 128];
        if (v != 0.f) atomicAdd(&zg[g * HD + ch], v);
    }
}

__global__ __launch_bounds__(128) void k_mlp(
        const float* __restrict__ zg, const float* __restrict__ gzinv,
        const float* __restrict__ wc, float* __restrict__ out) {
    __shared__ float zr[HD], z1[HD];
    int g = blockIdx.x, tid = threadIdx.x;
    zr[tid] = zg[g * HD + tid] * gzinv[g];
    __syncthreads();
    float acc = wc[OFF_PB1 + tid];
    for (int k = 0; k < HD; k++) acc += zr[k] * wc[OFF_PW1 + k * HD + tid];
    z1[tid] = fmaxf(acc, 0.f);
    __syncthreads();
    if (tid < 64) {
        float a2 = wc[OFF_PB2 + tid];
        for (int k = 0; k < HD; k++) a2 += z1[k] * wc[OFF_PW2 + k * 64 + tid];
        out[g * 64 + tid] = a2;
    }
}

extern "C" void kernel_launch(void* const* d_in, const int* in_sizes, int n_in,
                              void* d_out, int out_size, void* d_ws, size_t ws_size,
                              hipStream_t stream) {
    const int* gate_types = (const int*)d_in[0];
    const int* qubit_idx  = (const int*)d_in[1];
    const int* src        = (const int*)d_in[2];
    const int* dst        = (const int*)d_in[3];
    const int* graph_ids  = (const int*)d_in[4];
    float* out = (float*)d_out;

    const int expect[19] = {NN, NN, NE, NE, NN, 4096, 2560, 49152, 384, 384,
                            384, 128, 128, 128, 1, 16384, 128, 8192, 64};
    for (int i = 0; i < 19 && i < n_in; i++) {
        if (in_sizes[i] != expect[i]) {
            k_diag<<<(out_size + 255) / 256, 256, 0, stream>>>(out, out_size,
                                                               7777000.f + i);
            return;
        }
    }

    char* ws = (char*)d_ws;
    size_t off = 0;
    auto alloc = [&](size_t bytes) {
        void* p = ws + off;
        off = (off + bytes + 255) & ~(size_t)255;
        return p;
    };
    int*    flag    = (int*)alloc(sizeof(int));
    float*  wc      = (float*)alloc(sizeof(float) * CVT_TOTAL);
    float*  el      = (float*)alloc(sizeof(float) * NN * 4);
    float*  er      = (float*)alloc(sizeof(float) * NN * 4);
    int*    row_ptr = (int*)alloc(sizeof(int) * (NN + 1));
    int*    deg     = (int*)alloc(sizeof(int) * NN);
    int*    cursor  = (int*)alloc(sizeof(int) * NN);
    int*    csr_src = (int*)alloc(sizeof(int) * NE);
    int*    bsum    = (int*)alloc(sizeof(int) * NSB);
    int*    boff    = (int*)alloc(sizeof(int) * NSB);
    float*  gate    = (float*)alloc(sizeof(float) * NN);
    int*    gb      = (int*)alloc(sizeof(int) * (NG + 1));
    float*  zg      = (float*)alloc(sizeof(float) * NG * HD);
    float*  gmax    = (float*)alloc(sizeof(float) * NG);
    float*  gzinv   = (float*)alloc(sizeof(float) * NG);
    bf16*   h       = (bf16*)alloc(sizeof(bf16) * NN * HD);
    bf16*   feat    = (bf16*)alloc(sizeof(bf16) * NN * HD);

    if (off > ws_size) {
        k_diag<<<(out_size + 255) / 256, 256, 0, stream>>>(
            out, out_size, (float)(ws_size >> 10));
        return;
    }

    k_detect<<<1, 256, 0, stream>>>((const u16*)d_in[7], flag);
    CvtSrc cs;
    for (int i = 0; i < 14; i++) cs.p[i] = d_in[5 + i];
    k_convert<<<128, 256, 0, stream>>>(cs, flag, wc);

    k_embed<<<(NN * 64 + 255) / 256, 256, 0, stream>>>(gate_types, qubit_idx,
                                                       wc, h);
    (void)hipMemsetAsync(deg, 0, sizeof(int) * NN, stream);
    k_count<<<(NE + 255) / 256, 256, 0, stream>>>(dst, deg);
    k_bsum<<<NSB, SBLK, 0, stream>>>(deg, bsum);
    k_bscan<<<1, SBLK, 0, stream>>>(bsum, boff, row_ptr);
    k_locscan<<<NSB, SBLK, 0, stream>>>(deg, boff, row_ptr, cursor);
    k_fill<<<(NE + 255) / 256, 256, 0, stream>>>(src, dst, cursor, csr_src);

    for (int l = 0; l < NL; l++) {
        k_gemm_mfma<<<GBLK, 256, 0, stream>>>(h, wc, feat, l);
        k_elr<<<(NN * 4 + 255) / 256, 256, 0, stream>>>(feat, wc, el, er, l);
        k_agg2<<<2048, 256, 0, stream>>>(feat, el, er, row_ptr, csr_src, wc, h, l);
    }
    k_ln_gate<<<(NN + 3) / 4, 256, 0, stream>>>(h, wc, gate);
    k_gbound<<<1, 128, 0, stream>>>(graph_ids, gb);
    k_gmaxz<<<NG, 256, 0, stream>>>(gate, gb, gmax, gzinv);
    (void)hipMemsetAsync(zg, 0, sizeof(float) * NG * HD, stream);
    k_poolsum<<<NG * PCHUNK, 256, 0, stream>>>(h, gate, gb, gmax, zg);
    k_mlp<<<NG, 128, 0, stream>>>(zg, gzinv, wc, out);
}

// Round 10
// 324.125 us; speedup vs baseline: 2.8604x; 1.0143x over previous
//
#include <hip/hip_runtime.h>
#include <hip/hip_bf16.h>

#define NN 50000
#define NE 600000
#define NG 64
#define HD 128
#define NL 3
#define NEG 0.2f
#define PCHUNK 16     // pooling blocks per graph
#define SBLK 256
#define NSB ((NN + SBLK - 1) / SBLK)   // 196 scan blocks
#define GBLK ((NN + 63) / 64)          // 782 gemm blocks

typedef __hip_bfloat16 bf16;
typedef unsigned short u16;
typedef unsigned int u32;
typedef __attribute__((ext_vector_type(8))) short short8v;      // 8 bf16
typedef __attribute__((ext_vector_type(4))) float float4v;      // MFMA acc

// converted-f32 weight region offsets (element units)
#define OFF_GE    0
#define OFF_QE    4096
#define OFF_W     6656
#define OFF_AL    55808
#define OFF_AR    56192
#define OFF_BIAS  56576
#define OFF_LNG   56960
#define OFF_LNB   57088
#define OFF_GW    57216
#define OFF_GB    57344
#define OFF_PW1   57345
#define OFF_PB1   73729
#define OFF_PW2   73857
#define OFF_PB2   82049
#define CVT_TOTAL 82113

__device__ __forceinline__ float b2f(bf16 x) { return __bfloat162float(x); }
__device__ __forceinline__ bf16 f2b(float x) { return __float2bfloat16(x); }
__device__ __forceinline__ float lrelu(float x) { return x > 0.f ? x : NEG * x; }
__device__ __forceinline__ float bf16lo(u32 u) { return __uint_as_float(u << 16); }
__device__ __forceinline__ float bf16hi(u32 u) { return __uint_as_float(u & 0xffff0000u); }
__device__ __forceinline__ u32 packbf16(float x, float y) {
    bf16 bx = f2b(x), by = f2b(y);
    u16 ux = *reinterpret_cast<u16*>(&bx);
    u16 uy = *reinterpret_cast<u16*>(&by);
    return (u32)ux | ((u32)uy << 16);
}

__device__ __forceinline__ float wave_sum64(float v) {
    #pragma unroll
    for (int m = 1; m < 64; m <<= 1) v += __shfl_xor(v, m, 64);
    return v;
}

// ---- diagnostics ----
__global__ void k_diag(float* out, int n, float code) {
    int i = blockIdx.x * blockDim.x + threadIdx.x;
    if (i < n) out[i] = code;
}

struct CvtSrc { const void* p[14]; };

// convert all weights to canonical f32 region + build transposed bf16 W.
// dtype detect (bf16 vs f32 misread) done per-block: deterministic inputs.
__global__ __launch_bounds__(256) void k_convert(CvtSrc srcs,
                                                 float* __restrict__ dst,
                                                 bf16* __restrict__ wbt) {
    __shared__ int cnt;
    if (threadIdx.x == 0) cnt = 0;
    __syncthreads();
    const u16* wraw = (const u16*)srcs.p[2];
    int bad = 0;
    for (int i = threadIdx.x; i < 2048; i += 256) {
        int e = (wraw[i] >> 7) & 0xFF;
        if (e == 0xFF || e >= 0x90) bad++;
    }
    if (bad) atomicAdd(&cnt, bad);
    __syncthreads();
    const bool isf32 = cnt > 16;

    const int starts[15] = {OFF_GE, OFF_QE, OFF_W, OFF_AL, OFF_AR, OFF_BIAS,
                            OFF_LNG, OFF_LNB, OFF_GW, OFF_GB, OFF_PW1, OFF_PB1,
                            OFF_PW2, OFF_PB2, CVT_TOTAL};
    for (int i = blockIdx.x * blockDim.x + threadIdx.x; i < CVT_TOTAL;
         i += gridDim.x * blockDim.x) {
        int a = 0;
        while (i >= starts[a + 1]) a++;
        int off = i - starts[a];
        dst[i] = isf32 ? ((const float*)srcs.p[a])[off]
                       : b2f(((const bf16*)srcs.p[a])[off]);
    }
    // wbt[l][col][k] = bf16(W[l][k][col])  (transposed, MFMA-B-fragment layout)
    for (int i = blockIdx.x * blockDim.x + threadIdx.x; i < NL * HD * HD;
         i += gridDim.x * blockDim.x) {
        int l = i >> 14, rem = i & 16383;
        int col = rem >> 7, k = rem & 127;
        int si = l * 16384 + k * 128 + col;
        float v = isf32 ? ((const float*)srcs.p[2])[si]
                        : b2f(((const bf16*)srcs.p[2])[si]);
        wbt[i] = f2b(v);
    }
}

// 2 channels per thread, packed u32 store; also zeroes deg[]
__global__ void k_embed(const int* __restrict__ gt, const int* __restrict__ qi,
                        const float* __restrict__ wc, bf16* __restrict__ h,
                        int* __restrict__ deg) {
    int idx = blockIdx.x * blockDim.x + threadIdx.x;
    if (idx < NN) deg[idx] = 0;
    if (idx >= NN * 64) return;
    int n = idx >> 6, c = (idx & 63) * 2;
    int g = gt[n], q = qi[n];
    float a0 = wc[OFF_GE + g * HD + c]     + wc[OFF_QE + q * HD + c];
    float a1 = wc[OFF_GE + g * HD + c + 1] + wc[OFF_QE + q * HD + c + 1];
    *reinterpret_cast<u32*>(h + n * HD + c) = packbf16(a0, a1);
}

__global__ void k_count(const int* __restrict__ dst, int* __restrict__ deg) {
    int e = blockIdx.x * blockDim.x + threadIdx.x;
    if (e < NE) atomicAdd(&deg[dst[e]], 1);
}

// ---- 3-phase multi-block exclusive scan of deg -> row_ptr/cursor ----
__global__ __launch_bounds__(SBLK) void k_bsum(const int* __restrict__ deg,
                                               int* __restrict__ bsum) {
    __shared__ int red[SBLK];
    int i = blockIdx.x * SBLK + threadIdx.x;
    red[threadIdx.x] = (i < NN) ? deg[i] : 0;
    __syncthreads();
    for (int off = SBLK / 2; off; off >>= 1) {
        if (threadIdx.x < off) red[threadIdx.x] += red[threadIdx.x + off];
        __syncthreads();
    }
    if (threadIdx.x == 0) bsum[blockIdx.x] = red[0];
}

__global__ __launch_bounds__(SBLK) void k_bscan(const int* __restrict__ bsum,
                                                int* __restrict__ boff,
                                                int* __restrict__ row_ptr) {
    __shared__ int s[SBLK];
    int t = threadIdx.x;
    int x = (t < NSB) ? bsum[t] : 0;
    s[t] = x;
    __syncthreads();
    #pragma unroll
    for (int off = 1; off < SBLK; off <<= 1) {
        int v = (t >= off) ? s[t - off] : 0;
        __syncthreads();
        if (t >= off) s[t] += v;
        __syncthreads();
    }
    if (t < NSB) boff[t] = s[t] - x;          // exclusive
    if (t == 0) row_ptr[NN] = s[SBLK - 1];    // total (= NE)
}

__global__ __launch_bounds__(SBLK) void k_locscan(const int* __restrict__ deg,
                                                  const int* __restrict__ boff,
                                                  int* __restrict__ row_ptr,
                                                  int* __restrict__ cursor) {
    __shared__ int s[SBLK];
    int t = threadIdx.x;
    int i = blockIdx.x * SBLK + t;
    int x = (i < NN) ? deg[i] : 0;
    s[t] = x;
    __syncthreads();
    #pragma unroll
    for (int off = 1; off < SBLK; off <<= 1) {
        int v = (t >= off) ? s[t - off] : 0;
        __syncthreads();
        if (t >= off) s[t] += v;
        __syncthreads();
    }
    if (i < NN) {
        int excl = boff[blockIdx.x] + s[t] - x;
        row_ptr[i] = excl;
        cursor[i] = excl;
    }
}

__global__ void k_fill(const int* __restrict__ src, const int* __restrict__ dst,
                       int* __restrict__ cursor, int* __restrict__ csr_src) {
    int e = blockIdx.x * blockDim.x + threadIdx.x;
    if (e < NE) {
        int p = atomicAdd(&cursor[dst[e]], 1);
        csr_src[p] = src[e];
    }
}

// Pure MFMA GEMM: feat = h @ W[l]. B-fragments come pre-transposed from wbt
// as 16B vector loads. 64-row supertile per block, 4 waves (head each).
__global__ __launch_bounds__(256) void k_gemm_mfma(
        const bf16* __restrict__ h, const bf16* __restrict__ wbt,
        bf16* __restrict__ feat, int l) {
    const int lane = threadIdx.x & 63, wid = threadIdx.x >> 6;
    const int r = lane & 15, q = lane >> 4;
    const int wbase = wid * 32;
    const bf16* Wt = wbt + l * HD * HD;

    short8v bfr[2][4];
    #pragma unroll
    for (int t = 0; t < 2; t++)
        #pragma unroll
        for (int ks = 0; ks < 4; ks++)
            bfr[t][ks] = *reinterpret_cast<const short8v*>(
                Wt + (wbase + t * 16 + r) * HD + ks * 32 + q * 8);

    const int base0 = blockIdx.x * 64;
    #pragma unroll
    for (int mt = 0; mt < 4; mt++) {
        const int base = base0 + mt * 16;
        if (base >= NN) break;
        float4v acc0 = {0.f, 0.f, 0.f, 0.f};
        float4v acc1 = {0.f, 0.f, 0.f, 0.f};
        #pragma unroll
        for (int ks = 0; ks < 4; ks++) {
            short8v a = *reinterpret_cast<const short8v*>(
                h + (base + r) * HD + ks * 32 + q * 8);
            acc0 = __builtin_amdgcn_mfma_f32_16x16x32_bf16(a, bfr[0][ks], acc0, 0, 0, 0);
            acc1 = __builtin_amdgcn_mfma_f32_16x16x32_bf16(a, bfr[1][ks], acc1, 0, 0, 0);
        }
        #pragma unroll
        for (int reg = 0; reg < 4; reg++) {
            const int row = base + q * 4 + reg;
            feat[row * HD + wbase + r]      = f2b(acc0[reg]);
            feat[row * HD + wbase + 16 + r] = f2b(acc1[reg]);
        }
    }
}

// el/er head-dots from feat: thread = (node, head); coalesced 64B feat slice.
__global__ __launch_bounds__(256) void k_elr(
        const bf16* __restrict__ feat, const float* __restrict__ wc,
        float* __restrict__ el, float* __restrict__ er, int l) {
    int t = blockIdx.x * blockDim.x + threadIdx.x;
    if (t >= NN * 4) return;
    int n = t >> 2, head = t & 3;
    const float* alh = wc + OFF_AL + l * HD + head * 32;
    const float* arh = wc + OFF_AR + l * HD + head * 32;
    const u32* f = reinterpret_cast<const u32*>(feat + n * HD + head * 32);
    float e1 = 0.f, e2 = 0.f;
    #pragma unroll
    for (int i = 0; i < 16; i++) {
        u32 v = f[i];
        float lo = bf16lo(v), hi = bf16hi(v);
        e1 += lo * alh[2 * i] + hi * alh[2 * i + 1];
        e2 += lo * arh[2 * i] + hi * arh[2 * i + 1];
    }
    el[t] = e1;
    er[t] = e2;
}

// batched aggregation: C-edge batch, compile-time unrolled, predicated.
// One coalesced csr load per batch; one alpha-exp per lane per batch
// (lane = edge(lane>>2) x head(lane&3)); feat loads all independent.
template <int C>
__device__ __forceinline__ void agg_batch(
        const bf16* __restrict__ feat, const float* __restrict__ el4,
        int rp, int base, int deg, int lane, int hsel, int esub, int hsub,
        float ern_sub, int c0, const int* __restrict__ csr_src,
        float& accA, float& accB, float& z) {
    int cnt = deg - base;           // >0; may exceed C only when C==16 mid-loop
    int sj = 0;
    if (lane < C) {
        int e = base + lane;
        sj = (e < deg) ? csr_src[rp + e] : 0;
    }
    float alpha = 0.f;
    if (esub < C) {
        int se = __shfl(sj, esub, 64);
        float myel = el4[se * 4 + hsub];
        alpha = (esub < cnt) ? __expf(lrelu(myel + ern_sub)) : 0.f;
    }
    #pragma unroll
    for (int e = 0; e < C; e++) {
        int s = __shfl(sj, e, 64);
        float w = __shfl(alpha, e * 4 + hsel, 64);
        u32 f = *reinterpret_cast<const u32*>(feat + s * HD + c0);
        accA += w * bf16lo(f);
        accB += w * bf16hi(f);
        z += w;
    }
}

__global__ __launch_bounds__(256) void k_agg3(
        const bf16* __restrict__ feat, const float* __restrict__ el4,
        const float* __restrict__ er4, const int* __restrict__ row_ptr,
        const int* __restrict__ csr_src, const float* __restrict__ wc,
        bf16* __restrict__ h, int l) {
    int lane = threadIdx.x & 63, wid = threadIdx.x >> 6;
    const int c0 = lane * 2;
    const int hsel = lane >> 4;   // head of my 2 channels
    const int esub = lane >> 2;   // edge slot for alpha duty (0..15)
    const int hsub = lane & 3;    // head for alpha duty
    for (int n = blockIdx.x * 4 + wid; n < NN; n += gridDim.x * 4) {
        int rp = row_ptr[n];
        int deg = row_ptr[n + 1] - rp;
        float ern_sub = er4[n * 4 + hsub];
        float accA = 0.f, accB = 0.f, z = 0.f;
        int base = 0;
        for (; base + 16 <= deg; base += 16)
            agg_batch<16>(feat, el4, rp, base, deg, lane, hsel, esub, hsub,
                          ern_sub, c0, csr_src, accA, accB, z);
        int rem = deg - base;
        if (rem > 8)
            agg_batch<16>(feat, el4, rp, base, deg, lane, hsel, esub, hsub,
                          ern_sub, c0, csr_src, accA, accB, z);
        else if (rem > 0)
            agg_batch<8>(feat, el4, rp, base, deg, lane, hsel, esub, hsub,
                         ern_sub, c0, csr_src, accA, accB, z);
        float rA = deg ? accA / z : 0.f;
        float rB = deg ? accB / z : 0.f;
        u32 hres = *reinterpret_cast<const u32*>(h + n * HD + c0);
        float v0 = rA + bf16lo(hres) + wc[OFF_BIAS + l * HD + c0];
        float v1 = rB + bf16hi(hres) + wc[OFF_BIAS + l * HD + c0 + 1];
        *reinterpret_cast<u32*>(h + n * HD + c0) =
            packbf16(fmaxf(v0, 0.f), fmaxf(v1, 0.f));
    }
}

__global__ __launch_bounds__(256) void k_ln_gate(
        bf16* __restrict__ h, const float* __restrict__ wc,
        float* __restrict__ gate) {
    int lane = threadIdx.x & 63, wid = threadIdx.x >> 6;
    int n = blockIdx.x * 4 + wid;
    if (n >= NN) return;
    float x0 = b2f(h[n * HD + lane]), x1 = b2f(h[n * HD + 64 + lane]);
    float mu = wave_sum64(x0 + x1) * (1.0f / 128.0f);
    float d0 = x0 - mu, d1 = x1 - mu;
    float var = wave_sum64(d0 * d0 + d1 * d1) * (1.0f / 128.0f);
    float rs = rsqrtf(var + 1e-5f);
    float y0 = d0 * rs * wc[OFF_LNG + lane]      + wc[OFF_LNB + lane];
    float y1 = d1 * rs * wc[OFF_LNG + 64 + lane] + wc[OFF_LNB + 64 + lane];
    h[n * HD + lane] = f2b(y0);
    h[n * HD + 64 + lane] = f2b(y1);
    float g = wave_sum64(y0 * wc[OFF_GW + lane] + y1 * wc[OFF_GW + 64 + lane]);
    if (lane == 0) gate[n] = g + wc[OFF_GB];
}

// per-graph gate max + 1/z; computes its own graph bounds (binary search),
// writes gb[] for poolsum, zeroes its zg row (runs before poolsum).
__global__ __launch_bounds__(256) void k_gmaxz(
        const float* __restrict__ gate, const int* __restrict__ gid,
        float* __restrict__ gmax, float* __restrict__ gzinv,
        int* __restrict__ gb, float* __restrict__ zg) {
    __shared__ float red[256];
    __shared__ int sb[2];
    int g = blockIdx.x, tid = threadIdx.x;
    if (tid < 2) {
        int target = g + tid;
        int lo = 0, hi = NN;
        while (lo < hi) {
            int mid = (lo + hi) >> 1;
            if (gid[mid] < target) lo = mid + 1;
            else hi = mid;
        }
        sb[tid] = lo;
        if (tid == 0) gb[g] = lo;
        if (tid == 1 && g == NG - 1) gb[NG] = lo;
    }
    if (tid < HD) zg[g * HD + tid] = 0.f;
    __syncthreads();
    int s0 = sb[0], e0 = sb[1];
    float m = -1e30f;
    for (int i = s0 + tid; i < e0; i += 256) m = fmaxf(m, gate[i]);
    red[tid] = m;
    __syncthreads();
    for (int off = 128; off; off >>= 1) {
        if (tid < off) red[tid] = fmaxf(red[tid], red[tid + off]);
        __syncthreads();
    }
    m = red[0];
    __syncthreads();
    float z = 0.f;
    for (int i = s0 + tid; i < e0; i += 256) z += __expf(gate[i] - m);
    red[tid] = z;
    __syncthreads();
    for (int off = 128; off; off >>= 1) {
        if (tid < off) red[tid] += red[tid + off];
        __syncthreads();
    }
    if (tid == 0) {
        gmax[g] = m;
        gzinv[g] = (e0 > s0 && red[0] > 0.f) ? 1.0f / red[0] : 0.f;
    }
}

// weighted node-sum, PCHUNK blocks per graph, atomicAdd into zeroed zg
__global__ __launch_bounds__(256) void k_poolsum(
        const bf16* __restrict__ h, const float* __restrict__ gate,
        const int* __restrict__ gb, const float* __restrict__ gmax,
        float* __restrict__ zg) {
    __shared__ float red[256];
    int b = blockIdx.x;
    int g = b / PCHUNK, c = b % PCHUNK;
    int s0 = gb[g], e0 = gb[g + 1];
    int len = e0 - s0;
    int beg = s0 + (int)(((long long)len * c) / PCHUNK);
    int end = s0 + (int)(((long long)len * (c + 1)) / PCHUNK);
    int ch = threadIdx.x & 127, half = threadIdx.x >> 7;
    float m = gmax[g];
    float acc = 0.f;
    for (int i = beg + half; i < end; i += 2)
        acc += __expf(gate[i] - m) * b2f(h[i * HD + ch]);
    red[threadIdx.x] = acc;
    __syncthreads();
    if (threadIdx.x < 128) {
        float v = red[threadIdx.x] + red[threadIdx.x + 128];
        if (v != 0.f) atomicAdd(&zg[g * HD + ch], v);
    }
}

__global__ __launch_bounds__(128) void k_mlp(
        const float* __restrict__ zg, const float* __restrict__ gzinv,
        const float* __restrict__ wc, float* __restrict__ out) {
    __shared__ float zr[HD], z1[HD];
    int g = blockIdx.x, tid = threadIdx.x;
    zr[tid] = zg[g * HD + tid] * gzinv[g];
    __syncthreads();
    float acc = wc[OFF_PB1 + tid];
    for (int k = 0; k < HD; k++) acc += zr[k] * wc[OFF_PW1 + k * HD + tid];
    z1[tid] = fmaxf(acc, 0.f);
    __syncthreads();
    if (tid < 64) {
        float a2 = wc[OFF_PB2 + tid];
        for (int k = 0; k < HD; k++) a2 += z1[k] * wc[OFF_PW2 + k * 64 + tid];
        out[g * 64 + tid] = a2;
    }
}

extern "C" void kernel_launch(void* const* d_in, const int* in_sizes, int n_in,
                              void* d_out, int out_size, void* d_ws, size_t ws_size,
                              hipStream_t stream) {
    const int* gate_types = (const int*)d_in[0];
    const int* qubit_idx  = (const int*)d_in[1];
    const int* src        = (const int*)d_in[2];
    const int* dst        = (const int*)d_in[3];
    const int* graph_ids  = (const int*)d_in[4];
    float* out = (float*)d_out;

    const int expect[19] = {NN, NN, NE, NE, NN, 4096, 2560, 49152, 384, 384,
                            384, 128, 128, 128, 1, 16384, 128, 8192, 64};
    for (int i = 0; i < 19 && i < n_in; i++) {
        if (in_sizes[i] != expect[i]) {
            k_diag<<<(out_size + 255) / 256, 256, 0, stream>>>(out, out_size,
                                                               7777000.f + i);
            return;
        }
    }

    char* ws = (char*)d_ws;
    size_t off = 0;
    auto alloc = [&](size_t bytes) {
        void* p = ws + off;
        off = (off + bytes + 255) & ~(size_t)255;
        return p;
    };
    float*  wc      = (float*)alloc(sizeof(float) * CVT_TOTAL);
    bf16*   wbt     = (bf16*)alloc(sizeof(bf16) * NL * HD * HD);
    float*  el      = (float*)alloc(sizeof(float) * NN * 4);
    float*  er      = (float*)alloc(sizeof(float) * NN * 4);
    int*    row_ptr = (int*)alloc(sizeof(int) * (NN + 1));
    int*    deg     = (int*)alloc(sizeof(int) * NN);
    int*    cursor  = (int*)alloc(sizeof(int) * NN);
    int*    csr_src = (int*)alloc(sizeof(int) * NE);
    int*    bsum    = (int*)alloc(sizeof(int) * NSB);
    int*    boff    = (int*)alloc(sizeof(int) * NSB);
    float*  gate    = (float*)alloc(sizeof(float) * NN);
    int*    gb      = (int*)alloc(sizeof(int) * (NG + 1));
    float*  zg      = (float*)alloc(sizeof(float) * NG * HD);
    float*  gmax    = (float*)alloc(sizeof(float) * NG);
    float*  gzinv   = (float*)alloc(sizeof(float) * NG);
    bf16*   h       = (bf16*)alloc(sizeof(bf16) * NN * HD);
    bf16*   feat    = (bf16*)alloc(sizeof(bf16) * NN * HD);

    if (off > ws_size) {
        k_diag<<<(out_size + 255) / 256, 256, 0, stream>>>(
            out, out_size, (float)(ws_size >> 10));
        return;
    }

    CvtSrc cs;
    for (int i = 0; i < 14; i++) cs.p[i] = d_in[5 + i];
    k_convert<<<128, 256, 0, stream>>>(cs, wc, wbt);

    k_embed<<<(NN * 64 + 255) / 256, 256, 0, stream>>>(gate_types, qubit_idx,
                                                       wc, h, deg);
    k_count<<<(NE + 255) / 256, 256, 0, stream>>>(dst, deg);
    k_bsum<<<NSB, SBLK, 0, stream>>>(deg, bsum);
    k_bscan<<<1, SBLK, 0, stream>>>(bsum, boff, row_ptr);
    k_locscan<<<NSB, SBLK, 0, stream>>>(deg, boff, row_ptr, cursor);
    k_fill<<<(NE + 255) / 256, 256, 0, stream>>>(src, dst, cursor, csr_src);

    for (int l = 0; l < NL; l++) {
        k_gemm_mfma<<<GBLK, 256, 0, stream>>>(h, wbt, feat, l);
        k_elr<<<(NN * 4 + 255) / 256, 256, 0, stream>>>(feat, wc, el, er, l);
        k_agg3<<<2048, 256, 0, stream>>>(feat, el, er, row_ptr, csr_src, wc, h, l);
    }
    k_ln_gate<<<(NN + 3) / 4, 256, 0, stream>>>(h, wc, gate);
    k_gmaxz<<<NG, 256, 0, stream>>>(gate, graph_ids, gmax, gzinv, gb, zg);
    k_poolsum<<<NG * PCHUNK, 256, 0, stream>>>(h, gate, gb, gmax, zg);
    k_mlp<<<NG, 128, 0, stream>>>(zg, gzinv, wc, out);
}

// Round 11
// 287.749 us; speedup vs baseline: 3.2220x; 1.1264x over previous
//
#include <hip/hip_runtime.h>
#include <hip/hip_bf16.h>

#define NN 50000
#define NE 600000
#define NG 64
#define HD 128
#define NL 3
#define NEG 0.2f
#define PCHUNK 16     // pooling blocks per graph
#define SBLK 256
#define NSB ((NN + SBLK - 1) / SBLK)   // 196 scan blocks
#define GBLK ((NN + 63) / 64)          // 782 gemm blocks

typedef __hip_bfloat16 bf16;
typedef unsigned short u16;
typedef unsigned int u32;
typedef __attribute__((ext_vector_type(8))) short short8v;      // 8 bf16
typedef __attribute__((ext_vector_type(4))) float float4v;      // MFMA acc

// converted-f32 weight region offsets (element units)
#define OFF_GE    0
#define OFF_QE    4096
#define OFF_W     6656
#define OFF_AL    55808
#define OFF_AR    56192
#define OFF_BIAS  56576
#define OFF_LNG   56960
#define OFF_LNB   57088
#define OFF_GW    57216
#define OFF_GB    57344
#define OFF_PW1   57345
#define OFF_PB1   73729
#define OFF_PW2   73857
#define OFF_PB2   82049
#define CVT_TOTAL 82113

__device__ __forceinline__ float b2f(bf16 x) { return __bfloat162float(x); }
__device__ __forceinline__ bf16 f2b(float x) { return __float2bfloat16(x); }
__device__ __forceinline__ float lrelu(float x) { return x > 0.f ? x : NEG * x; }
__device__ __forceinline__ float bf16lo(u32 u) { return __uint_as_float(u << 16); }
__device__ __forceinline__ float bf16hi(u32 u) { return __uint_as_float(u & 0xffff0000u); }
__device__ __forceinline__ u32 packbf16(float x, float y) {
    bf16 bx = f2b(x), by = f2b(y);
    u16 ux = *reinterpret_cast<u16*>(&bx);
    u16 uy = *reinterpret_cast<u16*>(&by);
    return (u32)ux | ((u32)uy << 16);
}

__device__ __forceinline__ float wave_sum64(float v) {
    #pragma unroll
    for (int m = 1; m < 64; m <<= 1) v += __shfl_xor(v, m, 64);
    return v;
}

// ---- diagnostics ----
__global__ void k_diag(float* out, int n, float code) {
    int i = blockIdx.x * blockDim.x + threadIdx.x;
    if (i < n) out[i] = code;
}

struct CvtSrc { const void* p[14]; };

// convert weights to canonical f32 region + transposed bf16 W + zero deg[].
__global__ __launch_bounds__(256) void k_convert(CvtSrc srcs,
                                                 float* __restrict__ dst,
                                                 bf16* __restrict__ wbt,
                                                 int* __restrict__ deg) {
    __shared__ int cnt;
    if (threadIdx.x == 0) cnt = 0;
    __syncthreads();
    const u16* wraw = (const u16*)srcs.p[2];
    int bad = 0;
    for (int i = threadIdx.x; i < 2048; i += 256) {
        int e = (wraw[i] >> 7) & 0xFF;
        if (e == 0xFF || e >= 0x90) bad++;
    }
    if (bad) atomicAdd(&cnt, bad);
    __syncthreads();
    const bool isf32 = cnt > 16;

    const int starts[15] = {OFF_GE, OFF_QE, OFF_W, OFF_AL, OFF_AR, OFF_BIAS,
                            OFF_LNG, OFF_LNB, OFF_GW, OFF_GB, OFF_PW1, OFF_PB1,
                            OFF_PW2, OFF_PB2, CVT_TOTAL};
    for (int i = blockIdx.x * blockDim.x + threadIdx.x; i < CVT_TOTAL;
         i += gridDim.x * blockDim.x) {
        int a = 0;
        while (i >= starts[a + 1]) a++;
        int off = i - starts[a];
        dst[i] = isf32 ? ((const float*)srcs.p[a])[off]
                       : b2f(((const bf16*)srcs.p[a])[off]);
    }
    // wbt[l][col][k] = bf16(W[l][k][col])  (transposed, MFMA-B-fragment layout)
    for (int i = blockIdx.x * blockDim.x + threadIdx.x; i < NL * HD * HD;
         i += gridDim.x * blockDim.x) {
        int l = i >> 14, rem = i & 16383;
        int col = rem >> 7, k = rem & 127;
        int si = l * 16384 + k * 128 + col;
        float v = isf32 ? ((const float*)srcs.p[2])[si]
                        : b2f(((const bf16*)srcs.p[2])[si]);
        wbt[i] = f2b(v);
    }
    for (int i = blockIdx.x * blockDim.x + threadIdx.x; i < NN;
         i += gridDim.x * blockDim.x)
        deg[i] = 0;
}

// embeddings (2 ch/thread, u32 stores) + fused degree count
__global__ void k_embed(const int* __restrict__ gt, const int* __restrict__ qi,
                        const float* __restrict__ wc, bf16* __restrict__ h,
                        const int* __restrict__ dst, int* __restrict__ deg) {
    int idx = blockIdx.x * blockDim.x + threadIdx.x;
    if (idx < NE) atomicAdd(&deg[dst[idx]], 1);
    if (idx >= NN * 64) return;
    int n = idx >> 6, c = (idx & 63) * 2;
    int g = gt[n], q = qi[n];
    float a0 = wc[OFF_GE + g * HD + c]     + wc[OFF_QE + q * HD + c];
    float a1 = wc[OFF_GE + g * HD + c + 1] + wc[OFF_QE + q * HD + c + 1];
    *reinterpret_cast<u32*>(h + n * HD + c) = packbf16(a0, a1);
}

// ---- 3-phase multi-block exclusive scan of deg -> row_ptr/cursor ----
__global__ __launch_bounds__(SBLK) void k_bsum(const int* __restrict__ deg,
                                               int* __restrict__ bsum) {
    __shared__ int red[SBLK];
    int i = blockIdx.x * SBLK + threadIdx.x;
    red[threadIdx.x] = (i < NN) ? deg[i] : 0;
    __syncthreads();
    for (int off = SBLK / 2; off; off >>= 1) {
        if (threadIdx.x < off) red[threadIdx.x] += red[threadIdx.x + off];
        __syncthreads();
    }
    if (threadIdx.x == 0) bsum[blockIdx.x] = red[0];
}

__global__ __launch_bounds__(SBLK) void k_bscan(const int* __restrict__ bsum,
                                                int* __restrict__ boff,
                                                int* __restrict__ row_ptr) {
    __shared__ int s[SBLK];
    int t = threadIdx.x;
    int x = (t < NSB) ? bsum[t] : 0;
    s[t] = x;
    __syncthreads();
    #pragma unroll
    for (int off = 1; off < SBLK; off <<= 1) {
        int v = (t >= off) ? s[t - off] : 0;
        __syncthreads();
        if (t >= off) s[t] += v;
        __syncthreads();
    }
    if (t < NSB) boff[t] = s[t] - x;          // exclusive
    if (t == 0) row_ptr[NN] = s[SBLK - 1];    // total (= NE)
}

__global__ __launch_bounds__(SBLK) void k_locscan(const int* __restrict__ deg,
                                                  const int* __restrict__ boff,
                                                  int* __restrict__ row_ptr,
                                                  int* __restrict__ cursor) {
    __shared__ int s[SBLK];
    int t = threadIdx.x;
    int i = blockIdx.x * SBLK + t;
    int x = (i < NN) ? deg[i] : 0;
    s[t] = x;
    __syncthreads();
    #pragma unroll
    for (int off = 1; off < SBLK; off <<= 1) {
        int v = (t >= off) ? s[t - off] : 0;
        __syncthreads();
        if (t >= off) s[t] += v;
        __syncthreads();
    }
    if (i < NN) {
        int excl = boff[blockIdx.x] + s[t] - x;
        row_ptr[i] = excl;
        cursor[i] = excl;
    }
}

__global__ void k_fill(const int* __restrict__ src, const int* __restrict__ dst,
                       int* __restrict__ cursor, int* __restrict__ csr_src) {
    int e = blockIdx.x * blockDim.x + threadIdx.x;
    if (e < NE) {
        int p = atomicAdd(&cursor[dst[e]], 1);
        csr_src[p] = src[e];
    }
}

// MFMA GEMM + fused el/er epilogue (16-lane shfl reduce, 8 shfl/reg).
__global__ __launch_bounds__(256) void k_gemm_elr(
        const bf16* __restrict__ h, const bf16* __restrict__ wbt,
        const float* __restrict__ wc, bf16* __restrict__ feat,
        float* __restrict__ el, float* __restrict__ er, int l) {
    const int lane = threadIdx.x & 63, wid = threadIdx.x >> 6;
    const int r = lane & 15, q = lane >> 4;
    const int wbase = wid * 32;
    const bf16* Wt = wbt + l * HD * HD;

    short8v bfr[2][4];
    #pragma unroll
    for (int t = 0; t < 2; t++)
        #pragma unroll
        for (int ks = 0; ks < 4; ks++)
            bfr[t][ks] = *reinterpret_cast<const short8v*>(
                Wt + (wbase + t * 16 + r) * HD + ks * 32 + q * 8);

    const float al0 = wc[OFF_AL + l * HD + wbase + r];
    const float al1 = wc[OFF_AL + l * HD + wbase + 16 + r];
    const float ar0 = wc[OFF_AR + l * HD + wbase + r];
    const float ar1 = wc[OFF_AR + l * HD + wbase + 16 + r];

    const int base0 = blockIdx.x * 64;
    #pragma unroll
    for (int mt = 0; mt < 4; mt++) {
        const int base = base0 + mt * 16;
        if (base >= NN) break;
        float4v acc0 = {0.f, 0.f, 0.f, 0.f};
        float4v acc1 = {0.f, 0.f, 0.f, 0.f};
        #pragma unroll
        for (int ks = 0; ks < 4; ks++) {
            short8v a = *reinterpret_cast<const short8v*>(
                h + (base + r) * HD + ks * 32 + q * 8);
            acc0 = __builtin_amdgcn_mfma_f32_16x16x32_bf16(a, bfr[0][ks], acc0, 0, 0, 0);
            acc1 = __builtin_amdgcn_mfma_f32_16x16x32_bf16(a, bfr[1][ks], acc1, 0, 0, 0);
        }
        #pragma unroll
        for (int reg = 0; reg < 4; reg++) {
            const int row = base + q * 4 + reg;
            feat[row * HD + wbase + r]      = f2b(acc0[reg]);
            feat[row * HD + wbase + 16 + r] = f2b(acc1[reg]);
            float elp = acc0[reg] * al0 + acc1[reg] * al1;
            float erp = acc0[reg] * ar0 + acc1[reg] * ar1;
            #pragma unroll
            for (int m = 1; m < 16; m <<= 1) {
                elp += __shfl_xor(elp, m, 64);
                erp += __shfl_xor(erp, m, 64);
            }
            if (r == 0) {
                el[row * 4 + wid] = elp;
                er[row * 4 + wid] = erp;
            }
        }
    }
}

// aggregation v4: lane = (channel-quad cL = lane&31, edge-parity p = lane>>5).
// u64 feat loads (4 ch each); 2 edges in flight per step; alpha duty lanes
// compute one exp per 16-edge batch; cross-parity combine at node end.
__global__ __launch_bounds__(256) void k_agg4(
        const bf16* __restrict__ feat, const float* __restrict__ el4,
        const float* __restrict__ er4, const int* __restrict__ row_ptr,
        const int* __restrict__ csr_src, const float* __restrict__ wc,
        bf16* __restrict__ h, int l) {
    int lane = threadIdx.x & 63, wid = threadIdx.x >> 6;
    const int cL = lane & 31;      // channels 4*cL .. 4*cL+3
    const int p = lane >> 5;       // edge parity
    const int hq = cL >> 3;        // head of my channels
    const int esub = lane >> 2;    // alpha duty: edge slot 0..15
    const int hsub = lane & 3;     // alpha duty: head
    const int cb = cL * 4;         // first channel
    for (int n = blockIdx.x * 4 + wid; n < NN; n += gridDim.x * 4) {
        int rp = row_ptr[n];
        int deg = row_ptr[n + 1] - rp;
        float ern_sub = er4[n * 4 + hsub];
        float a0 = 0.f, a1 = 0.f, a2 = 0.f, a3 = 0.f, z = 0.f;
        for (int bb = 0; bb < deg; bb += 16) {
            int sj = 0;
            if (lane < 16) {
                int e = bb + lane;
                sj = (e < deg) ? csr_src[rp + e] : 0;
            }
            int se = __shfl(sj, esub, 64);
            float myel = el4[se * 4 + hsub];
            float alpha = (bb + esub < deg)
                              ? __expf(lrelu(myel + ern_sub)) : 0.f;
            #pragma unroll
            for (int bb2 = 0; bb2 < 16; bb2 += 2) {
                int j = bb2 + p;
                int s = __shfl(sj, j, 64);
                float w = __shfl(alpha, 4 * j + hq, 64);
                uint2 f = *reinterpret_cast<const uint2*>(feat + s * HD + cb);
                a0 += w * bf16lo(f.x);
                a1 += w * bf16hi(f.x);
                a2 += w * bf16lo(f.y);
                a3 += w * bf16hi(f.y);
                z += w;
            }
        }
        // combine parities (same channels live in lane and lane^32)
        a0 += __shfl_xor(a0, 32, 64);
        a1 += __shfl_xor(a1, 32, 64);
        a2 += __shfl_xor(a2, 32, 64);
        a3 += __shfl_xor(a3, 32, 64);
        z  += __shfl_xor(z, 32, 64);
        if (p == 0) {
            float inv = (deg && z != 0.f) ? 1.0f / z : 0.f;
            uint2 hv = *reinterpret_cast<const uint2*>(h + n * HD + cb);
            float v0 = a0 * inv + bf16lo(hv.x) + wc[OFF_BIAS + l * HD + cb];
            float v1 = a1 * inv + bf16hi(hv.x) + wc[OFF_BIAS + l * HD + cb + 1];
            float v2 = a2 * inv + bf16lo(hv.y) + wc[OFF_BIAS + l * HD + cb + 2];
            float v3 = a3 * inv + bf16hi(hv.y) + wc[OFF_BIAS + l * HD + cb + 3];
            uint2 o;
            o.x = packbf16(fmaxf(v0, 0.f), fmaxf(v1, 0.f));
            o.y = packbf16(fmaxf(v2, 0.f), fmaxf(v3, 0.f));
            *reinterpret_cast<uint2*>(h + n * HD + cb) = o;
        }
    }
}

__global__ __launch_bounds__(256) void k_ln_gate(
        bf16* __restrict__ h, const float* __restrict__ wc,
        float* __restrict__ gate) {
    int lane = threadIdx.x & 63, wid = threadIdx.x >> 6;
    int n = blockIdx.x * 4 + wid;
    if (n >= NN) return;
    float x0 = b2f(h[n * HD + lane]), x1 = b2f(h[n * HD + 64 + lane]);
    float mu = wave_sum64(x0 + x1) * (1.0f / 128.0f);
    float d0 = x0 - mu, d1 = x1 - mu;
    float var = wave_sum64(d0 * d0 + d1 * d1) * (1.0f / 128.0f);
    float rs = rsqrtf(var + 1e-5f);
    float y0 = d0 * rs * wc[OFF_LNG + lane]      + wc[OFF_LNB + lane];
    float y1 = d1 * rs * wc[OFF_LNG + 64 + lane] + wc[OFF_LNB + 64 + lane];
    h[n * HD + lane] = f2b(y0);
    h[n * HD + 64 + lane] = f2b(y1);
    float g = wave_sum64(y0 * wc[OFF_GW + lane] + y1 * wc[OFF_GW + 64 + lane]);
    if (lane == 0) gate[n] = g + wc[OFF_GB];
}

// per-graph gate max + 1/z; computes its own graph bounds (binary search),
// writes gb[] for poolsum, zeroes its zg row (runs before poolsum).
__global__ __launch_bounds__(256) void k_gmaxz(
        const float* __restrict__ gate, const int* __restrict__ gid,
        float* __restrict__ gmax, float* __restrict__ gzinv,
        int* __restrict__ gb, float* __restrict__ zg) {
    __shared__ float red[256];
    __shared__ int sb[2];
    int g = blockIdx.x, tid = threadIdx.x;
    if (tid < 2) {
        int target = g + tid;
        int lo = 0, hi = NN;
        while (lo < hi) {
            int mid = (lo + hi) >> 1;
            if (gid[mid] < target) lo = mid + 1;
            else hi = mid;
        }
        sb[tid] = lo;
        if (tid == 0) gb[g] = lo;
        if (tid == 1 && g == NG - 1) gb[NG] = lo;
    }
    if (tid < HD) zg[g * HD + tid] = 0.f;
    __syncthreads();
    int s0 = sb[0], e0 = sb[1];
    float m = -1e30f;
    for (int i = s0 + tid; i < e0; i += 256) m = fmaxf(m, gate[i]);
    red[tid] = m;
    __syncthreads();
    for (int off = 128; off; off >>= 1) {
        if (tid < off) red[tid] = fmaxf(red[tid], red[tid + off]);
        __syncthreads();
    }
    m = red[0];
    __syncthreads();
    float z = 0.f;
    for (int i = s0 + tid; i < e0; i += 256) z += __expf(gate[i] - m);
    red[tid] = z;
    __syncthreads();
    for (int off = 128; off; off >>= 1) {
        if (tid < off) red[tid] += red[tid + off];
        __syncthreads();
    }
    if (tid == 0) {
        gmax[g] = m;
        gzinv[g] = (e0 > s0 && red[0] > 0.f) ? 1.0f / red[0] : 0.f;
    }
}

// weighted node-sum, PCHUNK blocks per graph, atomicAdd into zeroed zg
__global__ __launch_bounds__(256) void k_poolsum(
        const bf16* __restrict__ h, const float* __restrict__ gate,
        const int* __restrict__ gb, const float* __restrict__ gmax,
        float* __restrict__ zg) {
    __shared__ float red[256];
    int b = blockIdx.x;
    int g = b / PCHUNK, c = b % PCHUNK;
    int s0 = gb[g], e0 = gb[g + 1];
    int len = e0 - s0;
    int beg = s0 + (int)(((long long)len * c) / PCHUNK);
    int end = s0 + (int)(((long long)len * (c + 1)) / PCHUNK);
    int ch = threadIdx.x & 127, half = threadIdx.x >> 7;
    float m = gmax[g];
    float acc = 0.f;
    for (int i = beg + half; i < end; i += 2)
        acc += __expf(gate[i] - m) * b2f(h[i * HD + ch]);
    red[threadIdx.x] = acc;
    __syncthreads();
    if (threadIdx.x < 128) {
        float v = red[threadIdx.x] + red[threadIdx.x + 128];
        if (v != 0.f) atomicAdd(&zg[g * HD + ch], v);
    }
}

__global__ __launch_bounds__(128) void k_mlp(
        const float* __restrict__ zg, const float* __restrict__ gzinv,
        const float* __restrict__ wc, float* __restrict__ out) {
    __shared__ float zr[HD], z1[HD];
    int g = blockIdx.x, tid = threadIdx.x;
    zr[tid] = zg[g * HD + tid] * gzinv[g];
    __syncthreads();
    float acc = wc[OFF_PB1 + tid];
    for (int k = 0; k < HD; k++) acc += zr[k] * wc[OFF_PW1 + k * HD + tid];
    z1[tid] = fmaxf(acc, 0.f);
    __syncthreads();
    if (tid < 64) {
        float a2 = wc[OFF_PB2 + tid];
        for (int k = 0; k < HD; k++) a2 += z1[k] * wc[OFF_PW2 + k * 64 + tid];
        out[g * 64 + tid] = a2;
    }
}

extern "C" void kernel_launch(void* const* d_in, const int* in_sizes, int n_in,
                              void* d_out, int out_size, void* d_ws, size_t ws_size,
                              hipStream_t stream) {
    const int* gate_types = (const int*)d_in[0];
    const int* qubit_idx  = (const int*)d_in[1];
    const int* src        = (const int*)d_in[2];
    const int* dst        = (const int*)d_in[3];
    const int* graph_ids  = (const int*)d_in[4];
    float* out = (float*)d_out;

    const int expect[19] = {NN, NN, NE, NE, NN, 4096, 2560, 49152, 384, 384,
                            384, 128, 128, 128, 1, 16384, 128, 8192, 64};
    for (int i = 0; i < 19 && i < n_in; i++) {
        if (in_sizes[i] != expect[i]) {
            k_diag<<<(out_size + 255) / 256, 256, 0, stream>>>(out, out_size,
                                                               7777000.f + i);
            return;
        }
    }

    char* ws = (char*)d_ws;
    size_t off = 0;
    auto alloc = [&](size_t bytes) {
        void* p = ws + off;
        off = (off + bytes + 255) & ~(size_t)255;
        return p;
    };
    float*  wc      = (float*)alloc(sizeof(float) * CVT_TOTAL);
    bf16*   wbt     = (bf16*)alloc(sizeof(bf16) * NL * HD * HD);
    float*  el      = (float*)alloc(sizeof(float) * NN * 4);
    float*  er      = (float*)alloc(sizeof(float) * NN * 4);
    int*    row_ptr = (int*)alloc(sizeof(int) * (NN + 1));
    int*    deg     = (int*)alloc(sizeof(int) * NN);
    int*    cursor  = (int*)alloc(sizeof(int) * NN);
    int*    csr_src = (int*)alloc(sizeof(int) * NE);
    int*    bsum    = (int*)alloc(sizeof(int) * NSB);
    int*    boff    = (int*)alloc(sizeof(int) * NSB);
    float*  gate    = (float*)alloc(sizeof(float) * NN);
    int*    gb      = (int*)alloc(sizeof(int) * (NG + 1));
    float*  zg      = (float*)alloc(sizeof(float) * NG * HD);
    float*  gmax    = (float*)alloc(sizeof(float) * NG);
    float*  gzinv   = (float*)alloc(sizeof(float) * NG);
    bf16*   h       = (bf16*)alloc(sizeof(bf16) * NN * HD);
    bf16*   feat    = (bf16*)alloc(sizeof(bf16) * NN * HD);

    if (off > ws_size) {
        k_diag<<<(out_size + 255) / 256, 256, 0, stream>>>(
            out, out_size, (float)(ws_size >> 10));
        return;
    }

    CvtSrc cs;
    for (int i = 0; i < 14; i++) cs.p[i] = d_in[5 + i];
    k_convert<<<128, 256, 0, stream>>>(cs, wc, wbt, deg);

    k_embed<<<(NN * 64 + 255) / 256, 256, 0, stream>>>(gate_types, qubit_idx,
                                                       wc, h, dst, deg);
    k_bsum<<<NSB, SBLK, 0, stream>>>(deg, bsum);
    k_bscan<<<1, SBLK, 0, stream>>>(bsum, boff, row_ptr);
    k_locscan<<<NSB, SBLK, 0, stream>>>(deg, boff, row_ptr, cursor);
    k_fill<<<(NE + 255) / 256, 256, 0, stream>>>(src, dst, cursor, csr_src);

    for (int l = 0; l < NL; l++) {
        k_gemm_elr<<<GBLK, 256, 0, stream>>>(h, wbt, wc, feat, el, er, l);
        k_agg4<<<2048, 256, 0, stream>>>(feat, el, er, row_ptr, csr_src, wc, h, l);
    }
    k_ln_gate<<<(NN + 3) / 4, 256, 0, stream>>>(h, wc, gate);
    k_gmaxz<<<NG, 256, 0, stream>>>(gate, graph_ids, gmax, gzinv, gb, zg);
    k_poolsum<<<NG * PCHUNK, 256, 0, stream>>>(h, gate, gb, gmax, zg);
    k_mlp<<<NG, 128, 0, stream>>>(zg, gzinv, wc, out);
}

// Round 12
// 279.830 us; speedup vs baseline: 3.3132x; 1.0283x over previous
//
#include <hip/hip_runtime.h>
#include <hip/hip_bf16.h>

#define NN 50000
#define NE 600000
#define NG 64
#define HD 128
#define NL 3
#define NEG 0.2f
#define PCHUNK 16     // pooling blocks per graph
#define SBLK 256
#define NSB ((NN + SBLK - 1) / SBLK)   // 196 scan blocks
#define GBLK ((NN + 63) / 64)          // 782 gemm blocks

typedef __hip_bfloat16 bf16;
typedef unsigned short u16;
typedef unsigned int u32;
typedef __attribute__((ext_vector_type(8))) short short8v;      // 8 bf16
typedef __attribute__((ext_vector_type(4))) float float4v;      // MFMA acc

// converted-f32 weight region offsets (element units)
#define OFF_GE    0
#define OFF_QE    4096
#define OFF_W     6656
#define OFF_AL    55808
#define OFF_AR    56192
#define OFF_BIAS  56576
#define OFF_LNG   56960
#define OFF_LNB   57088
#define OFF_GW    57216
#define OFF_GB    57344
#define OFF_PW1   57345
#define OFF_PB1   73729
#define OFF_PW2   73857
#define OFF_PB2   82049
#define CVT_TOTAL 82113

__device__ __forceinline__ float b2f(bf16 x) { return __bfloat162float(x); }
__device__ __forceinline__ bf16 f2b(float x) { return __float2bfloat16(x); }
__device__ __forceinline__ float lrelu(float x) { return x > 0.f ? x : NEG * x; }
__device__ __forceinline__ float bf16lo(u32 u) { return __uint_as_float(u << 16); }
__device__ __forceinline__ float bf16hi(u32 u) { return __uint_as_float(u & 0xffff0000u); }
__device__ __forceinline__ u32 packbf16(float x, float y) {
    bf16 bx = f2b(x), by = f2b(y);
    u16 ux = *reinterpret_cast<u16*>(&bx);
    u16 uy = *reinterpret_cast<u16*>(&by);
    return (u32)ux | ((u32)uy << 16);
}

__device__ __forceinline__ float wave_sum64(float v) {
    #pragma unroll
    for (int m = 1; m < 64; m <<= 1) v += __shfl_xor(v, m, 64);
    return v;
}
__device__ __forceinline__ float grp_sum32(float v) {   // lanes 0..31 only
    #pragma unroll
    for (int m = 1; m < 32; m <<= 1) v += __shfl_xor(v, m, 64);
    return v;
}

// ---- diagnostics ----
__global__ void k_diag(float* out, int n, float code) {
    int i = blockIdx.x * blockDim.x + threadIdx.x;
    if (i < n) out[i] = code;
}

struct CvtSrc { const void* p[14]; };

// convert weights to canonical f32 region + transposed bf16 W + zero deg[].
__global__ __launch_bounds__(256) void k_convert(CvtSrc srcs,
                                                 float* __restrict__ dst,
                                                 bf16* __restrict__ wbt,
                                                 int* __restrict__ deg) {
    __shared__ int cnt;
    if (threadIdx.x == 0) cnt = 0;
    __syncthreads();
    const u16* wraw = (const u16*)srcs.p[2];
    int bad = 0;
    for (int i = threadIdx.x; i < 2048; i += 256) {
        int e = (wraw[i] >> 7) & 0xFF;
        if (e == 0xFF || e >= 0x90) bad++;
    }
    if (bad) atomicAdd(&cnt, bad);
    __syncthreads();
    const bool isf32 = cnt > 16;

    const int starts[15] = {OFF_GE, OFF_QE, OFF_W, OFF_AL, OFF_AR, OFF_BIAS,
                            OFF_LNG, OFF_LNB, OFF_GW, OFF_GB, OFF_PW1, OFF_PB1,
                            OFF_PW2, OFF_PB2, CVT_TOTAL};
    for (int i = blockIdx.x * blockDim.x + threadIdx.x; i < CVT_TOTAL;
         i += gridDim.x * blockDim.x) {
        int a = 0;
        while (i >= starts[a + 1]) a++;
        int off = i - starts[a];
        dst[i] = isf32 ? ((const float*)srcs.p[a])[off]
                       : b2f(((const bf16*)srcs.p[a])[off]);
    }
    // wbt[l][col][k] = bf16(W[l][k][col])  (transposed, MFMA-B-fragment layout)
    for (int i = blockIdx.x * blockDim.x + threadIdx.x; i < NL * HD * HD;
         i += gridDim.x * blockDim.x) {
        int l = i >> 14, rem = i & 16383;
        int col = rem >> 7, k = rem & 127;
        int si = l * 16384 + k * 128 + col;
        float v = isf32 ? ((const float*)srcs.p[2])[si]
                        : b2f(((const bf16*)srcs.p[2])[si]);
        wbt[i] = f2b(v);
    }
    for (int i = blockIdx.x * blockDim.x + threadIdx.x; i < NN;
         i += gridDim.x * blockDim.x)
        deg[i] = 0;
}

// embeddings (2 ch/thread, u32 stores) + fused degree count
__global__ void k_embed(const int* __restrict__ gt, const int* __restrict__ qi,
                        const float* __restrict__ wc, bf16* __restrict__ h,
                        const int* __restrict__ dst, int* __restrict__ deg) {
    int idx = blockIdx.x * blockDim.x + threadIdx.x;
    if (idx < NE) atomicAdd(&deg[dst[idx]], 1);
    if (idx >= NN * 64) return;
    int n = idx >> 6, c = (idx & 63) * 2;
    int g = gt[n], q = qi[n];
    float a0 = wc[OFF_GE + g * HD + c]     + wc[OFF_QE + q * HD + c];
    float a1 = wc[OFF_GE + g * HD + c + 1] + wc[OFF_QE + q * HD + c + 1];
    *reinterpret_cast<u32*>(h + n * HD + c) = packbf16(a0, a1);
}

// ---- 3-phase multi-block exclusive scan of deg -> row_ptr/cursor ----
__global__ __launch_bounds__(SBLK) void k_bsum(const int* __restrict__ deg,
                                               int* __restrict__ bsum) {
    __shared__ int red[SBLK];
    int i = blockIdx.x * SBLK + threadIdx.x;
    red[threadIdx.x] = (i < NN) ? deg[i] : 0;
    __syncthreads();
    for (int off = SBLK / 2; off; off >>= 1) {
        if (threadIdx.x < off) red[threadIdx.x] += red[threadIdx.x + off];
        __syncthreads();
    }
    if (threadIdx.x == 0) bsum[blockIdx.x] = red[0];
}

__global__ __launch_bounds__(SBLK) void k_bscan(const int* __restrict__ bsum,
                                                int* __restrict__ boff,
                                                int* __restrict__ row_ptr) {
    __shared__ int s[SBLK];
    int t = threadIdx.x;
    int x = (t < NSB) ? bsum[t] : 0;
    s[t] = x;
    __syncthreads();
    #pragma unroll
    for (int off = 1; off < SBLK; off <<= 1) {
        int v = (t >= off) ? s[t - off] : 0;
        __syncthreads();
        if (t >= off) s[t] += v;
        __syncthreads();
    }
    if (t < NSB) boff[t] = s[t] - x;          // exclusive
    if (t == 0) row_ptr[NN] = s[SBLK - 1];    // total (= NE)
}

__global__ __launch_bounds__(SBLK) void k_locscan(const int* __restrict__ deg,
                                                  const int* __restrict__ boff,
                                                  int* __restrict__ row_ptr,
                                                  int* __restrict__ cursor) {
    __shared__ int s[SBLK];
    int t = threadIdx.x;
    int i = blockIdx.x * SBLK + t;
    int x = (i < NN) ? deg[i] : 0;
    s[t] = x;
    __syncthreads();
    #pragma unroll
    for (int off = 1; off < SBLK; off <<= 1) {
        int v = (t >= off) ? s[t - off] : 0;
        __syncthreads();
        if (t >= off) s[t] += v;
        __syncthreads();
    }
    if (i < NN) {
        int excl = boff[blockIdx.x] + s[t] - x;
        row_ptr[i] = excl;
        cursor[i] = excl;
    }
}

__global__ void k_fill(const int* __restrict__ src, const int* __restrict__ dst,
                       int* __restrict__ cursor, int* __restrict__ csr_src) {
    int e = blockIdx.x * blockDim.x + threadIdx.x;
    if (e < NE) {
        int p = atomicAdd(&cursor[dst[e]], 1);
        csr_src[p] = src[e];
    }
}

// MFMA GEMM + fused el/er epilogue. Packed-channel permutation: B0 slot r
// holds channel wbase+2r, B1 holds wbase+2r+1 -> lane's acc0/acc1 are
// ADJACENT channels -> one u32 store per reg (not two 2B stores).
__global__ __launch_bounds__(256) void k_gemm_elr(
        const bf16* __restrict__ h, const bf16* __restrict__ wbt,
        const float* __restrict__ wc, bf16* __restrict__ feat,
        float* __restrict__ el, float* __restrict__ er, int l) {
    const int lane = threadIdx.x & 63, wid = threadIdx.x >> 6;
    const int r = lane & 15, q = lane >> 4;
    const int wbase = wid * 32;
    const bf16* Wt = wbt + l * HD * HD;

    short8v bfr[2][4];
    #pragma unroll
    for (int t = 0; t < 2; t++)
        #pragma unroll
        for (int ks = 0; ks < 4; ks++)
            bfr[t][ks] = *reinterpret_cast<const short8v*>(
                Wt + (wbase + 2 * r + t) * HD + ks * 32 + q * 8);

    const float al0 = wc[OFF_AL + l * HD + wbase + 2 * r];
    const float al1 = wc[OFF_AL + l * HD + wbase + 2 * r + 1];
    const float ar0 = wc[OFF_AR + l * HD + wbase + 2 * r];
    const float ar1 = wc[OFF_AR + l * HD + wbase + 2 * r + 1];

    const int base0 = blockIdx.x * 64;
    #pragma unroll
    for (int mt = 0; mt < 4; mt++) {
        const int base = base0 + mt * 16;
        if (base >= NN) break;
        float4v acc0 = {0.f, 0.f, 0.f, 0.f};
        float4v acc1 = {0.f, 0.f, 0.f, 0.f};
        #pragma unroll
        for (int ks = 0; ks < 4; ks++) {
            short8v a = *reinterpret_cast<const short8v*>(
                h + (base + r) * HD + ks * 32 + q * 8);
            acc0 = __builtin_amdgcn_mfma_f32_16x16x32_bf16(a, bfr[0][ks], acc0, 0, 0, 0);
            acc1 = __builtin_amdgcn_mfma_f32_16x16x32_bf16(a, bfr[1][ks], acc1, 0, 0, 0);
        }
        #pragma unroll
        for (int reg = 0; reg < 4; reg++) {
            const int row = base + q * 4 + reg;
            *reinterpret_cast<u32*>(feat + row * HD + wbase + 2 * r) =
                packbf16(acc0[reg], acc1[reg]);
            float elp = acc0[reg] * al0 + acc1[reg] * al1;
            float erp = acc0[reg] * ar0 + acc1[reg] * ar1;
            #pragma unroll
            for (int m = 1; m < 16; m <<= 1) {
                elp += __shfl_xor(elp, m, 64);
                erp += __shfl_xor(erp, m, 64);
            }
            if (r == 0) {
                el[row * 4 + wid] = elp;
                er[row * 4 + wid] = erp;
            }
        }
    }
}

// aggregation v4 (+optional fused LayerNorm/gate for the last layer).
// lane = (channel-quad cL = lane&31, edge-parity p = lane>>5).
template <bool LAST>
__global__ __launch_bounds__(256) void k_agg4(
        const bf16* __restrict__ feat, const float* __restrict__ el4,
        const float* __restrict__ er4, const int* __restrict__ row_ptr,
        const int* __restrict__ csr_src, const float* __restrict__ wc,
        bf16* __restrict__ h, float* __restrict__ gate, int l) {
    int lane = threadIdx.x & 63, wid = threadIdx.x >> 6;
    const int cL = lane & 31;      // channels 4*cL .. 4*cL+3
    const int p = lane >> 5;       // edge parity
    const int hq = cL >> 3;        // head of my channels
    const int esub = lane >> 2;    // alpha duty: edge slot 0..15
    const int hsub = lane & 3;     // alpha duty: head
    const int cb = cL * 4;         // first channel
    for (int n = blockIdx.x * 4 + wid; n < NN; n += gridDim.x * 4) {
        int rp = row_ptr[n];
        int deg = row_ptr[n + 1] - rp;
        float ern_sub = er4[n * 4 + hsub];
        float a0 = 0.f, a1 = 0.f, a2 = 0.f, a3 = 0.f, z = 0.f;
        for (int bb = 0; bb < deg; bb += 16) {
            int sj = 0;
            if (lane < 16) {
                int e = bb + lane;
                sj = (e < deg) ? csr_src[rp + e] : 0;
            }
            int se = __shfl(sj, esub, 64);
            float myel = el4[se * 4 + hsub];
            float alpha = (bb + esub < deg)
                              ? __expf(lrelu(myel + ern_sub)) : 0.f;
            #pragma unroll
            for (int bb2 = 0; bb2 < 16; bb2 += 2) {
                int j = bb2 + p;
                int s = __shfl(sj, j, 64);
                float w = __shfl(alpha, 4 * j + hq, 64);
                uint2 f = *reinterpret_cast<const uint2*>(feat + s * HD + cb);
                a0 += w * bf16lo(f.x);
                a1 += w * bf16hi(f.x);
                a2 += w * bf16lo(f.y);
                a3 += w * bf16hi(f.y);
                z += w;
            }
        }
        // combine parities (same channels live in lane and lane^32)
        a0 += __shfl_xor(a0, 32, 64);
        a1 += __shfl_xor(a1, 32, 64);
        a2 += __shfl_xor(a2, 32, 64);
        a3 += __shfl_xor(a3, 32, 64);
        z  += __shfl_xor(z, 32, 64);
        if (p == 0) {
            float inv = (deg && z != 0.f) ? 1.0f / z : 0.f;
            uint2 hv = *reinterpret_cast<const uint2*>(h + n * HD + cb);
            float v0 = fmaxf(a0 * inv + bf16lo(hv.x) + wc[OFF_BIAS + l * HD + cb], 0.f);
            float v1 = fmaxf(a1 * inv + bf16hi(hv.x) + wc[OFF_BIAS + l * HD + cb + 1], 0.f);
            float v2 = fmaxf(a2 * inv + bf16lo(hv.y) + wc[OFF_BIAS + l * HD + cb + 2], 0.f);
            float v3 = fmaxf(a3 * inv + bf16hi(hv.y) + wc[OFF_BIAS + l * HD + cb + 3], 0.f);
            if (!LAST) {
                uint2 o;
                o.x = packbf16(v0, v1);
                o.y = packbf16(v2, v3);
                *reinterpret_cast<uint2*>(h + n * HD + cb) = o;
            } else {
                // fused LayerNorm + gate (row distributed over lanes 0..31)
                float mu = grp_sum32(v0 + v1 + v2 + v3) * (1.0f / 128.0f);
                float d0 = v0 - mu, d1 = v1 - mu, d2 = v2 - mu, d3 = v3 - mu;
                float var = grp_sum32(d0 * d0 + d1 * d1 + d2 * d2 + d3 * d3)
                            * (1.0f / 128.0f);
                float rs = rsqrtf(var + 1e-5f);
                float y0 = d0 * rs * wc[OFF_LNG + cb]     + wc[OFF_LNB + cb];
                float y1 = d1 * rs * wc[OFF_LNG + cb + 1] + wc[OFF_LNB + cb + 1];
                float y2 = d2 * rs * wc[OFF_LNG + cb + 2] + wc[OFF_LNB + cb + 2];
                float y3 = d3 * rs * wc[OFF_LNG + cb + 3] + wc[OFF_LNB + cb + 3];
                uint2 o;
                o.x = packbf16(y0, y1);
                o.y = packbf16(y2, y3);
                *reinterpret_cast<uint2*>(h + n * HD + cb) = o;
                float gd = y0 * wc[OFF_GW + cb]     + y1 * wc[OFF_GW + cb + 1] +
                           y2 * wc[OFF_GW + cb + 2] + y3 * wc[OFF_GW + cb + 3];
                gd = grp_sum32(gd);
                if (lane == 0) gate[n] = gd + wc[OFF_GB];
            }
        }
    }
}

// per-graph gate max + 1/z; computes its own graph bounds (binary search),
// writes gb[] for poolsum, zeroes its zg row (runs before poolsum).
__global__ __launch_bounds__(256) void k_gmaxz(
        const float* __restrict__ gate, const int* __restrict__ gid,
        float* __restrict__ gmax, float* __restrict__ gzinv,
        int* __restrict__ gb, float* __restrict__ zg) {
    __shared__ float red[256];
    __shared__ int sb[2];
    int g = blockIdx.x, tid = threadIdx.x;
    if (tid < 2) {
        int target = g + tid;
        int lo = 0, hi = NN;
        while (lo < hi) {
            int mid = (lo + hi) >> 1;
            if (gid[mid] < target) lo = mid + 1;
            else hi = mid;
        }
        sb[tid] = lo;
        if (tid == 0) gb[g] = lo;
        if (tid == 1 && g == NG - 1) gb[NG] = lo;
    }
    if (tid < HD) zg[g * HD + tid] = 0.f;
    __syncthreads();
    int s0 = sb[0], e0 = sb[1];
    float m = -1e30f;
    for (int i = s0 + tid; i < e0; i += 256) m = fmaxf(m, gate[i]);
    red[tid] = m;
    __syncthreads();
    for (int off = 128; off; off >>= 1) {
        if (tid < off) red[tid] = fmaxf(red[tid], red[tid + off]);
        __syncthreads();
    }
    m = red[0];
    __syncthreads();
    float z = 0.f;
    for (int i = s0 + tid; i < e0; i += 256) z += __expf(gate[i] - m);
    red[tid] = z;
    __syncthreads();
    for (int off = 128; off; off >>= 1) {
        if (tid < off) red[tid] += red[tid + off];
        __syncthreads();
    }
    if (tid == 0) {
        gmax[g] = m;
        gzinv[g] = (e0 > s0 && red[0] > 0.f) ? 1.0f / red[0] : 0.f;
    }
}

// weighted node-sum, PCHUNK blocks per graph, atomicAdd into zeroed zg
__global__ __launch_bounds__(256) void k_poolsum(
        const bf16* __restrict__ h, const float* __restrict__ gate,
        const int* __restrict__ gb, const float* __restrict__ gmax,
        float* __restrict__ zg) {
    __shared__ float red[256];
    int b = blockIdx.x;
    int g = b / PCHUNK, c = b % PCHUNK;
    int s0 = gb[g], e0 = gb[g + 1];
    int len = e0 - s0;
    int beg = s0 + (int)(((long long)len * c) / PCHUNK);
    int end = s0 + (int)(((long long)len * (c + 1)) / PCHUNK);
    int ch = threadIdx.x & 127, half = threadIdx.x >> 7;
    float m = gmax[g];
    float acc = 0.f;
    for (int i = beg + half; i < end; i += 2)
        acc += __expf(gate[i] - m) * b2f(h[i * HD + ch]);
    red[threadIdx.x] = acc;
    __syncthreads();
    if (threadIdx.x < 128) {
        float v = red[threadIdx.x] + red[threadIdx.x + 128];
        if (v != 0.f) atomicAdd(&zg[g * HD + ch], v);
    }
}

__global__ __launch_bounds__(128) void k_mlp(
        const float* __restrict__ zg, const float* __restrict__ gzinv,
        const float* __restrict__ wc, float* __restrict__ out) {
    __shared__ float zr[HD], z1[HD];
    int g = blockIdx.x, tid = threadIdx.x;
    zr[tid] = zg[g * HD + tid] * gzinv[g];
    __syncthreads();
    float acc = wc[OFF_PB1 + tid];
    for (int k = 0; k < HD; k++) acc += zr[k] * wc[OFF_PW1 + k * HD + tid];
    z1[tid] = fmaxf(acc, 0.f);
    __syncthreads();
    if (tid < 64) {
        float a2 = wc[OFF_PB2 + tid];
        for (int k = 0; k < HD; k++) a2 += z1[k] * wc[OFF_PW2 + k * 64 + tid];
        out[g * 64 + tid] = a2;
    }
}

extern "C" void kernel_launch(void* const* d_in, const int* in_sizes, int n_in,
                              void* d_out, int out_size, void* d_ws, size_t ws_size,
                              hipStream_t stream) {
    const int* gate_types = (const int*)d_in[0];
    const int* qubit_idx  = (const int*)d_in[1];
    const int* src        = (const int*)d_in[2];
    const int* dst        = (const int*)d_in[3];
    const int* graph_ids  = (const int*)d_in[4];
    float* out = (float*)d_out;

    const int expect[19] = {NN, NN, NE, NE, NN, 4096, 2560, 49152, 384, 384,
                            384, 128, 128, 128, 1, 16384, 128, 8192, 64};
    for (int i = 0; i < 19 && i < n_in; i++) {
        if (in_sizes[i] != expect[i]) {
            k_diag<<<(out_size + 255) / 256, 256, 0, stream>>>(out, out_size,
                                                               7777000.f + i);
            return;
        }
    }

    char* ws = (char*)d_ws;
    size_t off = 0;
    auto alloc = [&](size_t bytes) {
        void* p = ws + off;
        off = (off + bytes + 255) & ~(size_t)255;
        return p;
    };
    float*  wc      = (float*)alloc(sizeof(float) * CVT_TOTAL);
    bf16*   wbt     = (bf16*)alloc(sizeof(bf16) * NL * HD * HD);
    float*  el      = (float*)alloc(sizeof(float) * NN * 4);
    float*  er      = (float*)alloc(sizeof(float) * NN * 4);
    int*    row_ptr = (int*)alloc(sizeof(int) * (NN + 1));
    int*    deg     = (int*)alloc(sizeof(int) * NN);
    int*    cursor  = (int*)alloc(sizeof(int) * NN);
    int*    csr_src = (int*)alloc(sizeof(int) * NE);
    int*    bsum    = (int*)alloc(sizeof(int) * NSB);
    int*    boff    = (int*)alloc(sizeof(int) * NSB);
    float*  gate    = (float*)alloc(sizeof(float) * NN);
    int*    gb      = (int*)alloc(sizeof(int) * (NG + 1));
    float*  zg      = (float*)alloc(sizeof(float) * NG * HD);
    float*  gmax    = (float*)alloc(sizeof(float) * NG);
    float*  gzinv   = (float*)alloc(sizeof(float) * NG);
    bf16*   h       = (bf16*)alloc(sizeof(bf16) * NN * HD);
    bf16*   feat    = (bf16*)alloc(sizeof(bf16) * NN * HD);

    if (off > ws_size) {
        k_diag<<<(out_size + 255) / 256, 256, 0, stream>>>(
            out, out_size, (float)(ws_size >> 10));
        return;
    }

    CvtSrc cs;
    for (int i = 0; i < 14; i++) cs.p[i] = d_in[5 + i];
    k_convert<<<256, 256, 0, stream>>>(cs, wc, wbt, deg);

    k_embed<<<(NN * 64 + 255) / 256, 256, 0, stream>>>(gate_types, qubit_idx,
                                                       wc, h, dst, deg);
    k_bsum<<<NSB, SBLK, 0, stream>>>(deg, bsum);
    k_bscan<<<1, SBLK, 0, stream>>>(bsum, boff, row_ptr);
    k_locscan<<<NSB, SBLK, 0, stream>>>(deg, boff, row_ptr, cursor);
    k_fill<<<(NE + 255) / 256, 256, 0, stream>>>(src, dst, cursor, csr_src);

    for (int l = 0; l < NL; l++) {
        k_gemm_elr<<<GBLK, 256, 0, stream>>>(h, wbt, wc, feat, el, er, l);
        if (l < NL - 1)
            k_agg4<false><<<2048, 256, 0, stream>>>(feat, el, er, row_ptr,
                                                    csr_src, wc, h, gate, l);
        else
            k_agg4<true><<<2048, 256, 0, stream>>>(feat, el, er, row_ptr,
                                                   csr_src, wc, h, gate, l);
    }
    k_gmaxz<<<NG, 256, 0, stream>>>(gate, graph_ids, gmax, gzinv, gb, zg);
    k_poolsum<<<NG * PCHUNK, 256, 0, stream>>>(h, gate, gb, gmax, zg);
    k_mlp<<<NG, 128, 0, stream>>>(zg, gzinv, wc, out);
}

// Round 13
// 266.315 us; speedup vs baseline: 3.4814x; 1.0508x over previous
//
#include <hip/hip_runtime.h>
#include <hip/hip_bf16.h>
#include <hip/hip_fp8.h>

#define NN 50000
#define NE 600000
#define NG 64
#define HD 128
#define NL 3
#define NEG 0.2f
#define PCHUNK 16     // pooling blocks per graph
#define SBLK 256
#define NSB ((NN + SBLK - 1) / SBLK)   // 196 scan blocks
#define GBLK ((NN + 63) / 64)          // 782 gemm blocks

typedef __hip_bfloat16 bf16;
typedef unsigned short u16;
typedef unsigned int u32;
typedef unsigned char u8;
typedef __attribute__((ext_vector_type(8))) short short8v;      // 8 bf16
typedef __attribute__((ext_vector_type(4))) float float4v;      // MFMA acc
typedef __attribute__((ext_vector_type(2))) float float2v;

// converted-f32 weight region offsets (element units)
#define OFF_GE    0
#define OFF_QE    4096
#define OFF_W     6656
#define OFF_AL    55808
#define OFF_AR    56192
#define OFF_BIAS  56576
#define OFF_LNG   56960
#define OFF_LNB   57088
#define OFF_GW    57216
#define OFF_GB    57344
#define OFF_PW1   57345
#define OFF_PB1   73729
#define OFF_PW2   73857
#define OFF_PB2   82049
#define CVT_TOTAL 82113

__device__ __forceinline__ float b2f(bf16 x) { return __bfloat162float(x); }
__device__ __forceinline__ bf16 f2b(float x) { return __float2bfloat16(x); }
__device__ __forceinline__ float lrelu(float x) { return x > 0.f ? x : NEG * x; }
__device__ __forceinline__ float bf16lo(u32 u) { return __uint_as_float(u << 16); }
__device__ __forceinline__ float bf16hi(u32 u) { return __uint_as_float(u & 0xffff0000u); }
__device__ __forceinline__ u32 packbf16(float x, float y) {
    bf16 bx = f2b(x), by = f2b(y);
    u16 ux = *reinterpret_cast<u16*>(&bx);
    u16 uy = *reinterpret_cast<u16*>(&by);
    return (u32)ux | ((u32)uy << 16);
}

// ---- fp8 e4m3 (OCP) encode/decode via HW cvt ----
__device__ __forceinline__ u16 enc2fp8(float a, float b) {
#if __has_builtin(__builtin_amdgcn_cvt_pk_fp8_f32)
    return (u16)__builtin_amdgcn_cvt_pk_fp8_f32(a, b, 0, false);
#else
    __hip_fp8_e4m3 fa(a), fb(b);
    return (u16)fa.__x | ((u16)fb.__x << 8);
#endif
}
__device__ __forceinline__ void dec4fp8(u32 v, float& x0, float& x1,
                                        float& x2, float& x3) {
#if __has_builtin(__builtin_amdgcn_cvt_pk_f32_fp8)
    float2v lo = __builtin_amdgcn_cvt_pk_f32_fp8((int)v, false);
    float2v hi = __builtin_amdgcn_cvt_pk_f32_fp8((int)v, true);
    x0 = lo[0]; x1 = lo[1]; x2 = hi[0]; x3 = hi[1];
#else
    __hip_fp8_e4m3 t0, t1, t2, t3;
    t0.__x = v & 0xff; t1.__x = (v >> 8) & 0xff;
    t2.__x = (v >> 16) & 0xff; t3.__x = (v >> 24) & 0xff;
    x0 = (float)t0; x1 = (float)t1; x2 = (float)t2; x3 = (float)t3;
#endif
}

__device__ __forceinline__ float wave_sum64(float v) {
    #pragma unroll
    for (int m = 1; m < 64; m <<= 1) v += __shfl_xor(v, m, 64);
    return v;
}
__device__ __forceinline__ float grp_sum32(float v) {   // lanes 0..31 only
    #pragma unroll
    for (int m = 1; m < 32; m <<= 1) v += __shfl_xor(v, m, 64);
    return v;
}

// ---- diagnostics ----
__global__ void k_diag(float* out, int n, float code) {
    int i = blockIdx.x * blockDim.x + threadIdx.x;
    if (i < n) out[i] = code;
}

struct CvtSrc { const void* p[14]; };

// convert weights to canonical f32 region + transposed bf16 W + zero deg[].
__global__ __launch_bounds__(256) void k_convert(CvtSrc srcs,
                                                 float* __restrict__ dst,
                                                 bf16* __restrict__ wbt,
                                                 int* __restrict__ deg) {
    __shared__ int cnt;
    if (threadIdx.x == 0) cnt = 0;
    __syncthreads();
    const u16* wraw = (const u16*)srcs.p[2];
    int bad = 0;
    for (int i = threadIdx.x; i < 2048; i += 256) {
        int e = (wraw[i] >> 7) & 0xFF;
        if (e == 0xFF || e >= 0x90) bad++;
    }
    if (bad) atomicAdd(&cnt, bad);
    __syncthreads();
    const bool isf32 = cnt > 16;

    const int starts[15] = {OFF_GE, OFF_QE, OFF_W, OFF_AL, OFF_AR, OFF_BIAS,
                            OFF_LNG, OFF_LNB, OFF_GW, OFF_GB, OFF_PW1, OFF_PB1,
                            OFF_PW2, OFF_PB2, CVT_TOTAL};
    for (int i = blockIdx.x * blockDim.x + threadIdx.x; i < CVT_TOTAL;
         i += gridDim.x * blockDim.x) {
        int a = 0;
        while (i >= starts[a + 1]) a++;
        int off = i - starts[a];
        dst[i] = isf32 ? ((const float*)srcs.p[a])[off]
                       : b2f(((const bf16*)srcs.p[a])[off]);
    }
    // wbt[l][col][k] = bf16(W[l][k][col])  (transposed, MFMA-B-fragment layout)
    for (int i = blockIdx.x * blockDim.x + threadIdx.x; i < NL * HD * HD;
         i += gridDim.x * blockDim.x) {
        int l = i >> 14, rem = i & 16383;
        int col = rem >> 7, k = rem & 127;
        int si = l * 16384 + k * 128 + col;
        float v = isf32 ? ((const float*)srcs.p[2])[si]
                        : b2f(((const bf16*)srcs.p[2])[si]);
        wbt[i] = f2b(v);
    }
    for (int i = blockIdx.x * blockDim.x + threadIdx.x; i < NN;
         i += gridDim.x * blockDim.x)
        deg[i] = 0;
}

// embeddings (2 ch/thread, u32 stores) + fused degree count
__global__ void k_embed(const int* __restrict__ gt, const int* __restrict__ qi,
                        const float* __restrict__ wc, bf16* __restrict__ h,
                        const int* __restrict__ dst, int* __restrict__ deg) {
    int idx = blockIdx.x * blockDim.x + threadIdx.x;
    if (idx < NE) atomicAdd(&deg[dst[idx]], 1);
    if (idx >= NN * 64) return;
    int n = idx >> 6, c = (idx & 63) * 2;
    int g = gt[n], q = qi[n];
    float a0 = wc[OFF_GE + g * HD + c]     + wc[OFF_QE + q * HD + c];
    float a1 = wc[OFF_GE + g * HD + c + 1] + wc[OFF_QE + q * HD + c + 1];
    *reinterpret_cast<u32*>(h + n * HD + c) = packbf16(a0, a1);
}

// ---- 3-phase multi-block exclusive scan of deg -> row_ptr/cursor ----
__global__ __launch_bounds__(SBLK) void k_bsum(const int* __restrict__ deg,
                                               int* __restrict__ bsum) {
    __shared__ int red[SBLK];
    int i = blockIdx.x * SBLK + threadIdx.x;
    red[threadIdx.x] = (i < NN) ? deg[i] : 0;
    __syncthreads();
    for (int off = SBLK / 2; off; off >>= 1) {
        if (threadIdx.x < off) red[threadIdx.x] += red[threadIdx.x + off];
        __syncthreads();
    }
    if (threadIdx.x == 0) bsum[blockIdx.x] = red[0];
}

__global__ __launch_bounds__(SBLK) void k_bscan(const int* __restrict__ bsum,
                                                int* __restrict__ boff,
                                                int* __restrict__ row_ptr) {
    __shared__ int s[SBLK];
    int t = threadIdx.x;
    int x = (t < NSB) ? bsum[t] : 0;
    s[t] = x;
    __syncthreads();
    #pragma unroll
    for (int off = 1; off < SBLK; off <<= 1) {
        int v = (t >= off) ? s[t - off] : 0;
        __syncthreads();
        if (t >= off) s[t] += v;
        __syncthreads();
    }
    if (t < NSB) boff[t] = s[t] - x;          // exclusive
    if (t == 0) row_ptr[NN] = s[SBLK - 1];    // total (= NE)
}

__global__ __launch_bounds__(SBLK) void k_locscan(const int* __restrict__ deg,
                                                  const int* __restrict__ boff,
                                                  int* __restrict__ row_ptr,
                                                  int* __restrict__ cursor) {
    __shared__ int s[SBLK];
    int t = threadIdx.x;
    int i = blockIdx.x * SBLK + t;
    int x = (i < NN) ? deg[i] : 0;
    s[t] = x;
    __syncthreads();
    #pragma unroll
    for (int off = 1; off < SBLK; off <<= 1) {
        int v = (t >= off) ? s[t - off] : 0;
        __syncthreads();
        if (t >= off) s[t] += v;
        __syncthreads();
    }
    if (i < NN) {
        int excl = boff[blockIdx.x] + s[t] - x;
        row_ptr[i] = excl;
        cursor[i] = excl;
    }
}

__global__ void k_fill(const int* __restrict__ src, const int* __restrict__ dst,
                       int* __restrict__ cursor, int* __restrict__ csr_src) {
    int e = blockIdx.x * blockDim.x + threadIdx.x;
    if (e < NE) {
        int p = atomicAdd(&cursor[dst[e]], 1);
        csr_src[p] = src[e];
    }
}

// MFMA GEMM + fused el/er epilogue. Packed-channel permutation: B0 slot r
// holds channel wbase+2r, B1 holds wbase+2r+1 -> lane's acc0/acc1 are
// ADJACENT channels. feat stored fp8 e4m3 (consumed only by the gather).
__global__ __launch_bounds__(256) void k_gemm_elr(
        const bf16* __restrict__ h, const bf16* __restrict__ wbt,
        const float* __restrict__ wc, u8* __restrict__ feat8,
        float* __restrict__ el, float* __restrict__ er, int l) {
    const int lane = threadIdx.x & 63, wid = threadIdx.x >> 6;
    const int r = lane & 15, q = lane >> 4;
    const int wbase = wid * 32;
    const bf16* Wt = wbt + l * HD * HD;

    short8v bfr[2][4];
    #pragma unroll
    for (int t = 0; t < 2; t++)
        #pragma unroll
        for (int ks = 0; ks < 4; ks++)
            bfr[t][ks] = *reinterpret_cast<const short8v*>(
                Wt + (wbase + 2 * r + t) * HD + ks * 32 + q * 8);

    const float al0 = wc[OFF_AL + l * HD + wbase + 2 * r];
    const float al1 = wc[OFF_AL + l * HD + wbase + 2 * r + 1];
    const float ar0 = wc[OFF_AR + l * HD + wbase + 2 * r];
    const float ar1 = wc[OFF_AR + l * HD + wbase + 2 * r + 1];

    const int base0 = blockIdx.x * 64;
    #pragma unroll
    for (int mt = 0; mt < 4; mt++) {
        const int base = base0 + mt * 16;
        if (base >= NN) break;
        float4v acc0 = {0.f, 0.f, 0.f, 0.f};
        float4v acc1 = {0.f, 0.f, 0.f, 0.f};
        #pragma unroll
        for (int ks = 0; ks < 4; ks++) {
            short8v a = *reinterpret_cast<const short8v*>(
                h + (base + r) * HD + ks * 32 + q * 8);
            acc0 = __builtin_amdgcn_mfma_f32_16x16x32_bf16(a, bfr[0][ks], acc0, 0, 0, 0);
            acc1 = __builtin_amdgcn_mfma_f32_16x16x32_bf16(a, bfr[1][ks], acc1, 0, 0, 0);
        }
        #pragma unroll
        for (int reg = 0; reg < 4; reg++) {
            const int row = base + q * 4 + reg;
            *reinterpret_cast<u16*>(feat8 + row * HD + wbase + 2 * r) =
                enc2fp8(acc0[reg], acc1[reg]);
            float elp = acc0[reg] * al0 + acc1[reg] * al1;
            float erp = acc0[reg] * ar0 + acc1[reg] * ar1;
            #pragma unroll
            for (int m = 1; m < 16; m <<= 1) {
                elp += __shfl_xor(elp, m, 64);
                erp += __shfl_xor(erp, m, 64);
            }
            if (r == 0) {
                el[row * 4 + wid] = elp;
                er[row * 4 + wid] = erp;
            }
        }
    }
}

// aggregation v5: fp8 feat gather (half the bytes), csr double-buffer
// prefetch. lane = (channel-quad cL = lane&31, edge-parity p = lane>>5).
template <bool LAST>
__global__ __launch_bounds__(256) void k_agg5(
        const u8* __restrict__ feat8, const float* __restrict__ el4,
        const float* __restrict__ er4, const int* __restrict__ row_ptr,
        const int* __restrict__ csr_src, const float* __restrict__ wc,
        bf16* __restrict__ h, float* __restrict__ gate, int l) {
    int lane = threadIdx.x & 63, wid = threadIdx.x >> 6;
    const int cL = lane & 31;      // channel quad: channels 4cL..4cL+3
    const int p = lane >> 5;       // edge parity
    const int hq = cL >> 3;        // head of my channels
    const int esub = lane >> 2;    // alpha duty: edge slot 0..15
    const int hsub = lane & 3;     // alpha duty: head
    const int cb = cL * 4;         // first channel (byte offset in fp8 row)
    for (int n = blockIdx.x * 4 + wid; n < NN; n += gridDim.x * 4) {
        int rp = row_ptr[n];
        int deg = row_ptr[n + 1] - rp;
        float ern_sub = er4[n * 4 + hsub];
        float a0 = 0.f, a1 = 0.f, a2 = 0.f, a3 = 0.f, z = 0.f;
        int sj = 0;
        if (lane < 16) sj = (lane < deg) ? csr_src[rp + lane] : 0;
        for (int bb = 0; bb < deg; bb += 16) {
            int sjn = 0;
            if (bb + 16 < deg && lane < 16) {
                int e = bb + 16 + lane;
                sjn = (e < deg) ? csr_src[rp + e] : 0;
            }
            int se = __shfl(sj, esub, 64);
            float myel = el4[se * 4 + hsub];
            float alpha = (bb + esub < deg)
                              ? __expf(lrelu(myel + ern_sub)) : 0.f;
            #pragma unroll
            for (int bb2 = 0; bb2 < 16; bb2 += 2) {
                int j = bb2 + p;
                int s = __shfl(sj, j, 64);
                float w = __shfl(alpha, 4 * j + hq, 64);
                u32 f = *reinterpret_cast<const u32*>(feat8 + s * HD + cb);
                float x0, x1, x2, x3;
                dec4fp8(f, x0, x1, x2, x3);
                a0 += w * x0;
                a1 += w * x1;
                a2 += w * x2;
                a3 += w * x3;
                z += w;
            }
            sj = sjn;
        }
        // combine parities (same channels live in lane and lane^32)
        a0 += __shfl_xor(a0, 32, 64);
        a1 += __shfl_xor(a1, 32, 64);
        a2 += __shfl_xor(a2, 32, 64);
        a3 += __shfl_xor(a3, 32, 64);
        z  += __shfl_xor(z, 32, 64);
        if (p == 0) {
            float inv = (deg && z != 0.f) ? 1.0f / z : 0.f;
            uint2 hv = *reinterpret_cast<const uint2*>(h + n * HD + cb);
            float v0 = fmaxf(a0 * inv + bf16lo(hv.x) + wc[OFF_BIAS + l * HD + cb], 0.f);
            float v1 = fmaxf(a1 * inv + bf16hi(hv.x) + wc[OFF_BIAS + l * HD + cb + 1], 0.f);
            float v2 = fmaxf(a2 * inv + bf16lo(hv.y) + wc[OFF_BIAS + l * HD + cb + 2], 0.f);
            float v3 = fmaxf(a3 * inv + bf16hi(hv.y) + wc[OFF_BIAS + l * HD + cb + 3], 0.f);
            if (!LAST) {
                uint2 o;
                o.x = packbf16(v0, v1);
                o.y = packbf16(v2, v3);
                *reinterpret_cast<uint2*>(h + n * HD + cb) = o;
            } else {
                // fused LayerNorm + gate (row distributed over lanes 0..31)
                float mu = grp_sum32(v0 + v1 + v2 + v3) * (1.0f / 128.0f);
                float d0 = v0 - mu, d1 = v1 - mu, d2 = v2 - mu, d3 = v3 - mu;
                float var = grp_sum32(d0 * d0 + d1 * d1 + d2 * d2 + d3 * d3)
                            * (1.0f / 128.0f);
                float rs = rsqrtf(var + 1e-5f);
                float y0 = d0 * rs * wc[OFF_LNG + cb]     + wc[OFF_LNB + cb];
                float y1 = d1 * rs * wc[OFF_LNG + cb + 1] + wc[OFF_LNB + cb + 1];
                float y2 = d2 * rs * wc[OFF_LNG + cb + 2] + wc[OFF_LNB + cb + 2];
                float y3 = d3 * rs * wc[OFF_LNG + cb + 3] + wc[OFF_LNB + cb + 3];
                uint2 o;
                o.x = packbf16(y0, y1);
                o.y = packbf16(y2, y3);
                *reinterpret_cast<uint2*>(h + n * HD + cb) = o;
                float gd = y0 * wc[OFF_GW + cb]     + y1 * wc[OFF_GW + cb + 1] +
                           y2 * wc[OFF_GW + cb + 2] + y3 * wc[OFF_GW + cb + 3];
                gd = grp_sum32(gd);
                if (lane == 0) gate[n] = gd + wc[OFF_GB];
            }
        }
    }
}

// per-graph gate max + 1/z; computes its own graph bounds (binary search),
// writes gb[] for poolsum, zeroes its zg row (runs before poolsum).
__global__ __launch_bounds__(256) void k_gmaxz(
        const float* __restrict__ gate, const int* __restrict__ gid,
        float* __restrict__ gmax, float* __restrict__ gzinv,
        int* __restrict__ gb, float* __restrict__ zg) {
    __shared__ float red[256];
    __shared__ int sb[2];
    int g = blockIdx.x, tid = threadIdx.x;
    if (tid < 2) {
        int target = g + tid;
        int lo = 0, hi = NN;
        while (lo < hi) {
            int mid = (lo + hi) >> 1;
            if (gid[mid] < target) lo = mid + 1;
            else hi = mid;
        }
        sb[tid] = lo;
        if (tid == 0) gb[g] = lo;
        if (tid == 1 && g == NG - 1) gb[NG] = lo;
    }
    if (tid < HD) zg[g * HD + tid] = 0.f;
    __syncthreads();
    int s0 = sb[0], e0 = sb[1];
    float m = -1e30f;
    for (int i = s0 + tid; i < e0; i += 256) m = fmaxf(m, gate[i]);
    red[tid] = m;
    __syncthreads();
    for (int off = 128; off; off >>= 1) {
        if (tid < off) red[tid] = fmaxf(red[tid], red[tid + off]);
        __syncthreads();
    }
    m = red[0];
    __syncthreads();
    float z = 0.f;
    for (int i = s0 + tid; i < e0; i += 256) z += __expf(gate[i] - m);
    red[tid] = z;
    __syncthreads();
    for (int off = 128; off; off >>= 1) {
        if (tid < off) red[tid] += red[tid + off];
        __syncthreads();
    }
    if (tid == 0) {
        gmax[g] = m;
        gzinv[g] = (e0 > s0 && red[0] > 0.f) ? 1.0f / red[0] : 0.f;
    }
}

// weighted node-sum, PCHUNK blocks per graph, atomicAdd into zeroed zg
__global__ __launch_bounds__(256) void k_poolsum(
        const bf16* __restrict__ h, const float* __restrict__ gate,
        const int* __restrict__ gb, const float* __restrict__ gmax,
        float* __restrict__ zg) {
    __shared__ float red[256];
    int b = blockIdx.x;
    int g = b / PCHUNK, c = b % PCHUNK;
    int s0 = gb[g], e0 = gb[g + 1];
    int len = e0 - s0;
    int beg = s0 + (int)(((long long)len * c) / PCHUNK);
    int end = s0 + (int)(((long long)len * (c + 1)) / PCHUNK);
    int ch = threadIdx.x & 127, half = threadIdx.x >> 7;
    float m = gmax[g];
    float acc = 0.f;
    for (int i = beg + half; i < end; i += 2)
        acc += __expf(gate[i] - m) * b2f(h[i * HD + ch]);
    red[threadIdx.x] = acc;
    __syncthreads();
    if (threadIdx.x < 128) {
        float v = red[threadIdx.x] + red[threadIdx.x + 128];
        if (v != 0.f) atomicAdd(&zg[g * HD + ch], v);
    }
}

__global__ __launch_bounds__(128) void k_mlp(
        const float* __restrict__ zg, const float* __restrict__ gzinv,
        const float* __restrict__ wc, float* __restrict__ out) {
    __shared__ float zr[HD], z1[HD];
    int g = blockIdx.x, tid = threadIdx.x;
    zr[tid] = zg[g * HD + tid] * gzinv[g];
    __syncthreads();
    float acc = wc[OFF_PB1 + tid];
    for (int k = 0; k < HD; k++) acc += zr[k] * wc[OFF_PW1 + k * HD + tid];
    z1[tid] = fmaxf(acc, 0.f);
    __syncthreads();
    if (tid < 64) {
        float a2 = wc[OFF_PB2 + tid];
        for (int k = 0; k < HD; k++) a2 += z1[k] * wc[OFF_PW2 + k * 64 + tid];
        out[g * 64 + tid] = a2;
    }
}

extern "C" void kernel_launch(void* const* d_in, const int* in_sizes, int n_in,
                              void* d_out, int out_size, void* d_ws, size_t ws_size,
                              hipStream_t stream) {
    const int* gate_types = (const int*)d_in[0];
    const int* qubit_idx  = (const int*)d_in[1];
    const int* src        = (const int*)d_in[2];
    const int* dst        = (const int*)d_in[3];
    const int* graph_ids  = (const int*)d_in[4];
    float* out = (float*)d_out;

    const int expect[19] = {NN, NN, NE, NE, NN, 4096, 2560, 49152, 384, 384,
                            384, 128, 128, 128, 1, 16384, 128, 8192, 64};
    for (int i = 0; i < 19 && i < n_in; i++) {
        if (in_sizes[i] != expect[i]) {
            k_diag<<<(out_size + 255) / 256, 256, 0, stream>>>(out, out_size,
                                                               7777000.f + i);
            return;
        }
    }

    char* ws = (char*)d_ws;
    size_t off = 0;
    auto alloc = [&](size_t bytes) {
        void* p = ws + off;
        off = (off + bytes + 255) & ~(size_t)255;
        return p;
    };
    float*  wc      = (float*)alloc(sizeof(float) * CVT_TOTAL);
    bf16*   wbt     = (bf16*)alloc(sizeof(bf16) * NL * HD * HD);
    float*  el      = (float*)alloc(sizeof(float) * NN * 4);
    float*  er      = (float*)alloc(sizeof(float) * NN * 4);
    int*    row_ptr = (int*)alloc(sizeof(int) * (NN + 1));
    int*    deg     = (int*)alloc(sizeof(int) * NN);
    int*    cursor  = (int*)alloc(sizeof(int) * NN);
    int*    csr_src = (int*)alloc(sizeof(int) * NE);
    int*    bsum    = (int*)alloc(sizeof(int) * NSB);
    int*    boff    = (int*)alloc(sizeof(int) * NSB);
    float*  gate    = (float*)alloc(sizeof(float) * NN);
    int*    gb      = (int*)alloc(sizeof(int) * (NG + 1));
    float*  zg      = (float*)alloc(sizeof(float) * NG * HD);
    float*  gmax    = (float*)alloc(sizeof(float) * NG);
    float*  gzinv   = (float*)alloc(sizeof(float) * NG);
    bf16*   h       = (bf16*)alloc(sizeof(bf16) * NN * HD);
    u8*     feat8   = (u8*)alloc(sizeof(u8) * NN * HD);

    if (off > ws_size) {
        k_diag<<<(out_size + 255) / 256, 256, 0, stream>>>(
            out, out_size, (float)(ws_size >> 10));
        return;
    }

    CvtSrc cs;
    for (int i = 0; i < 14; i++) cs.p[i] = d_in[5 + i];
    k_convert<<<256, 256, 0, stream>>>(cs, wc, wbt, deg);

    k_embed<<<(NN * 64 + 255) / 256, 256, 0, stream>>>(gate_types, qubit_idx,
                                                       wc, h, dst, deg);
    k_bsum<<<NSB, SBLK, 0, stream>>>(deg, bsum);
    k_bscan<<<1, SBLK, 0, stream>>>(bsum, boff, row_ptr);
    k_locscan<<<NSB, SBLK, 0, stream>>>(deg, boff, row_ptr, cursor);
    k_fill<<<(NE + 255) / 256, 256, 0, stream>>>(src, dst, cursor, csr_src);

    for (int l = 0; l < NL; l++) {
        k_gemm_elr<<<GBLK, 256, 0, stream>>>(h, wbt, wc, feat8, el, er, l);
        if (l < NL - 1)
            k_agg5<false><<<2048, 256, 0, stream>>>(feat8, el, er, row_ptr,
                                                    csr_src, wc, h, gate, l);
        else
            k_agg5<true><<<2048, 256, 0, stream>>>(feat8, el, er, row_ptr,
                                                   csr_src, wc, h, gate, l);
    }
    k_gmaxz<<<NG, 256, 0, stream>>>(gate, graph_ids, gmax, gzinv, gb, zg);
    k_poolsum<<<NG * PCHUNK, 256, 0, stream>>>(h, gate, gb, gmax, zg);
    k_mlp<<<NG, 128, 0, stream>>>(zg, gzinv, wc, out);
}

// Round 14
// 252.204 us; speedup vs baseline: 3.6761x; 1.0559x over previous
//
#include <hip/hip_runtime.h>
#include <hip/hip_bf16.h>
#include <hip/hip_fp8.h>

#define NN 50000
#define NE 600000
#define NG 64
#define HD 128
#define NL 3
#define NEG 0.2f
#define PCHUNK 16     // pooling blocks per graph
#define SBLK 256
#define NSB ((NN + SBLK - 1) / SBLK)   // 196 scan blocks
#define GBLK ((NN + 63) / 64)          // 782 gemm blocks

typedef __hip_bfloat16 bf16;
typedef unsigned short u16;
typedef unsigned int u32;
typedef unsigned char u8;
typedef __attribute__((ext_vector_type(8))) short short8v;      // 8 bf16
typedef __attribute__((ext_vector_type(4))) float float4v;      // MFMA acc
typedef __attribute__((ext_vector_type(2))) float float2v;

// converted-f32 weight region offsets (element units)
#define OFF_GE    0
#define OFF_QE    4096
#define OFF_W     6656
#define OFF_AL    55808
#define OFF_AR    56192
#define OFF_BIAS  56576
#define OFF_LNG   56960
#define OFF_LNB   57088
#define OFF_GW    57216
#define OFF_GB    57344
#define OFF_PW1   57345
#define OFF_PB1   73729
#define OFF_PW2   73857
#define OFF_PB2   82049
#define CVT_TOTAL 82113

__device__ __forceinline__ float b2f(bf16 x) { return __bfloat162float(x); }
__device__ __forceinline__ bf16 f2b(float x) { return __float2bfloat16(x); }
__device__ __forceinline__ float lrelu(float x) { return x > 0.f ? x : NEG * x; }
__device__ __forceinline__ float bf16lo(u32 u) { return __uint_as_float(u << 16); }
__device__ __forceinline__ float bf16hi(u32 u) { return __uint_as_float(u & 0xffff0000u); }
__device__ __forceinline__ u32 packbf16(float x, float y) {
    bf16 bx = f2b(x), by = f2b(y);
    u16 ux = *reinterpret_cast<u16*>(&bx);
    u16 uy = *reinterpret_cast<u16*>(&by);
    return (u32)ux | ((u32)uy << 16);
}

// ---- fp8 e4m3 (OCP) encode/decode via HW cvt ----
__device__ __forceinline__ u16 enc2fp8(float a, float b) {
#if __has_builtin(__builtin_amdgcn_cvt_pk_fp8_f32)
    return (u16)__builtin_amdgcn_cvt_pk_fp8_f32(a, b, 0, false);
#else
    __hip_fp8_e4m3 fa(a), fb(b);
    return (u16)fa.__x | ((u16)fb.__x << 8);
#endif
}
__device__ __forceinline__ void dec4fp8(u32 v, float& x0, float& x1,
                                        float& x2, float& x3) {
#if __has_builtin(__builtin_amdgcn_cvt_pk_f32_fp8)
    float2v lo = __builtin_amdgcn_cvt_pk_f32_fp8((int)v, false);
    float2v hi = __builtin_amdgcn_cvt_pk_f32_fp8((int)v, true);
    x0 = lo[0]; x1 = lo[1]; x2 = hi[0]; x3 = hi[1];
#else
    __hip_fp8_e4m3 t0, t1, t2, t3;
    t0.__x = v & 0xff; t1.__x = (v >> 8) & 0xff;
    t2.__x = (v >> 16) & 0xff; t3.__x = (v >> 24) & 0xff;
    x0 = (float)t0; x1 = (float)t1; x2 = (float)t2; x3 = (float)t3;
#endif
}

__device__ __forceinline__ float wave_sum64(float v) {
    #pragma unroll
    for (int m = 1; m < 64; m <<= 1) v += __shfl_xor(v, m, 64);
    return v;
}
__device__ __forceinline__ float grp_sum32(float v) {   // lanes 0..31 only
    #pragma unroll
    for (int m = 1; m < 32; m <<= 1) v += __shfl_xor(v, m, 64);
    return v;
}

// ---- diagnostics ----
__global__ void k_diag(float* out, int n, float code) {
    int i = blockIdx.x * blockDim.x + threadIdx.x;
    if (i < n) out[i] = code;
}

struct CvtSrc { const void* p[14]; };

// convert weights to canonical f32 region + transposed bf16 W + zero deg[].
__global__ __launch_bounds__(256) void k_convert(CvtSrc srcs,
                                                 float* __restrict__ dst,
                                                 bf16* __restrict__ wbt,
                                                 int* __restrict__ deg) {
    __shared__ int cnt;
    if (threadIdx.x == 0) cnt = 0;
    __syncthreads();
    const u16* wraw = (const u16*)srcs.p[2];
    int bad = 0;
    for (int i = threadIdx.x; i < 2048; i += 256) {
        int e = (wraw[i] >> 7) & 0xFF;
        if (e == 0xFF || e >= 0x90) bad++;
    }
    if (bad) atomicAdd(&cnt, bad);
    __syncthreads();
    const bool isf32 = cnt > 16;

    const int starts[15] = {OFF_GE, OFF_QE, OFF_W, OFF_AL, OFF_AR, OFF_BIAS,
                            OFF_LNG, OFF_LNB, OFF_GW, OFF_GB, OFF_PW1, OFF_PB1,
                            OFF_PW2, OFF_PB2, CVT_TOTAL};
    for (int i = blockIdx.x * blockDim.x + threadIdx.x; i < CVT_TOTAL;
         i += gridDim.x * blockDim.x) {
        int a = 0;
        while (i >= starts[a + 1]) a++;
        int off = i - starts[a];
        dst[i] = isf32 ? ((const float*)srcs.p[a])[off]
                       : b2f(((const bf16*)srcs.p[a])[off]);
    }
    // wbt[l][col][k] = bf16(W[l][k][col])  (transposed, MFMA-B-fragment layout)
    for (int i = blockIdx.x * blockDim.x + threadIdx.x; i < NL * HD * HD;
         i += gridDim.x * blockDim.x) {
        int l = i >> 14, rem = i & 16383;
        int col = rem >> 7, k = rem & 127;
        int si = l * 16384 + k * 128 + col;
        float v = isf32 ? ((const float*)srcs.p[2])[si]
                        : b2f(((const bf16*)srcs.p[2])[si]);
        wbt[i] = f2b(v);
    }
    for (int i = blockIdx.x * blockDim.x + threadIdx.x; i < NN;
         i += gridDim.x * blockDim.x)
        deg[i] = 0;
}

// embeddings (2 ch/thread, u32 stores) + fused degree count
__global__ void k_embed(const int* __restrict__ gt, const int* __restrict__ qi,
                        const float* __restrict__ wc, bf16* __restrict__ h,
                        const int* __restrict__ dst, int* __restrict__ deg) {
    int idx = blockIdx.x * blockDim.x + threadIdx.x;
    if (idx < NE) atomicAdd(&deg[dst[idx]], 1);
    if (idx >= NN * 64) return;
    int n = idx >> 6, c = (idx & 63) * 2;
    int g = gt[n], q = qi[n];
    float a0 = wc[OFF_GE + g * HD + c]     + wc[OFF_QE + q * HD + c];
    float a1 = wc[OFF_GE + g * HD + c + 1] + wc[OFF_QE + q * HD + c + 1];
    *reinterpret_cast<u32*>(h + n * HD + c) = packbf16(a0, a1);
}

// ---- 3-phase multi-block exclusive scan of deg -> row_ptr/cursor ----
__global__ __launch_bounds__(SBLK) void k_bsum(const int* __restrict__ deg,
                                               int* __restrict__ bsum) {
    __shared__ int red[SBLK];
    int i = blockIdx.x * SBLK + threadIdx.x;
    red[threadIdx.x] = (i < NN) ? deg[i] : 0;
    __syncthreads();
    for (int off = SBLK / 2; off; off >>= 1) {
        if (threadIdx.x < off) red[threadIdx.x] += red[threadIdx.x + off];
        __syncthreads();
    }
    if (threadIdx.x == 0) bsum[blockIdx.x] = red[0];
}

__global__ __launch_bounds__(SBLK) void k_bscan(const int* __restrict__ bsum,
                                                int* __restrict__ boff,
                                                int* __restrict__ row_ptr) {
    __shared__ int s[SBLK];
    int t = threadIdx.x;
    int x = (t < NSB) ? bsum[t] : 0;
    s[t] = x;
    __syncthreads();
    #pragma unroll
    for (int off = 1; off < SBLK; off <<= 1) {
        int v = (t >= off) ? s[t - off] : 0;
        __syncthreads();
        if (t >= off) s[t] += v;
        __syncthreads();
    }
    if (t < NSB) boff[t] = s[t] - x;          // exclusive
    if (t == 0) row_ptr[NN] = s[SBLK - 1];    // total (= NE)
}

__global__ __launch_bounds__(SBLK) void k_locscan(const int* __restrict__ deg,
                                                  const int* __restrict__ boff,
                                                  int* __restrict__ row_ptr,
                                                  int* __restrict__ cursor) {
    __shared__ int s[SBLK];
    int t = threadIdx.x;
    int i = blockIdx.x * SBLK + t;
    int x = (i < NN) ? deg[i] : 0;
    s[t] = x;
    __syncthreads();
    #pragma unroll
    for (int off = 1; off < SBLK; off <<= 1) {
        int v = (t >= off) ? s[t - off] : 0;
        __syncthreads();
        if (t >= off) s[t] += v;
        __syncthreads();
    }
    if (i < NN) {
        int excl = boff[blockIdx.x] + s[t] - x;
        row_ptr[i] = excl;
        cursor[i] = excl;
    }
}

__global__ void k_fill(const int* __restrict__ src, const int* __restrict__ dst,
                       int* __restrict__ cursor, int* __restrict__ csr_src) {
    int e = blockIdx.x * blockDim.x + threadIdx.x;
    if (e < NE) {
        int p = atomicAdd(&cursor[dst[e]], 1);
        csr_src[p] = src[e];
    }
}

// MFMA GEMM + fused el/er epilogue. Packed-channel permutation: B0 slot r
// holds channel wbase+2r, B1 holds wbase+2r+1 -> lane's acc0/acc1 are
// ADJACENT channels. feat stored fp8 e4m3 (consumed only by the gather).
__global__ __launch_bounds__(256) void k_gemm_elr(
        const bf16* __restrict__ h, const bf16* __restrict__ wbt,
        const float* __restrict__ wc, u8* __restrict__ feat8,
        float* __restrict__ el, float* __restrict__ er, int l) {
    const int lane = threadIdx.x & 63, wid = threadIdx.x >> 6;
    const int r = lane & 15, q = lane >> 4;
    const int wbase = wid * 32;
    const bf16* Wt = wbt + l * HD * HD;

    short8v bfr[2][4];
    #pragma unroll
    for (int t = 0; t < 2; t++)
        #pragma unroll
        for (int ks = 0; ks < 4; ks++)
            bfr[t][ks] = *reinterpret_cast<const short8v*>(
                Wt + (wbase + 2 * r + t) * HD + ks * 32 + q * 8);

    const float al0 = wc[OFF_AL + l * HD + wbase + 2 * r];
    const float al1 = wc[OFF_AL + l * HD + wbase + 2 * r + 1];
    const float ar0 = wc[OFF_AR + l * HD + wbase + 2 * r];
    const float ar1 = wc[OFF_AR + l * HD + wbase + 2 * r + 1];

    const int base0 = blockIdx.x * 64;
    #pragma unroll
    for (int mt = 0; mt < 4; mt++) {
        const int base = base0 + mt * 16;
        if (base >= NN) break;
        float4v acc0 = {0.f, 0.f, 0.f, 0.f};
        float4v acc1 = {0.f, 0.f, 0.f, 0.f};
        #pragma unroll
        for (int ks = 0; ks < 4; ks++) {
            short8v a = *reinterpret_cast<const short8v*>(
                h + (base + r) * HD + ks * 32 + q * 8);
            acc0 = __builtin_amdgcn_mfma_f32_16x16x32_bf16(a, bfr[0][ks], acc0, 0, 0, 0);
            acc1 = __builtin_amdgcn_mfma_f32_16x16x32_bf16(a, bfr[1][ks], acc1, 0, 0, 0);
        }
        #pragma unroll
        for (int reg = 0; reg < 4; reg++) {
            const int row = base + q * 4 + reg;
            *reinterpret_cast<u16*>(feat8 + row * HD + wbase + 2 * r) =
                enc2fp8(acc0[reg], acc1[reg]);
            float elp = acc0[reg] * al0 + acc1[reg] * al1;
            float erp = acc0[reg] * ar0 + acc1[reg] * ar1;
            #pragma unroll
            for (int m = 1; m < 16; m <<= 1) {
                elp += __shfl_xor(elp, m, 64);
                erp += __shfl_xor(erp, m, 64);
            }
            if (r == 0) {
                el[row * 4 + wid] = elp;
                er[row * 4 + wid] = erp;
            }
        }
    }
}

// aggregation v6: ZERO cross-lane ops in the inner loop. Within a 32-lane
// parity group, s and alpha are uniform -> load them directly (uniform VMEM
// addresses broadcast in L1); alpha recomputed per lane (1 exp). All work
// per-lane independent -> deep VMEM pipelining via unroll.
template <bool LAST>
__global__ __launch_bounds__(256) void k_agg6(
        const u8* __restrict__ feat8, const float* __restrict__ el4,
        const float* __restrict__ er4, const int* __restrict__ row_ptr,
        const int* __restrict__ csr_src, const float* __restrict__ wc,
        bf16* __restrict__ h, float* __restrict__ gate, int l) {
    int lane = threadIdx.x & 63, wid = threadIdx.x >> 6;
    const int cL = lane & 31;      // channel quad: channels 4cL..4cL+3
    const int p = lane >> 5;       // edge parity
    const int hq = cL >> 3;        // head of my channels
    const int cb = cL * 4;         // first channel (byte offset in fp8 row)
    for (int n = blockIdx.x * 4 + wid; n < NN; n += gridDim.x * 4) {
        int rp = row_ptr[n];
        int deg = row_ptr[n + 1] - rp;
        float ern = er4[n * 4 + hq];
        float a0 = 0.f, a1 = 0.f, a2 = 0.f, a3 = 0.f, z = 0.f;
        #pragma unroll 4
        for (int j = p; j < deg; j += 2) {
            int s = csr_src[rp + j];                 // uniform per group
            float elv = el4[s * 4 + hq];             // 4 words per group
            float w = __expf(lrelu(elv + ern));
            u32 f = *reinterpret_cast<const u32*>(feat8 + s * HD + cb);
            float x0, x1, x2, x3;
            dec4fp8(f, x0, x1, x2, x3);
            a0 += w * x0;
            a1 += w * x1;
            a2 += w * x2;
            a3 += w * x3;
            z += w;
        }
        // combine parities (same channels live in lane and lane^32)
        a0 += __shfl_xor(a0, 32, 64);
        a1 += __shfl_xor(a1, 32, 64);
        a2 += __shfl_xor(a2, 32, 64);
        a3 += __shfl_xor(a3, 32, 64);
        z  += __shfl_xor(z, 32, 64);
        if (p == 0) {
            float inv = (deg && z != 0.f) ? 1.0f / z : 0.f;
            uint2 hv = *reinterpret_cast<const uint2*>(h + n * HD + cb);
            float v0 = fmaxf(a0 * inv + bf16lo(hv.x) + wc[OFF_BIAS + l * HD + cb], 0.f);
            float v1 = fmaxf(a1 * inv + bf16hi(hv.x) + wc[OFF_BIAS + l * HD + cb + 1], 0.f);
            float v2 = fmaxf(a2 * inv + bf16lo(hv.y) + wc[OFF_BIAS + l * HD + cb + 2], 0.f);
            float v3 = fmaxf(a3 * inv + bf16hi(hv.y) + wc[OFF_BIAS + l * HD + cb + 3], 0.f);
            if (!LAST) {
                uint2 o;
                o.x = packbf16(v0, v1);
                o.y = packbf16(v2, v3);
                *reinterpret_cast<uint2*>(h + n * HD + cb) = o;
            } else {
                // fused LayerNorm + gate (row distributed over lanes 0..31)
                float mu = grp_sum32(v0 + v1 + v2 + v3) * (1.0f / 128.0f);
                float d0 = v0 - mu, d1 = v1 - mu, d2 = v2 - mu, d3 = v3 - mu;
                float var = grp_sum32(d0 * d0 + d1 * d1 + d2 * d2 + d3 * d3)
                            * (1.0f / 128.0f);
                float rs = rsqrtf(var + 1e-5f);
                float y0 = d0 * rs * wc[OFF_LNG + cb]     + wc[OFF_LNB + cb];
                float y1 = d1 * rs * wc[OFF_LNG + cb + 1] + wc[OFF_LNB + cb + 1];
                float y2 = d2 * rs * wc[OFF_LNG + cb + 2] + wc[OFF_LNB + cb + 2];
                float y3 = d3 * rs * wc[OFF_LNG + cb + 3] + wc[OFF_LNB + cb + 3];
                uint2 o;
                o.x = packbf16(y0, y1);
                o.y = packbf16(y2, y3);
                *reinterpret_cast<uint2*>(h + n * HD + cb) = o;
                float gd = y0 * wc[OFF_GW + cb]     + y1 * wc[OFF_GW + cb + 1] +
                           y2 * wc[OFF_GW + cb + 2] + y3 * wc[OFF_GW + cb + 3];
                gd = grp_sum32(gd);
                if (lane == 0) gate[n] = gd + wc[OFF_GB];
            }
        }
    }
}

// per-graph gate max + 1/z; computes its own graph bounds (binary search),
// writes gb[] for poolsum, zeroes its zg row (runs before poolsum).
__global__ __launch_bounds__(256) void k_gmaxz(
        const float* __restrict__ gate, const int* __restrict__ gid,
        float* __restrict__ gmax, float* __restrict__ gzinv,
        int* __restrict__ gb, float* __restrict__ zg) {
    __shared__ float red[256];
    __shared__ int sb[2];
    int g = blockIdx.x, tid = threadIdx.x;
    if (tid < 2) {
        int target = g + tid;
        int lo = 0, hi = NN;
        while (lo < hi) {
            int mid = (lo + hi) >> 1;
            if (gid[mid] < target) lo = mid + 1;
            else hi = mid;
        }
        sb[tid] = lo;
        if (tid == 0) gb[g] = lo;
        if (tid == 1 && g == NG - 1) gb[NG] = lo;
    }
    if (tid < HD) zg[g * HD + tid] = 0.f;
    __syncthreads();
    int s0 = sb[0], e0 = sb[1];
    float m = -1e30f;
    for (int i = s0 + tid; i < e0; i += 256) m = fmaxf(m, gate[i]);
    red[tid] = m;
    __syncthreads();
    for (int off = 128; off; off >>= 1) {
        if (tid < off) red[tid] = fmaxf(red[tid], red[tid + off]);
        __syncthreads();
    }
    m = red[0];
    __syncthreads();
    float z = 0.f;
    for (int i = s0 + tid; i < e0; i += 256) z += __expf(gate[i] - m);
    red[tid] = z;
    __syncthreads();
    for (int off = 128; off; off >>= 1) {
        if (tid < off) red[tid] += red[tid + off];
        __syncthreads();
    }
    if (tid == 0) {
        gmax[g] = m;
        gzinv[g] = (e0 > s0 && red[0] > 0.f) ? 1.0f / red[0] : 0.f;
    }
}

// weighted node-sum, PCHUNK blocks per graph, atomicAdd into zeroed zg
__global__ __launch_bounds__(256) void k_poolsum(
        const bf16* __restrict__ h, const float* __restrict__ gate,
        const int* __restrict__ gb, const float* __restrict__ gmax,
        float* __restrict__ zg) {
    __shared__ float red[256];
    int b = blockIdx.x;
    int g = b / PCHUNK, c = b % PCHUNK;
    int s0 = gb[g], e0 = gb[g + 1];
    int len = e0 - s0;
    int beg = s0 + (int)(((long long)len * c) / PCHUNK);
    int end = s0 + (int)(((long long)len * (c + 1)) / PCHUNK);
    int ch = threadIdx.x & 127, half = threadIdx.x >> 7;
    float m = gmax[g];
    float acc = 0.f;
    for (int i = beg + half; i < end; i += 2)
        acc += __expf(gate[i] - m) * b2f(h[i * HD + ch]);
    red[threadIdx.x] = acc;
    __syncthreads();
    if (threadIdx.x < 128) {
        float v = red[threadIdx.x] + red[threadIdx.x + 128];
        if (v != 0.f) atomicAdd(&zg[g * HD + ch], v);
    }
}

__global__ __launch_bounds__(128) void k_mlp(
        const float* __restrict__ zg, const float* __restrict__ gzinv,
        const float* __restrict__ wc, float* __restrict__ out) {
    __shared__ float zr[HD], z1[HD];
    int g = blockIdx.x, tid = threadIdx.x;
    zr[tid] = zg[g * HD + tid] * gzinv[g];
    __syncthreads();
    float acc = wc[OFF_PB1 + tid];
    for (int k = 0; k < HD; k++) acc += zr[k] * wc[OFF_PW1 + k * HD + tid];
    z1[tid] = fmaxf(acc, 0.f);
    __syncthreads();
    if (tid < 64) {
        float a2 = wc[OFF_PB2 + tid];
        for (int k = 0; k < HD; k++) a2 += z1[k] * wc[OFF_PW2 + k * 64 + tid];
        out[g * 64 + tid] = a2;
    }
}

extern "C" void kernel_launch(void* const* d_in, const int* in_sizes, int n_in,
                              void* d_out, int out_size, void* d_ws, size_t ws_size,
                              hipStream_t stream) {
    const int* gate_types = (const int*)d_in[0];
    const int* qubit_idx  = (const int*)d_in[1];
    const int* src        = (const int*)d_in[2];
    const int* dst        = (const int*)d_in[3];
    const int* graph_ids  = (const int*)d_in[4];
    float* out = (float*)d_out;

    const int expect[19] = {NN, NN, NE, NE, NN, 4096, 2560, 49152, 384, 384,
                            384, 128, 128, 128, 1, 16384, 128, 8192, 64};
    for (int i = 0; i < 19 && i < n_in; i++) {
        if (in_sizes[i] != expect[i]) {
            k_diag<<<(out_size + 255) / 256, 256, 0, stream>>>(out, out_size,
                                                               7777000.f + i);
            return;
        }
    }

    char* ws = (char*)d_ws;
    size_t off = 0;
    auto alloc = [&](size_t bytes) {
        void* p = ws + off;
        off = (off + bytes + 255) & ~(size_t)255;
        return p;
    };
    float*  wc      = (float*)alloc(sizeof(float) * CVT_TOTAL);
    bf16*   wbt     = (bf16*)alloc(sizeof(bf16) * NL * HD * HD);
    float*  el      = (float*)alloc(sizeof(float) * NN * 4);
    float*  er      = (float*)alloc(sizeof(float) * NN * 4);
    int*    row_ptr = (int*)alloc(sizeof(int) * (NN + 1));
    int*    deg     = (int*)alloc(sizeof(int) * NN);
    int*    cursor  = (int*)alloc(sizeof(int) * NN);
    int*    csr_src = (int*)alloc(sizeof(int) * NE);
    int*    bsum    = (int*)alloc(sizeof(int) * NSB);
    int*    boff    = (int*)alloc(sizeof(int) * NSB);
    float*  gate    = (float*)alloc(sizeof(float) * NN);
    int*    gb      = (int*)alloc(sizeof(int) * (NG + 1));
    float*  zg      = (float*)alloc(sizeof(float) * NG * HD);
    float*  gmax    = (float*)alloc(sizeof(float) * NG);
    float*  gzinv   = (float*)alloc(sizeof(float) * NG);
    bf16*   h       = (bf16*)alloc(sizeof(bf16) * NN * HD);
    u8*     feat8   = (u8*)alloc(sizeof(u8) * NN * HD);

    if (off > ws_size) {
        k_diag<<<(out_size + 255) / 256, 256, 0, stream>>>(
            out, out_size, (float)(ws_size >> 10));
        return;
    }

    CvtSrc cs;
    for (int i = 0; i < 14; i++) cs.p[i] = d_in[5 + i];
    k_convert<<<256, 256, 0, stream>>>(cs, wc, wbt, deg);

    k_embed<<<(NN * 64 + 255) / 256, 256, 0, stream>>>(gate_types, qubit_idx,
                                                       wc, h, dst, deg);
    k_bsum<<<NSB, SBLK, 0, stream>>>(deg, bsum);
    k_bscan<<<1, SBLK, 0, stream>>>(bsum, boff, row_ptr);
    k_locscan<<<NSB, SBLK, 0, stream>>>(deg, boff, row_ptr, cursor);
    k_fill<<<(NE + 255) / 256, 256, 0, stream>>>(src, dst, cursor, csr_src);

    for (int l = 0; l < NL; l++) {
        k_gemm_elr<<<GBLK, 256, 0, stream>>>(h, wbt, wc, feat8, el, er, l);
        if (l < NL - 1)
            k_agg6<false><<<2048, 256, 0, stream>>>(feat8, el, er, row_ptr,
                                                    csr_src, wc, h, gate, l);
        else
            k_agg6<true><<<2048, 256, 0, stream>>>(feat8, el, er, row_ptr,
                                                   csr_src, wc, h, gate, l);
    }
    k_gmaxz<<<NG, 256, 0, stream>>>(gate, graph_ids, gmax, gzinv, gb, zg);
    k_poolsum<<<NG * PCHUNK, 256, 0, stream>>>(h, gate, gb, gmax, zg);
    k_mlp<<<NG, 128, 0, stream>>>(zg, gzinv, wc, out);
}

// Round 15
// 246.718 us; speedup vs baseline: 3.7579x; 1.0222x over previous
//
#include <hip/hip_runtime.h>
#include <hip/hip_bf16.h>
#include <hip/hip_fp8.h>

#define NN 50000
#define NE 600000
#define NG 64
#define HD 128
#define NL 3
#define NEG 0.2f
#define PCHUNK 16     // pooling blocks per graph
#define SBLK 256
#define NSB ((NN + SBLK - 1) / SBLK)   // 196 scan blocks
#define GBLK2 ((NN + 127) / 128)       // 391 gemm blocks (128 rows each)

typedef __hip_bfloat16 bf16;
typedef unsigned short u16;
typedef unsigned int u32;
typedef unsigned char u8;
typedef __attribute__((ext_vector_type(8))) short short8v;      // 8 bf16
typedef __attribute__((ext_vector_type(4))) float float4v;      // MFMA acc
typedef __attribute__((ext_vector_type(2))) float float2v;

// converted-f32 weight region offsets (element units)
#define OFF_GE    0
#define OFF_QE    4096
#define OFF_W     6656
#define OFF_AL    55808
#define OFF_AR    56192
#define OFF_BIAS  56576
#define OFF_LNG   56960
#define OFF_LNB   57088
#define OFF_GW    57216
#define OFF_GB    57344
#define OFF_PW1   57345
#define OFF_PB1   73729
#define OFF_PW2   73857
#define OFF_PB2   82049
#define CVT_TOTAL 82113

__device__ __forceinline__ float b2f(bf16 x) { return __bfloat162float(x); }
__device__ __forceinline__ bf16 f2b(float x) { return __float2bfloat16(x); }
__device__ __forceinline__ float lrelu(float x) { return x > 0.f ? x : NEG * x; }
__device__ __forceinline__ float bf16lo(u32 u) { return __uint_as_float(u << 16); }
__device__ __forceinline__ float bf16hi(u32 u) { return __uint_as_float(u & 0xffff0000u); }
__device__ __forceinline__ u32 packbf16(float x, float y) {
    bf16 bx = f2b(x), by = f2b(y);
    u16 ux = *reinterpret_cast<u16*>(&bx);
    u16 uy = *reinterpret_cast<u16*>(&by);
    return (u32)ux | ((u32)uy << 16);
}

// ---- fp8 e4m3 (OCP) encode/decode via HW cvt ----
__device__ __forceinline__ u16 enc2fp8(float a, float b) {
#if __has_builtin(__builtin_amdgcn_cvt_pk_fp8_f32)
    return (u16)__builtin_amdgcn_cvt_pk_fp8_f32(a, b, 0, false);
#else
    __hip_fp8_e4m3 fa(a), fb(b);
    return (u16)fa.__x | ((u16)fb.__x << 8);
#endif
}
__device__ __forceinline__ void dec4fp8(u32 v, float& x0, float& x1,
                                        float& x2, float& x3) {
#if __has_builtin(__builtin_amdgcn_cvt_pk_f32_fp8)
    float2v lo = __builtin_amdgcn_cvt_pk_f32_fp8((int)v, false);
    float2v hi = __builtin_amdgcn_cvt_pk_f32_fp8((int)v, true);
    x0 = lo[0]; x1 = lo[1]; x2 = hi[0]; x3 = hi[1];
#else
    __hip_fp8_e4m3 t0, t1, t2, t3;
    t0.__x = v & 0xff; t1.__x = (v >> 8) & 0xff;
    t2.__x = (v >> 16) & 0xff; t3.__x = (v >> 24) & 0xff;
    x0 = (float)t0; x1 = (float)t1; x2 = (float)t2; x3 = (float)t3;
#endif
}

__device__ __forceinline__ float grp_sum32(float v) {   // within 32-lane group
    #pragma unroll
    for (int m = 1; m < 32; m <<= 1) v += __shfl_xor(v, m, 64);
    return v;
}

// ---- diagnostics ----
__global__ void k_diag(float* out, int n, float code) {
    int i = blockIdx.x * blockDim.x + threadIdx.x;
    if (i < n) out[i] = code;
}

struct CvtSrc { const void* p[14]; };

// convert weights to canonical f32 region + transposed bf16 W + zero deg[].
__global__ __launch_bounds__(256) void k_convert(CvtSrc srcs,
                                                 float* __restrict__ dst,
                                                 bf16* __restrict__ wbt,
                                                 int* __restrict__ deg) {
    __shared__ int cnt;
    if (threadIdx.x == 0) cnt = 0;
    __syncthreads();
    const u16* wraw = (const u16*)srcs.p[2];
    int bad = 0;
    for (int i = threadIdx.x; i < 2048; i += 256) {
        int e = (wraw[i] >> 7) & 0xFF;
        if (e == 0xFF || e >= 0x90) bad++;
    }
    if (bad) atomicAdd(&cnt, bad);
    __syncthreads();
    const bool isf32 = cnt > 16;

    const int starts[15] = {OFF_GE, OFF_QE, OFF_W, OFF_AL, OFF_AR, OFF_BIAS,
                            OFF_LNG, OFF_LNB, OFF_GW, OFF_GB, OFF_PW1, OFF_PB1,
                            OFF_PW2, OFF_PB2, CVT_TOTAL};
    for (int i = blockIdx.x * blockDim.x + threadIdx.x; i < CVT_TOTAL;
         i += gridDim.x * blockDim.x) {
        int a = 0;
        while (i >= starts[a + 1]) a++;
        int off = i - starts[a];
        dst[i] = isf32 ? ((const float*)srcs.p[a])[off]
                       : b2f(((const bf16*)srcs.p[a])[off]);
    }
    // wbt[l][col][k] = bf16(W[l][k][col])  (transposed, MFMA-B-fragment layout)
    for (int i = blockIdx.x * blockDim.x + threadIdx.x; i < NL * HD * HD;
         i += gridDim.x * blockDim.x) {
        int l = i >> 14, rem = i & 16383;
        int col = rem >> 7, k = rem & 127;
        int si = l * 16384 + k * 128 + col;
        float v = isf32 ? ((const float*)srcs.p[2])[si]
                        : b2f(((const bf16*)srcs.p[2])[si]);
        wbt[i] = f2b(v);
    }
    for (int i = blockIdx.x * blockDim.x + threadIdx.x; i < NN;
         i += gridDim.x * blockDim.x)
        deg[i] = 0;
}

// embeddings (2 ch/thread, u32 stores) + fused degree count
__global__ void k_embed(const int* __restrict__ gt, const int* __restrict__ qi,
                        const float* __restrict__ wc, bf16* __restrict__ h,
                        const int* __restrict__ dst, int* __restrict__ deg) {
    int idx = blockIdx.x * blockDim.x + threadIdx.x;
    if (idx < NE) atomicAdd(&deg[dst[idx]], 1);
    if (idx >= NN * 64) return;
    int n = idx >> 6, c = (idx & 63) * 2;
    int g = gt[n], q = qi[n];
    float a0 = wc[OFF_GE + g * HD + c]     + wc[OFF_QE + q * HD + c];
    float a1 = wc[OFF_GE + g * HD + c + 1] + wc[OFF_QE + q * HD + c + 1];
    *reinterpret_cast<u32*>(h + n * HD + c) = packbf16(a0, a1);
}

// ---- CSR scan: per-block sums, then fused (block-offset + local scan) ----
__global__ __launch_bounds__(SBLK) void k_bsum(const int* __restrict__ deg,
                                               int* __restrict__ bsum) {
    __shared__ int red[SBLK];
    int i = blockIdx.x * SBLK + threadIdx.x;
    red[threadIdx.x] = (i < NN) ? deg[i] : 0;
    __syncthreads();
    for (int off = SBLK / 2; off; off >>= 1) {
        if (threadIdx.x < off) red[threadIdx.x] += red[threadIdx.x + off];
        __syncthreads();
    }
    if (threadIdx.x == 0) bsum[blockIdx.x] = red[0];
}

// each block derives its own exclusive offset from bsum (196 entries, L2-hot)
__global__ __launch_bounds__(SBLK) void k_locscan(const int* __restrict__ deg,
                                                  const int* __restrict__ bsum,
                                                  int* __restrict__ row_ptr,
                                                  int* __restrict__ cursor) {
    __shared__ int s[SBLK];
    __shared__ int boffs;
    int t = threadIdx.x;
    // exclusive offset: sum of bsum[0..bid)
    int part = (t < NSB && t < blockIdx.x) ? bsum[t] : 0;
    #pragma unroll
    for (int m = 1; m < 64; m <<= 1) part += __shfl_xor(part, m, 64);
    if (t == 0) s[0] = 0;
    __syncthreads();
    if ((t & 63) == 0) atomicAdd(&s[0], part);
    __syncthreads();
    if (t == 0) boffs = s[0];
    __syncthreads();
    int boff = boffs;

    int i = blockIdx.x * SBLK + t;
    int x = (i < NN) ? deg[i] : 0;
    s[t] = x;
    __syncthreads();
    #pragma unroll
    for (int off = 1; off < SBLK; off <<= 1) {
        int v = (t >= off) ? s[t - off] : 0;
        __syncthreads();
        if (t >= off) s[t] += v;
        __syncthreads();
    }
    if (i < NN) {
        int excl = boff + s[t] - x;
        row_ptr[i] = excl;
        cursor[i] = excl;
    }
    if (blockIdx.x == NSB - 1 && t == SBLK - 1)
        row_ptr[NN] = boff + s[t];
}

__global__ void k_fill(const int* __restrict__ src, const int* __restrict__ dst,
                       int* __restrict__ cursor, int* __restrict__ csr_src) {
    int e = blockIdx.x * blockDim.x + threadIdx.x;
    if (e < NE) {
        int p = atomicAdd(&cursor[dst[e]], 1);
        csr_src[p] = src[e];
    }
}

// MFMA GEMM + fused el/er epilogue. Packed-channel permutation: B0 slot r
// holds channel wbase+2r, B1 holds wbase+2r+1 -> lane's acc0/acc1 are
// ADJACENT channels. 128 rows per block (8 M-tiles) amortizes B-frag load.
__global__ __launch_bounds__(256) void k_gemm_elr(
        const bf16* __restrict__ h, const bf16* __restrict__ wbt,
        const float* __restrict__ wc, u8* __restrict__ feat8,
        float* __restrict__ el, float* __restrict__ er, int l) {
    const int lane = threadIdx.x & 63, wid = threadIdx.x >> 6;
    const int r = lane & 15, q = lane >> 4;
    const int wbase = wid * 32;
    const bf16* Wt = wbt + l * HD * HD;

    short8v bfr[2][4];
    #pragma unroll
    for (int t = 0; t < 2; t++)
        #pragma unroll
        for (int ks = 0; ks < 4; ks++)
            bfr[t][ks] = *reinterpret_cast<const short8v*>(
                Wt + (wbase + 2 * r + t) * HD + ks * 32 + q * 8);

    const float al0 = wc[OFF_AL + l * HD + wbase + 2 * r];
    const float al1 = wc[OFF_AL + l * HD + wbase + 2 * r + 1];
    const float ar0 = wc[OFF_AR + l * HD + wbase + 2 * r];
    const float ar1 = wc[OFF_AR + l * HD + wbase + 2 * r + 1];

    const int base0 = blockIdx.x * 128;
    #pragma unroll
    for (int mt = 0; mt < 8; mt++) {
        const int base = base0 + mt * 16;
        if (base >= NN) break;
        float4v acc0 = {0.f, 0.f, 0.f, 0.f};
        float4v acc1 = {0.f, 0.f, 0.f, 0.f};
        #pragma unroll
        for (int ks = 0; ks < 4; ks++) {
            short8v a = *reinterpret_cast<const short8v*>(
                h + (base + r) * HD + ks * 32 + q * 8);
            acc0 = __builtin_amdgcn_mfma_f32_16x16x32_bf16(a, bfr[0][ks], acc0, 0, 0, 0);
            acc1 = __builtin_amdgcn_mfma_f32_16x16x32_bf16(a, bfr[1][ks], acc1, 0, 0, 0);
        }
        #pragma unroll
        for (int reg = 0; reg < 4; reg++) {
            const int row = base + q * 4 + reg;
            *reinterpret_cast<u16*>(feat8 + row * HD + wbase + 2 * r) =
                enc2fp8(acc0[reg], acc1[reg]);
            float elp = acc0[reg] * al0 + acc1[reg] * al1;
            float erp = acc0[reg] * ar0 + acc1[reg] * ar1;
            #pragma unroll
            for (int m = 1; m < 16; m <<= 1) {
                elp += __shfl_xor(elp, m, 64);
                erp += __shfl_xor(erp, m, 64);
            }
            if (r == 0) {
                el[row * 4 + wid] = elp;
                er[row * 4 + wid] = erp;
            }
        }
    }
}

// aggregation v7: one 32-lane group per node (2 nodes/wave). A group's
// 32 x u32 fp8 load = exactly one 128B feat row; s/alpha uniform per group
// (direct uniform loads, no cross-lane ops); no parity combine at all.
template <bool LAST>
__global__ __launch_bounds__(256) void k_agg7(
        const u8* __restrict__ feat8, const float* __restrict__ el4,
        const float* __restrict__ er4, const int* __restrict__ row_ptr,
        const int* __restrict__ csr_src, const float* __restrict__ wc,
        bf16* __restrict__ h, float* __restrict__ gate, int l) {
    int tid = threadIdx.x;
    const int grp = tid >> 5;      // 8 node-groups per block
    const int gl = tid & 31;       // lane in group
    const int hq = gl >> 3;        // head of my channel quad
    const int cb = gl * 4;         // first channel (byte offset in fp8 row)
    for (int n = blockIdx.x * 8 + grp; n < NN; n += gridDim.x * 8) {
        int rp = row_ptr[n];
        int deg = row_ptr[n + 1] - rp;
        float ern = er4[n * 4 + hq];
        float a0 = 0.f, a1 = 0.f, a2 = 0.f, a3 = 0.f, z = 0.f;
        #pragma unroll 4
        for (int j = 0; j < deg; j++) {
            int s = csr_src[rp + j];                 // uniform per group
            float elv = el4[s * 4 + hq];             // 4 words per group
            float w = __expf(lrelu(elv + ern));
            u32 f = *reinterpret_cast<const u32*>(feat8 + s * HD + cb);
            float x0, x1, x2, x3;
            dec4fp8(f, x0, x1, x2, x3);
            a0 += w * x0;
            a1 += w * x1;
            a2 += w * x2;
            a3 += w * x3;
            z += w;
        }
        float inv = (deg && z != 0.f) ? 1.0f / z : 0.f;
        uint2 hv = *reinterpret_cast<const uint2*>(h + n * HD + cb);
        float v0 = fmaxf(a0 * inv + bf16lo(hv.x) + wc[OFF_BIAS + l * HD + cb], 0.f);
        float v1 = fmaxf(a1 * inv + bf16hi(hv.x) + wc[OFF_BIAS + l * HD + cb + 1], 0.f);
        float v2 = fmaxf(a2 * inv + bf16lo(hv.y) + wc[OFF_BIAS + l * HD + cb + 2], 0.f);
        float v3 = fmaxf(a3 * inv + bf16hi(hv.y) + wc[OFF_BIAS + l * HD + cb + 3], 0.f);
        if (!LAST) {
            uint2 o;
            o.x = packbf16(v0, v1);
            o.y = packbf16(v2, v3);
            *reinterpret_cast<uint2*>(h + n * HD + cb) = o;
        } else {
            // fused LayerNorm + gate (row distributed over the 32-lane group)
            float mu = grp_sum32(v0 + v1 + v2 + v3) * (1.0f / 128.0f);
            float d0 = v0 - mu, d1 = v1 - mu, d2 = v2 - mu, d3 = v3 - mu;
            float var = grp_sum32(d0 * d0 + d1 * d1 + d2 * d2 + d3 * d3)
                        * (1.0f / 128.0f);
            float rs = rsqrtf(var + 1e-5f);
            float y0 = d0 * rs * wc[OFF_LNG + cb]     + wc[OFF_LNB + cb];
            float y1 = d1 * rs * wc[OFF_LNG + cb + 1] + wc[OFF_LNB + cb + 1];
            float y2 = d2 * rs * wc[OFF_LNG + cb + 2] + wc[OFF_LNB + cb + 2];
            float y3 = d3 * rs * wc[OFF_LNG + cb + 3] + wc[OFF_LNB + cb + 3];
            uint2 o;
            o.x = packbf16(y0, y1);
            o.y = packbf16(y2, y3);
            *reinterpret_cast<uint2*>(h + n * HD + cb) = o;
            float gd = y0 * wc[OFF_GW + cb]     + y1 * wc[OFF_GW + cb + 1] +
                       y2 * wc[OFF_GW + cb + 2] + y3 * wc[OFF_GW + cb + 3];
            gd = grp_sum32(gd);
            if (gl == 0) gate[n] = gd + wc[OFF_GB];
        }
    }
}

// per-graph gate max + 1/z; computes its own graph bounds (binary search),
// writes gb[] for poolsum, zeroes its zg row (runs before poolsum).
__global__ __launch_bounds__(256) void k_gmaxz(
        const float* __restrict__ gate, const int* __restrict__ gid,
        float* __restrict__ gmax, float* __restrict__ gzinv,
        int* __restrict__ gb, float* __restrict__ zg) {
    __shared__ float red[256];
    __shared__ int sb[2];
    int g = blockIdx.x, tid = threadIdx.x;
    if (tid < 2) {
        int target = g + tid;
        int lo = 0, hi = NN;
        while (lo < hi) {
            int mid = (lo + hi) >> 1;
            if (gid[mid] < target) lo = mid + 1;
            else hi = mid;
        }
        sb[tid] = lo;
        if (tid == 0) gb[g] = lo;
        if (tid == 1 && g == NG - 1) gb[NG] = lo;
    }
    if (tid < HD) zg[g * HD + tid] = 0.f;
    __syncthreads();
    int s0 = sb[0], e0 = sb[1];
    float m = -1e30f;
    for (int i = s0 + tid; i < e0; i += 256) m = fmaxf(m, gate[i]);
    red[tid] = m;
    __syncthreads();
    for (int off = 128; off; off >>= 1) {
        if (tid < off) red[tid] = fmaxf(red[tid], red[tid + off]);
        __syncthreads();
    }
    m = red[0];
    __syncthreads();
    float z = 0.f;
    for (int i = s0 + tid; i < e0; i += 256) z += __expf(gate[i] - m);
    red[tid] = z;
    __syncthreads();
    for (int off = 128; off; off >>= 1) {
        if (tid < off) red[tid] += red[tid + off];
        __syncthreads();
    }
    if (tid == 0) {
        gmax[g] = m;
        gzinv[g] = (e0 > s0 && red[0] > 0.f) ? 1.0f / red[0] : 0.f;
    }
}

// weighted node-sum, PCHUNK blocks per graph, atomicAdd into zeroed zg
__global__ __launch_bounds__(256) void k_poolsum(
        const bf16* __restrict__ h, const float* __restrict__ gate,
        const int* __restrict__ gb, const float* __restrict__ gmax,
        float* __restrict__ zg) {
    __shared__ float red[256];
    int b = blockIdx.x;
    int g = b / PCHUNK, c = b % PCHUNK;
    int s0 = gb[g], e0 = gb[g + 1];
    int len = e0 - s0;
    int beg = s0 + (int)(((long long)len * c) / PCHUNK);
    int end = s0 + (int)(((long long)len * (c + 1)) / PCHUNK);
    int ch = threadIdx.x & 127, half = threadIdx.x >> 7;
    float m = gmax[g];
    float acc = 0.f;
    for (int i = beg + half; i < end; i += 2)
        acc += __expf(gate[i] - m) * b2f(h[i * HD + ch]);
    red[threadIdx.x] = acc;
    __syncthreads();
    if (threadIdx.x < 128) {
        float v = red[threadIdx.x] + red[threadIdx.x + 128];
        if (v != 0.f) atomicAdd(&zg[g * HD + ch], v);
    }
}

__global__ __launch_bounds__(128) void k_mlp(
        const float* __restrict__ zg, const float* __restrict__ gzinv,
        const float* __restrict__ wc, float* __restrict__ out) {
    __shared__ float zr[HD], z1[HD];
    int g = blockIdx.x, tid = threadIdx.x;
    zr[tid] = zg[g * HD + tid] * gzinv[g];
    __syncthreads();
    float acc = wc[OFF_PB1 + tid];
    for (int k = 0; k < HD; k++) acc += zr[k] * wc[OFF_PW1 + k * HD + tid];
    z1[tid] = fmaxf(acc, 0.f);
    __syncthreads();
    if (tid < 64) {
        float a2 = wc[OFF_PB2 + tid];
        for (int k = 0; k < HD; k++) a2 += z1[k] * wc[OFF_PW2 + k * 64 + tid];
        out[g * 64 + tid] = a2;
    }
}

extern "C" void kernel_launch(void* const* d_in, const int* in_sizes, int n_in,
                              void* d_out, int out_size, void* d_ws, size_t ws_size,
                              hipStream_t stream) {
    const int* gate_types = (const int*)d_in[0];
    const int* qubit_idx  = (const int*)d_in[1];
    const int* src        = (const int*)d_in[2];
    const int* dst        = (const int*)d_in[3];
    const int* graph_ids  = (const int*)d_in[4];
    float* out = (float*)d_out;

    const int expect[19] = {NN, NN, NE, NE, NN, 4096, 2560, 49152, 384, 384,
                            384, 128, 128, 128, 1, 16384, 128, 8192, 64};
    for (int i = 0; i < 19 && i < n_in; i++) {
        if (in_sizes[i] != expect[i]) {
            k_diag<<<(out_size + 255) / 256, 256, 0, stream>>>(out, out_size,
                                                               7777000.f + i);
            return;
        }
    }

    char* ws = (char*)d_ws;
    size_t off = 0;
    auto alloc = [&](size_t bytes) {
        void* p = ws + off;
        off = (off + bytes + 255) & ~(size_t)255;
        return p;
    };
    float*  wc      = (float*)alloc(sizeof(float) * CVT_TOTAL);
    bf16*   wbt     = (bf16*)alloc(sizeof(bf16) * NL * HD * HD);
    float*  el      = (float*)alloc(sizeof(float) * NN * 4);
    float*  er      = (float*)alloc(sizeof(float) * NN * 4);
    int*    row_ptr = (int*)alloc(sizeof(int) * (NN + 1));
    int*    deg     = (int*)alloc(sizeof(int) * NN);
    int*    cursor  = (int*)alloc(sizeof(int) * NN);
    int*    csr_src = (int*)alloc(sizeof(int) * NE);
    int*    bsum    = (int*)alloc(sizeof(int) * NSB);
    float*  gate    = (float*)alloc(sizeof(float) * NN);
    int*    gb      = (int*)alloc(sizeof(int) * (NG + 1));
    float*  zg      = (float*)alloc(sizeof(float) * NG * HD);
    float*  gmax    = (float*)alloc(sizeof(float) * NG);
    float*  gzinv   = (float*)alloc(sizeof(float) * NG);
    bf16*   h       = (bf16*)alloc(sizeof(bf16) * NN * HD);
    u8*     feat8   = (u8*)alloc(sizeof(u8) * NN * HD);

    if (off > ws_size) {
        k_diag<<<(out_size + 255) / 256, 256, 0, stream>>>(
            out, out_size, (float)(ws_size >> 10));
        return;
    }

    CvtSrc cs;
    for (int i = 0; i < 14; i++) cs.p[i] = d_in[5 + i];
    k_convert<<<256, 256, 0, stream>>>(cs, wc, wbt, deg);

    k_embed<<<(NN * 64 + 255) / 256, 256, 0, stream>>>(gate_types, qubit_idx,
                                                       wc, h, dst, deg);
    k_bsum<<<NSB, SBLK, 0, stream>>>(deg, bsum);
    k_locscan<<<NSB, SBLK, 0, stream>>>(deg, bsum, row_ptr, cursor);
    k_fill<<<(NE + 255) / 256, 256, 0, stream>>>(src, dst, cursor, csr_src);

    for (int l = 0; l < NL; l++) {
        k_gemm_elr<<<GBLK2, 256, 0, stream>>>(h, wbt, wc, feat8, el, er, l);
        if (l < NL - 1)
            k_agg7<false><<<2048, 256, 0, stream>>>(feat8, el, er, row_ptr,
                                                    csr_src, wc, h, gate, l);
        else
            k_agg7<true><<<2048, 256, 0, stream>>>(feat8, el, er, row_ptr,
                                                   csr_src, wc, h, gate, l);
    }
    k_gmaxz<<<NG, 256, 0, stream>>>(gate, graph_ids, gmax, gzinv, gb, zg);
    k_poolsum<<<NG * PCHUNK, 256, 0, stream>>>(h, gate, gb, gmax, zg);
    k_mlp<<<NG, 128, 0, stream>>>(zg, gzinv, wc, out);
}

// Round 16
// 244.098 us; speedup vs baseline: 3.7982x; 1.0107x over previous
//
#include <hip/hip_runtime.h>
#include <hip/hip_bf16.h>
#include <hip/hip_fp8.h>

#define NN 50000
#define NE 600000
#define NG 64
#define HD 128
#define NL 3
#define NEG 0.2f
#define PCHUNK 16     // pooling blocks per graph
#define SBLK 256
#define NSB ((NN + SBLK - 1) / SBLK)   // 196 scan blocks
#define GBLK2 ((NN + 127) / 128)       // 391 gemm blocks (128 rows each)

typedef __hip_bfloat16 bf16;
typedef unsigned short u16;
typedef unsigned int u32;
typedef unsigned char u8;
typedef __attribute__((ext_vector_type(8))) short short8v;      // 8 bf16
typedef __attribute__((ext_vector_type(4))) float float4v;      // MFMA acc
typedef __attribute__((ext_vector_type(2))) float float2v;

struct __attribute__((packed, aligned(4))) int4u { int x, y, z, w; };

// converted-f32 weight region offsets (element units)
#define OFF_GE    0
#define OFF_QE    4096
#define OFF_W     6656
#define OFF_AL    55808
#define OFF_AR    56192
#define OFF_BIAS  56576
#define OFF_LNG   56960
#define OFF_LNB   57088
#define OFF_GW    57216
#define OFF_GB    57344
#define OFF_PW1   57345
#define OFF_PB1   73729
#define OFF_PW2   73857
#define OFF_PB2   82049
#define CVT_TOTAL 82113

__device__ __forceinline__ float b2f(bf16 x) { return __bfloat162float(x); }
__device__ __forceinline__ bf16 f2b(float x) { return __float2bfloat16(x); }
__device__ __forceinline__ float lrelu(float x) { return x > 0.f ? x : NEG * x; }
__device__ __forceinline__ float bf16lo(u32 u) { return __uint_as_float(u << 16); }
__device__ __forceinline__ float bf16hi(u32 u) { return __uint_as_float(u & 0xffff0000u); }
__device__ __forceinline__ u32 packbf16(float x, float y) {
    bf16 bx = f2b(x), by = f2b(y);
    u16 ux = *reinterpret_cast<u16*>(&bx);
    u16 uy = *reinterpret_cast<u16*>(&by);
    return (u32)ux | ((u32)uy << 16);
}

// ---- fp8 e4m3 (OCP) encode/decode via HW cvt ----
__device__ __forceinline__ u16 enc2fp8(float a, float b) {
#if __has_builtin(__builtin_amdgcn_cvt_pk_fp8_f32)
    return (u16)__builtin_amdgcn_cvt_pk_fp8_f32(a, b, 0, false);
#else
    __hip_fp8_e4m3 fa(a), fb(b);
    return (u16)fa.__x | ((u16)fb.__x << 8);
#endif
}
__device__ __forceinline__ void dec4fp8(u32 v, float& x0, float& x1,
                                        float& x2, float& x3) {
#if __has_builtin(__builtin_amdgcn_cvt_pk_f32_fp8)
    float2v lo = __builtin_amdgcn_cvt_pk_f32_fp8((int)v, false);
    float2v hi = __builtin_amdgcn_cvt_pk_f32_fp8((int)v, true);
    x0 = lo[0]; x1 = lo[1]; x2 = hi[0]; x3 = hi[1];
#else
    __hip_fp8_e4m3 t0, t1, t2, t3;
    t0.__x = v & 0xff; t1.__x = (v >> 8) & 0xff;
    t2.__x = (v >> 16) & 0xff; t3.__x = (v >> 24) & 0xff;
    x0 = (float)t0; x1 = (float)t1; x2 = (float)t2; x3 = (float)t3;
#endif
}

__device__ __forceinline__ float grp_sum32(float v) {   // within 32-lane group
    #pragma unroll
    for (int m = 1; m < 32; m <<= 1) v += __shfl_xor(v, m, 64);
    return v;
}

// ---- diagnostics ----
__global__ void k_diag(float* out, int n, float code) {
    int i = blockIdx.x * blockDim.x + threadIdx.x;
    if (i < n) out[i] = code;
}

struct CvtSrc { const void* p[14]; };

// convert weights to canonical f32 region + transposed bf16 W + zero deg[].
__global__ __launch_bounds__(256) void k_convert(CvtSrc srcs,
                                                 float* __restrict__ dst,
                                                 bf16* __restrict__ wbt,
                                                 int* __restrict__ deg) {
    __shared__ int cnt;
    if (threadIdx.x == 0) cnt = 0;
    __syncthreads();
    const u16* wraw = (const u16*)srcs.p[2];
    int bad = 0;
    for (int i = threadIdx.x; i < 2048; i += 256) {
        int e = (wraw[i] >> 7) & 0xFF;
        if (e == 0xFF || e >= 0x90) bad++;
    }
    if (bad) atomicAdd(&cnt, bad);
    __syncthreads();
    const bool isf32 = cnt > 16;

    const int starts[15] = {OFF_GE, OFF_QE, OFF_W, OFF_AL, OFF_AR, OFF_BIAS,
                            OFF_LNG, OFF_LNB, OFF_GW, OFF_GB, OFF_PW1, OFF_PB1,
                            OFF_PW2, OFF_PB2, CVT_TOTAL};
    for (int i = blockIdx.x * blockDim.x + threadIdx.x; i < CVT_TOTAL;
         i += gridDim.x * blockDim.x) {
        int a = 0;
        while (i >= starts[a + 1]) a++;
        int off = i - starts[a];
        dst[i] = isf32 ? ((const float*)srcs.p[a])[off]
                       : b2f(((const bf16*)srcs.p[a])[off]);
    }
    // wbt[l][col][k] = bf16(W[l][k][col])  (transposed, MFMA-B-fragment layout)
    for (int i = blockIdx.x * blockDim.x + threadIdx.x; i < NL * HD * HD;
         i += gridDim.x * blockDim.x) {
        int l = i >> 14, rem = i & 16383;
        int col = rem >> 7, k = rem & 127;
        int si = l * 16384 + k * 128 + col;
        float v = isf32 ? ((const float*)srcs.p[2])[si]
                        : b2f(((const bf16*)srcs.p[2])[si]);
        wbt[i] = f2b(v);
    }
    for (int i = blockIdx.x * blockDim.x + threadIdx.x; i < NN;
         i += gridDim.x * blockDim.x)
        deg[i] = 0;
}

// embeddings (2 ch/thread, u32 stores) + fused degree count
__global__ void k_embed(const int* __restrict__ gt, const int* __restrict__ qi,
                        const float* __restrict__ wc, bf16* __restrict__ h,
                        const int* __restrict__ dst, int* __restrict__ deg) {
    int idx = blockIdx.x * blockDim.x + threadIdx.x;
    if (idx < NE) atomicAdd(&deg[dst[idx]], 1);
    if (idx >= NN * 64) return;
    int n = idx >> 6, c = (idx & 63) * 2;
    int g = gt[n], q = qi[n];
    float a0 = wc[OFF_GE + g * HD + c]     + wc[OFF_QE + q * HD + c];
    float a1 = wc[OFF_GE + g * HD + c + 1] + wc[OFF_QE + q * HD + c + 1];
    *reinterpret_cast<u32*>(h + n * HD + c) = packbf16(a0, a1);
}

// ---- CSR scan: per-block sums, then fused (block-offset + local scan) ----
__global__ __launch_bounds__(SBLK) void k_bsum(const int* __restrict__ deg,
                                               int* __restrict__ bsum) {
    __shared__ int red[SBLK];
    int i = blockIdx.x * SBLK + threadIdx.x;
    red[threadIdx.x] = (i < NN) ? deg[i] : 0;
    __syncthreads();
    for (int off = SBLK / 2; off; off >>= 1) {
        if (threadIdx.x < off) red[threadIdx.x] += red[threadIdx.x + off];
        __syncthreads();
    }
    if (threadIdx.x == 0) bsum[blockIdx.x] = red[0];
}

// each block derives its own exclusive offset from bsum (196 entries, L2-hot)
__global__ __launch_bounds__(SBLK) void k_locscan(const int* __restrict__ deg,
                                                  const int* __restrict__ bsum,
                                                  int* __restrict__ row_ptr,
                                                  int* __restrict__ cursor) {
    __shared__ int s[SBLK];
    __shared__ int boffs;
    int t = threadIdx.x;
    int part = (t < NSB && t < blockIdx.x) ? bsum[t] : 0;
    #pragma unroll
    for (int m = 1; m < 64; m <<= 1) part += __shfl_xor(part, m, 64);
    if (t == 0) s[0] = 0;
    __syncthreads();
    if ((t & 63) == 0) atomicAdd(&s[0], part);
    __syncthreads();
    if (t == 0) boffs = s[0];
    __syncthreads();
    int boff = boffs;

    int i = blockIdx.x * SBLK + t;
    int x = (i < NN) ? deg[i] : 0;
    s[t] = x;
    __syncthreads();
    #pragma unroll
    for (int off = 1; off < SBLK; off <<= 1) {
        int v = (t >= off) ? s[t - off] : 0;
        __syncthreads();
        if (t >= off) s[t] += v;
        __syncthreads();
    }
    if (i < NN) {
        int excl = boff + s[t] - x;
        row_ptr[i] = excl;
        cursor[i] = excl;
    }
    if (blockIdx.x == NSB - 1 && t == SBLK - 1)
        row_ptr[NN] = boff + s[t];
}

__global__ void k_fill(const int* __restrict__ src, const int* __restrict__ dst,
                       int* __restrict__ cursor, int* __restrict__ csr_src) {
    int e = blockIdx.x * blockDim.x + threadIdx.x;
    if (e < NE) {
        int p = atomicAdd(&cursor[dst[e]], 1);
        csr_src[p] = src[e];
    }
}

// MFMA GEMM + fused el/er epilogue. Packed-channel permutation; 128 rows/blk.
__global__ __launch_bounds__(256) void k_gemm_elr(
        const bf16* __restrict__ h, const bf16* __restrict__ wbt,
        const float* __restrict__ wc, u8* __restrict__ feat8,
        float* __restrict__ el, float* __restrict__ er, int l) {
    const int lane = threadIdx.x & 63, wid = threadIdx.x >> 6;
    const int r = lane & 15, q = lane >> 4;
    const int wbase = wid * 32;
    const bf16* Wt = wbt + l * HD * HD;

    short8v bfr[2][4];
    #pragma unroll
    for (int t = 0; t < 2; t++)
        #pragma unroll
        for (int ks = 0; ks < 4; ks++)
            bfr[t][ks] = *reinterpret_cast<const short8v*>(
                Wt + (wbase + 2 * r + t) * HD + ks * 32 + q * 8);

    const float al0 = wc[OFF_AL + l * HD + wbase + 2 * r];
    const float al1 = wc[OFF_AL + l * HD + wbase + 2 * r + 1];
    const float ar0 = wc[OFF_AR + l * HD + wbase + 2 * r];
    const float ar1 = wc[OFF_AR + l * HD + wbase + 2 * r + 1];

    const int base0 = blockIdx.x * 128;
    #pragma unroll
    for (int mt = 0; mt < 8; mt++) {
        const int base = base0 + mt * 16;
        if (base >= NN) break;
        float4v acc0 = {0.f, 0.f, 0.f, 0.f};
        float4v acc1 = {0.f, 0.f, 0.f, 0.f};
        #pragma unroll
        for (int ks = 0; ks < 4; ks++) {
            short8v a = *reinterpret_cast<const short8v*>(
                h + (base + r) * HD + ks * 32 + q * 8);
            acc0 = __builtin_amdgcn_mfma_f32_16x16x32_bf16(a, bfr[0][ks], acc0, 0, 0, 0);
            acc1 = __builtin_amdgcn_mfma_f32_16x16x32_bf16(a, bfr[1][ks], acc1, 0, 0, 0);
        }
        #pragma unroll
        for (int reg = 0; reg < 4; reg++) {
            const int row = base + q * 4 + reg;
            *reinterpret_cast<u16*>(feat8 + row * HD + wbase + 2 * r) =
                enc2fp8(acc0[reg], acc1[reg]);
            float elp = acc0[reg] * al0 + acc1[reg] * al1;
            float erp = acc0[reg] * ar0 + acc1[reg] * ar1;
            #pragma unroll
            for (int m = 1; m < 16; m <<= 1) {
                elp += __shfl_xor(elp, m, 64);
                erp += __shfl_xor(erp, m, 64);
            }
            if (r == 0) {
                el[row * 4 + wid] = elp;
                er[row * 4 + wid] = erp;
            }
        }
    }
}

// aggregation v8: group-per-node; 4 edge indices fetched in ONE dwordx4,
// software-pipelined one batch ahead -> per batch: 1 prefetched index load
// + 8 INDEPENDENT gathers (4 el4 + 4 feat rows) in flight simultaneously.
template <bool LAST>
__global__ __launch_bounds__(256) void k_agg8(
        const u8* __restrict__ feat8, const float* __restrict__ el4,
        const float* __restrict__ er4, const int* __restrict__ row_ptr,
        const int* __restrict__ csr_src, const float* __restrict__ wc,
        bf16* __restrict__ h, float* __restrict__ gate, int l) {
    int tid = threadIdx.x;
    const int grp = tid >> 5;      // 8 node-groups per block
    const int gl = tid & 31;       // lane in group
    const int hq = gl >> 3;        // head of my channel quad
    const int cb = gl * 4;         // first channel (byte offset in fp8 row)
    for (int n = blockIdx.x * 8 + grp; n < NN; n += gridDim.x * 8) {
        int rp = row_ptr[n];
        int deg = row_ptr[n + 1] - rp;
        float ern = er4[n * 4 + hq];
        float a0 = 0.f, a1 = 0.f, a2 = 0.f, a3 = 0.f, z = 0.f;
        int j = 0;
        if (deg >= 4) {
            int4u s4 = *reinterpret_cast<const int4u*>(csr_src + rp);
            for (; j + 4 <= deg; j += 4) {
                int4u cur = s4;
                if (j + 8 <= deg)
                    s4 = *reinterpret_cast<const int4u*>(csr_src + rp + j + 4);
                float e0 = el4[cur.x * 4 + hq];
                float e1 = el4[cur.y * 4 + hq];
                float e2 = el4[cur.z * 4 + hq];
                float e3 = el4[cur.w * 4 + hq];
                u32 f0 = *reinterpret_cast<const u32*>(feat8 + cur.x * HD + cb);
                u32 f1 = *reinterpret_cast<const u32*>(feat8 + cur.y * HD + cb);
                u32 f2 = *reinterpret_cast<const u32*>(feat8 + cur.z * HD + cb);
                u32 f3 = *reinterpret_cast<const u32*>(feat8 + cur.w * HD + cb);
                float w0 = __expf(lrelu(e0 + ern));
                float w1 = __expf(lrelu(e1 + ern));
                float w2 = __expf(lrelu(e2 + ern));
                float w3 = __expf(lrelu(e3 + ern));
                float x0, x1, x2, x3;
                dec4fp8(f0, x0, x1, x2, x3);
                a0 += w0 * x0; a1 += w0 * x1; a2 += w0 * x2; a3 += w0 * x3;
                dec4fp8(f1, x0, x1, x2, x3);
                a0 += w1 * x0; a1 += w1 * x1; a2 += w1 * x2; a3 += w1 * x3;
                dec4fp8(f2, x0, x1, x2, x3);
                a0 += w2 * x0; a1 += w2 * x1; a2 += w2 * x2; a3 += w2 * x3;
                dec4fp8(f3, x0, x1, x2, x3);
                a0 += w3 * x0; a1 += w3 * x1; a2 += w3 * x2; a3 += w3 * x3;
                z += (w0 + w1) + (w2 + w3);
            }
        }
        for (; j < deg; j++) {
            int s = csr_src[rp + j];
            float elv = el4[s * 4 + hq];
            float w = __expf(lrelu(elv + ern));
            u32 f = *reinterpret_cast<const u32*>(feat8 + s * HD + cb);
            float x0, x1, x2, x3;
            dec4fp8(f, x0, x1, x2, x3);
            a0 += w * x0; a1 += w * x1; a2 += w * x2; a3 += w * x3;
            z += w;
        }
        float inv = (deg && z != 0.f) ? 1.0f / z : 0.f;
        uint2 hv = *reinterpret_cast<const uint2*>(h + n * HD + cb);
        float v0 = fmaxf(a0 * inv + bf16lo(hv.x) + wc[OFF_BIAS + l * HD + cb], 0.f);
        float v1 = fmaxf(a1 * inv + bf16hi(hv.x) + wc[OFF_BIAS + l * HD + cb + 1], 0.f);
        float v2 = fmaxf(a2 * inv + bf16lo(hv.y) + wc[OFF_BIAS + l * HD + cb + 2], 0.f);
        float v3 = fmaxf(a3 * inv + bf16hi(hv.y) + wc[OFF_BIAS + l * HD + cb + 3], 0.f);
        if (!LAST) {
            uint2 o;
            o.x = packbf16(v0, v1);
            o.y = packbf16(v2, v3);
            *reinterpret_cast<uint2*>(h + n * HD + cb) = o;
        } else {
            // fused LayerNorm + gate (row distributed over the 32-lane group)
            float mu = grp_sum32(v0 + v1 + v2 + v3) * (1.0f / 128.0f);
            float d0 = v0 - mu, d1 = v1 - mu, d2 = v2 - mu, d3 = v3 - mu;
            float var = grp_sum32(d0 * d0 + d1 * d1 + d2 * d2 + d3 * d3)
                        * (1.0f / 128.0f);
            float rs = rsqrtf(var + 1e-5f);
            float y0 = d0 * rs * wc[OFF_LNG + cb]     + wc[OFF_LNB + cb];
            float y1 = d1 * rs * wc[OFF_LNG + cb + 1] + wc[OFF_LNB + cb + 1];
            float y2 = d2 * rs * wc[OFF_LNG + cb + 2] + wc[OFF_LNB + cb + 2];
            float y3 = d3 * rs * wc[OFF_LNG + cb + 3] + wc[OFF_LNB + cb + 3];
            uint2 o;
            o.x = packbf16(y0, y1);
            o.y = packbf16(y2, y3);
            *reinterpret_cast<uint2*>(h + n * HD + cb) = o;
            float gd = y0 * wc[OFF_GW + cb]     + y1 * wc[OFF_GW + cb + 1] +
                       y2 * wc[OFF_GW + cb + 2] + y3 * wc[OFF_GW + cb + 3];
            gd = grp_sum32(gd);
            if (gl == 0) gate[n] = gd + wc[OFF_GB];
        }
    }
}

// per-graph gate max + 1/z; computes its own graph bounds (binary search),
// writes gb[] for poolsum, zeroes its zg row (runs before poolsum).
__global__ __launch_bounds__(256) void k_gmaxz(
        const float* __restrict__ gate, const int* __restrict__ gid,
        float* __restrict__ gmax, float* __restrict__ gzinv,
        int* __restrict__ gb, float* __restrict__ zg) {
    __shared__ float red[256];
    __shared__ int sb[2];
    int g = blockIdx.x, tid = threadIdx.x;
    if (tid < 2) {
        int target = g + tid;
        int lo = 0, hi = NN;
        while (lo < hi) {
            int mid = (lo + hi) >> 1;
            if (gid[mid] < target) lo = mid + 1;
            else hi = mid;
        }
        sb[tid] = lo;
        if (tid == 0) gb[g] = lo;
        if (tid == 1 && g == NG - 1) gb[NG] = lo;
    }
    if (tid < HD) zg[g * HD + tid] = 0.f;
    __syncthreads();
    int s0 = sb[0], e0 = sb[1];
    float m = -1e30f;
    for (int i = s0 + tid; i < e0; i += 256) m = fmaxf(m, gate[i]);
    red[tid] = m;
    __syncthreads();
    for (int off = 128; off; off >>= 1) {
        if (tid < off) red[tid] = fmaxf(red[tid], red[tid + off]);
        __syncthreads();
    }
    m = red[0];
    __syncthreads();
    float z = 0.f;
    for (int i = s0 + tid; i < e0; i += 256) z += __expf(gate[i] - m);
    red[tid] = z;
    __syncthreads();
    for (int off = 128; off; off >>= 1) {
        if (tid < off) red[tid] += red[tid + off];
        __syncthreads();
    }
    if (tid == 0) {
        gmax[g] = m;
        gzinv[g] = (e0 > s0 && red[0] > 0.f) ? 1.0f / red[0] : 0.f;
    }
}

// weighted node-sum, PCHUNK blocks per graph, atomicAdd into zeroed zg
__global__ __launch_bounds__(256) void k_poolsum(
        const bf16* __restrict__ h, const float* __restrict__ gate,
        const int* __restrict__ gb, const float* __restrict__ gmax,
        float* __restrict__ zg) {
    __shared__ float red[256];
    int b = blockIdx.x;
    int g = b / PCHUNK, c = b % PCHUNK;
    int s0 = gb[g], e0 = gb[g + 1];
    int len = e0 - s0;
    int beg = s0 + (int)(((long long)len * c) / PCHUNK);
    int end = s0 + (int)(((long long)len * (c + 1)) / PCHUNK);
    int ch = threadIdx.x & 127, half = threadIdx.x >> 7;
    float m = gmax[g];
    float acc = 0.f;
    for (int i = beg + half; i < end; i += 2)
        acc += __expf(gate[i] - m) * b2f(h[i * HD + ch]);
    red[threadIdx.x] = acc;
    __syncthreads();
    if (threadIdx.x < 128) {
        float v = red[threadIdx.x] + red[threadIdx.x + 128];
        if (v != 0.f) atomicAdd(&zg[g * HD + ch], v);
    }
}

__global__ __launch_bounds__(128) void k_mlp(
        const float* __restrict__ zg, const float* __restrict__ gzinv,
        const float* __restrict__ wc, float* __restrict__ out) {
    __shared__ float zr[HD], z1[HD];
    int g = blockIdx.x, tid = threadIdx.x;
    zr[tid] = zg[g * HD + tid] * gzinv[g];
    __syncthreads();
    float acc = wc[OFF_PB1 + tid];
    for (int k = 0; k < HD; k++) acc += zr[k] * wc[OFF_PW1 + k * HD + tid];
    z1[tid] = fmaxf(acc, 0.f);
    __syncthreads();
    if (tid < 64) {
        float a2 = wc[OFF_PB2 + tid];
        for (int k = 0; k < HD; k++) a2 += z1[k] * wc[OFF_PW2 + k * 64 + tid];
        out[g * 64 + tid] = a2;
    }
}

extern "C" void kernel_launch(void* const* d_in, const int* in_sizes, int n_in,
                              void* d_out, int out_size, void* d_ws, size_t ws_size,
                              hipStream_t stream) {
    const int* gate_types = (const int*)d_in[0];
    const int* qubit_idx  = (const int*)d_in[1];
    const int* src        = (const int*)d_in[2];
    const int* dst        = (const int*)d_in[3];
    const int* graph_ids  = (const int*)d_in[4];
    float* out = (float*)d_out;

    const int expect[19] = {NN, NN, NE, NE, NN, 4096, 2560, 49152, 384, 384,
                            384, 128, 128, 128, 1, 16384, 128, 8192, 64};
    for (int i = 0; i < 19 && i < n_in; i++) {
        if (in_sizes[i] != expect[i]) {
            k_diag<<<(out_size + 255) / 256, 256, 0, stream>>>(out, out_size,
                                                               7777000.f + i);
            return;
        }
    }

    char* ws = (char*)d_ws;
    size_t off = 0;
    auto alloc = [&](size_t bytes) {
        void* p = ws + off;
        off = (off + bytes + 255) & ~(size_t)255;
        return p;
    };
    float*  wc      = (float*)alloc(sizeof(float) * CVT_TOTAL);
    bf16*   wbt     = (bf16*)alloc(sizeof(bf16) * NL * HD * HD);
    float*  el      = (float*)alloc(sizeof(float) * NN * 4);
    float*  er      = (float*)alloc(sizeof(float) * NN * 4);
    int*    row_ptr = (int*)alloc(sizeof(int) * (NN + 1));
    int*    deg     = (int*)alloc(sizeof(int) * NN);
    int*    cursor  = (int*)alloc(sizeof(int) * NN);
    int*    csr_src = (int*)alloc(sizeof(int) * (NE + 4));   // +4: safe int4 tail
    int*    bsum    = (int*)alloc(sizeof(int) * NSB);
    float*  gate    = (float*)alloc(sizeof(float) * NN);
    int*    gb      = (int*)alloc(sizeof(int) * (NG + 1));
    float*  zg      = (float*)alloc(sizeof(float) * NG * HD);
    float*  gmax    = (float*)alloc(sizeof(float) * NG);
    float*  gzinv   = (float*)alloc(sizeof(float) * NG);
    bf16*   h       = (bf16*)alloc(sizeof(bf16) * NN * HD);
    u8*     feat8   = (u8*)alloc(sizeof(u8) * NN * HD);

    if (off > ws_size) {
        k_diag<<<(out_size + 255) / 256, 256, 0, stream>>>(
            out, out_size, (float)(ws_size >> 10));
        return;
    }

    CvtSrc cs;
    for (int i = 0; i < 14; i++) cs.p[i] = d_in[5 + i];
    k_convert<<<256, 256, 0, stream>>>(cs, wc, wbt, deg);

    k_embed<<<(NN * 64 + 255) / 256, 256, 0, stream>>>(gate_types, qubit_idx,
                                                       wc, h, dst, deg);
    k_bsum<<<NSB, SBLK, 0, stream>>>(deg, bsum);
    k_locscan<<<NSB, SBLK, 0, stream>>>(deg, bsum, row_ptr, cursor);
    k_fill<<<(NE + 255) / 256, 256, 0, stream>>>(src, dst, cursor, csr_src);

    for (int l = 0; l < NL; l++) {
        k_gemm_elr<<<GBLK2, 256, 0, stream>>>(h, wbt, wc, feat8, el, er, l);
        if (l < NL - 1)
            k_agg8<false><<<2048, 256, 0, stream>>>(feat8, el, er, row_ptr,
                                                    csr_src, wc, h, gate, l);
        else
            k_agg8<true><<<2048, 256, 0, stream>>>(feat8, el, er, row_ptr,
                                                   csr_src, wc, h, gate, l);
    }
    k_gmaxz<<<NG, 256, 0, stream>>>(gate, graph_ids, gmax, gzinv, gb, zg);
    k_poolsum<<<NG * PCHUNK, 256, 0, stream>>>(h, gate, gb, gmax, zg);
    k_mlp<<<NG, 128, 0, stream>>>(zg, gzinv, wc, out);
}